// Round 4
// baseline (662.567 us; speedup 1.0000x reference)
//
#include <hip/hip_runtime.h>
#include <cstdint>
#include <cstddef>

typedef unsigned short ushort_t;
typedef unsigned char uchar_t;
typedef __attribute__((ext_vector_type(4))) float f4;
typedef __attribute__((ext_vector_type(4))) unsigned int u4;
typedef __attribute__((ext_vector_type(2))) unsigned int u2;

#define DEVI static __device__ __forceinline__

DEVI ushort_t f2bf(float x) {
  union { float f; unsigned int u; } v; v.f = x;
  unsigned int r = v.u + 0x7fffu + ((v.u >> 16) & 1u);
  return (ushort_t)(r >> 16);
}
DEVI float bf2f(ushort_t b) {
  union { unsigned int u; float f; } v; v.u = ((unsigned int)b) << 16;
  return v.f;
}
DEVI unsigned pk2(ushort_t a, ushort_t b) { return (unsigned)a | ((unsigned)b << 16); }

DEVI void mfma16(f4& c, u4 a, u4 b) {
  asm("v_mfma_f32_16x16x32_bf16 %0, %1, %2, %0" : "+v"(c) : "v"(a), "v"(b));
}

constexpr int LDR = 40;  // padded LDS row stride (shorts) for reg-staged tiles

// --------------------------------------------------------------------------
// global_load_lds staging: bf16 tile [128 rows][32 cols], linear LDS layout.
// --------------------------------------------------------------------------
#if defined(__has_builtin)
#if __has_builtin(__builtin_amdgcn_global_load_lds)
#define HAS_GLD 1
#endif
#endif
#ifndef HAS_GLD
#define HAS_GLD 0
#endif

#if HAS_GLD
typedef const __attribute__((address_space(1))) unsigned int* gas1_t;
typedef __attribute__((address_space(3))) unsigned int* las3_t;
DEVI void gld16(const void* g, void* l) {
  __builtin_amdgcn_global_load_lds((gas1_t)g, (las3_t)l, 16, 0, 0);
}
#endif

// Stages rows 0..127, cols k0..k0+31 of src (row stride srcStride) into
// lT[128][32] linear. 2 vmcnt-ops/thread on the gld path.
DEVI void stage_tile(const ushort_t* __restrict__ src, int srcStride, int k0,
                     ushort_t* lT, int t) {
#if HAS_GLD
  int w = t >> 6, lane = t & 63;
#pragma unroll
  for (int c = 0; c < 2; ++c) {
    int row = c * 64 + w * 16 + (lane >> 2);
    const ushort_t* g = src + (size_t)row * srcStride + k0 + (lane & 3) * 8;
    gld16(g, lT + (c * 64 + w * 16) * 32);
  }
#else
  int row = t >> 1, kp = (t & 1) << 4;
  const ushort_t* g = src + (size_t)row * srcStride + k0 + kp;
  *(u4*)(lT + row * 32 + kp) = *(const u4*)g;
  *(u4*)(lT + row * 32 + kp + 8) = *(const u4*)(g + 8);
#endif
}

// fragment reads + 16 MFMA for the 128x128, 4-wave layout (linear [128][32] LDS)
DEVI void compute16(const ushort_t* lA, const ushort_t* lB, f4 acc[4][4],
                    int wr, int wc, int fr, int fg) {
  u4 af[4], bfv[4];
#pragma unroll
  for (int m = 0; m < 4; ++m) af[m] = *(const u4*)(lA + (wr + m * 16 + fr) * 32 + (fg << 3));
#pragma unroll
  for (int n = 0; n < 4; ++n) bfv[n] = *(const u4*)(lB + (wc + n * 16 + fr) * 32 + (fg << 3));
#pragma unroll
  for (int m = 0; m < 4; ++m)
#pragma unroll
    for (int n = 0; n < 4; ++n) mfma16(acc[m][n], af[m], bfv[n]);
}

// ---------------------------------------------------------------------------
// 3-deep pipelined GEMM core (T4: counted vmcnt, loads in flight across raw
// s_barrier). Race ledger:
//  R1 buf[t] ready before ds_read: vmcnt(4) waits stage(t) (stage(t+1)'s 4
//     loads may remain in flight); s_barrier makes it workgroup-wide.
//  R2 stage(t+2) overwrites buf[(t+2)%3]=buf[(t-1)%3]: its last readers
//     (iter t-1 ds_reads) drained lgkmcnt(0) before their MFMA, which is
//     before they reached the barrier we just crossed. Issue AFTER barrier.
//  R3 rule #18: sched_barrier(0) after lgkmcnt(0) so MFMA can't hoist.
// Requires nt >= 2. Only valid on the gld path (vmcnt counting).
// ---------------------------------------------------------------------------
#if HAS_GLD
DEVI void gemm_pipe(const ushort_t* __restrict__ A, int lda,
                    const ushort_t* __restrict__ B, int ldb, int K,
                    ushort_t* lab, f4 acc[4][4], int t, int wr, int wc,
                    int fr, int fg) {
  ushort_t* a0 = lab;             ushort_t* b0 = lab + 4096;
  ushort_t* a1 = lab + 2 * 4096;  ushort_t* b1 = lab + 3 * 4096;
  ushort_t* a2 = lab + 4 * 4096;  ushort_t* b2 = lab + 5 * 4096;
  const int nt = K >> 5;
  stage_tile(A, lda, 0, a0, t);
  stage_tile(B, ldb, 0, b0, t);
  stage_tile(A, lda, 32, a1, t);
  stage_tile(B, ldb, 32, b1, t);
  for (int tt = 0; tt < nt; ++tt) {
    if (tt + 1 < nt) asm volatile("s_waitcnt vmcnt(4)" ::: "memory");
    else             asm volatile("s_waitcnt vmcnt(0)" ::: "memory");
    asm volatile("s_barrier" ::: "memory");
    if (tt + 2 < nt) {
      stage_tile(A, lda, (tt + 2) << 5, a2, t);
      stage_tile(B, ldb, (tt + 2) << 5, b2, t);
    }
    u4 af[4], bfv[4];
#pragma unroll
    for (int m = 0; m < 4; ++m) af[m] = *(const u4*)(a0 + (wr + m * 16 + fr) * 32 + (fg << 3));
#pragma unroll
    for (int n = 0; n < 4; ++n) bfv[n] = *(const u4*)(b0 + (wc + n * 16 + fr) * 32 + (fg << 3));
    asm volatile("s_waitcnt lgkmcnt(0)" ::: "memory");
    __builtin_amdgcn_sched_barrier(0);
#pragma unroll
    for (int m = 0; m < 4; ++m)
#pragma unroll
      for (int n = 0; n < 4; ++n) mfma16(acc[m][n], af[m], bfv[n]);
    ushort_t* ta = a0; a0 = a1; a1 = a2; a2 = ta;
    ushort_t* tb = b0; b0 = b1; b1 = b2; b2 = tb;
  }
}
#else
// fallback: 2-phase double-buffered with __syncthreads
DEVI void gemm_pipe(const ushort_t* __restrict__ A, int lda,
                    const ushort_t* __restrict__ B, int ldb, int K,
                    ushort_t* lab, f4 acc[4][4], int t, int wr, int wc,
                    int fr, int fg) {
  ushort_t* a0 = lab;             ushort_t* b0 = lab + 4096;
  ushort_t* a1 = lab + 2 * 4096;  ushort_t* b1 = lab + 3 * 4096;
  stage_tile(A, lda, 0, a0, t);
  stage_tile(B, ldb, 0, b0, t);
  __syncthreads();
  const int nt = K >> 5;
  for (int tt = 0; tt < nt; ++tt) {
    ushort_t* ca = (tt & 1) ? a1 : a0;
    ushort_t* cb = (tt & 1) ? b1 : b0;
    ushort_t* na = (tt & 1) ? a0 : a1;
    ushort_t* nb = (tt & 1) ? b0 : b1;
    if (tt + 1 < nt) {
      stage_tile(A, lda, (tt + 1) << 5, na, t);
      stage_tile(B, ldb, (tt + 1) << 5, nb, t);
    }
    compute16(ca, cb, acc, wr, wc, fr, fg);
    __syncthreads();
  }
}
#endif

// ---------------------------------------------------------------------------
// mask prep: detect uint8-bool vs int32 storage, write transposed [b][pos]
// ---------------------------------------------------------------------------
__global__ __launch_bounds__(256) void prep_masks_kernel(
    const uchar_t* __restrict__ prem, const uchar_t* __restrict__ hypo,
    uchar_t* __restrict__ premT, uchar_t* __restrict__ hypoT) {
  __shared__ int flagP, flagH;
  int t = threadIdx.x;
  if (t == 0) { flagP = 0; flagH = 0; }
  __syncthreads();
  int locP = 0, locH = 0;
  for (int i = t; i < 16384; i += 256) {
    if (i & 3) { locP |= prem[i]; locH |= hypo[i]; }
  }
  if (locP) atomicOr(&flagP, 1);
  if (locH) atomicOr(&flagH, 1);
  __syncthreads();
  bool p8 = flagP != 0, h8 = flagH != 0;  // true -> 1-byte bools
  for (int i = t; i < 16384; i += 256) {
    int p = i >> 6, b = i & 63;
    premT[b * 256 + p] = p8 ? prem[i] : prem[i * 4];
    hypoT[b * 256 + p] = h8 ? hypo[i] : hypo[i * 4];
  }
}

// ---------------------------------------------------------------------------
// weight transpose: f32 [K][N] -> bf16 [N][K] (optionally hi/lo split)
// ---------------------------------------------------------------------------
__global__ __launch_bounds__(256) void transpose_w_kernel(
    const float* __restrict__ Win, ushort_t* __restrict__ Thi,
    ushort_t* __restrict__ Tlo, int N, int K) {
  __shared__ float tl[64][65];
  int k0 = blockIdx.x * 64, n0 = blockIdx.y * 64;
  int t = threadIdx.x;
#pragma unroll
  for (int it = 0; it < 16; ++it) {
    int idx = t + it * 256;
    int k = idx >> 6, n = idx & 63;
    tl[n][k] = Win[(size_t)(k0 + k) * N + n0 + n];
  }
  __syncthreads();
#pragma unroll
  for (int it = 0; it < 16; ++it) {
    int idx = t + it * 256;
    int n = idx >> 6, k = idx & 63;
    float x = tl[n][k];
    ushort_t h = f2bf(x);
    Thi[(size_t)(n0 + n) * K + k0 + k] = h;
    if (Tlo) Tlo[(size_t)(n0 + n) * K + k0 + k] = f2bf(x - bf2f(h));
  }
}

// ---------------------------------------------------------------------------
// S GEMM, bf16x2 split, 64x64 tiles, double-buffered single-barrier loop.
// grid (4,4,64), block 256. S[b][i][j] = sum_h Penc[i][b][h]*Henc[j][b][h]
// ---------------------------------------------------------------------------
__global__ __launch_bounds__(256) void gemm_s_kernel(
    const float* __restrict__ Penc, const float* __restrict__ Henc,
    float* __restrict__ S) {
  __shared__ ushort_t lAh[2][64 * LDR], lAl[2][64 * LDR];
  __shared__ ushort_t lBh[2][64 * LDR], lBl[2][64 * LDR];
  const int t = threadIdx.x;
  const int b = blockIdx.z;
  const int i0 = blockIdx.x * 64, j0 = blockIdx.y * 64;
  const int lda = 64 * 1024;
  const float* Ab = Penc + (size_t)i0 * lda + (size_t)b * 1024;
  const float* Bb = Henc + (size_t)j0 * lda + (size_t)b * 1024;
  const int lane = t & 63, wave = t >> 6;
  const int wr = (wave >> 1) << 5, wc = (wave & 1) << 5;
  const int fr = lane & 15, fg = lane >> 4;
  const int row = t >> 2, kp = (t & 3) << 3;

  f4 acc[2][2];
#pragma unroll
  for (int m = 0; m < 2; ++m)
#pragma unroll
    for (int n = 0; n < 2; ++n) acc[m][n] = f4{0.f, 0.f, 0.f, 0.f};

  auto stage = [&](int k0, int bi) {
    {
      const float* p = Ab + (size_t)row * lda + k0 + kp;
      f4 x0 = *(const f4*)p, x1 = *(const f4*)(p + 4);
      ushort_t hh[8], ll[8];
#pragma unroll
      for (int q = 0; q < 4; ++q) {
        ushort_t h0 = f2bf(x0[q]); hh[q] = h0; ll[q] = f2bf(x0[q] - bf2f(h0));
        ushort_t h1 = f2bf(x1[q]); hh[4 + q] = h1; ll[4 + q] = f2bf(x1[q] - bf2f(h1));
      }
      *(u4*)(lAh[bi] + row * LDR + kp) = u4{ pk2(hh[0], hh[1]), pk2(hh[2], hh[3]), pk2(hh[4], hh[5]), pk2(hh[6], hh[7]) };
      *(u4*)(lAl[bi] + row * LDR + kp) = u4{ pk2(ll[0], ll[1]), pk2(ll[2], ll[3]), pk2(ll[4], ll[5]), pk2(ll[6], ll[7]) };
    }
    {
      const float* p = Bb + (size_t)row * lda + k0 + kp;
      f4 x0 = *(const f4*)p, x1 = *(const f4*)(p + 4);
      ushort_t hh[8], ll[8];
#pragma unroll
      for (int q = 0; q < 4; ++q) {
        ushort_t h0 = f2bf(x0[q]); hh[q] = h0; ll[q] = f2bf(x0[q] - bf2f(h0));
        ushort_t h1 = f2bf(x1[q]); hh[4 + q] = h1; ll[4 + q] = f2bf(x1[q] - bf2f(h1));
      }
      *(u4*)(lBh[bi] + row * LDR + kp) = u4{ pk2(hh[0], hh[1]), pk2(hh[2], hh[3]), pk2(hh[4], hh[5]), pk2(hh[6], hh[7]) };
      *(u4*)(lBl[bi] + row * LDR + kp) = u4{ pk2(ll[0], ll[1]), pk2(ll[2], ll[3]), pk2(ll[4], ll[5]), pk2(ll[6], ll[7]) };
    }
  };

  stage(0, 0);
  __syncthreads();
  for (int tt = 0; tt < 32; ++tt) {
    int cur = tt & 1;
    if (tt + 1 < 32) stage((tt + 1) << 5, cur ^ 1);
    u4 ah[2], al[2], bh[2], bl[2];
#pragma unroll
    for (int m = 0; m < 2; ++m) {
      int off = (wr + m * 16 + fr) * LDR + (fg << 3);
      ah[m] = *(const u4*)(lAh[cur] + off);
      al[m] = *(const u4*)(lAl[cur] + off);
    }
#pragma unroll
    for (int n = 0; n < 2; ++n) {
      int off = (wc + n * 16 + fr) * LDR + (fg << 3);
      bh[n] = *(const u4*)(lBh[cur] + off);
      bl[n] = *(const u4*)(lBl[cur] + off);
    }
#pragma unroll
    for (int m = 0; m < 2; ++m)
#pragma unroll
      for (int n = 0; n < 2; ++n) {
        mfma16(acc[m][n], ah[m], bh[n]);
        mfma16(acc[m][n], ah[m], bl[n]);
        mfma16(acc[m][n], al[m], bh[n]);
      }
    __syncthreads();
  }

  float* Sb = S + (size_t)b * 65536;
#pragma unroll
  for (int m = 0; m < 2; ++m)
#pragma unroll
    for (int n = 0; n < 2; ++n)
#pragma unroll
      for (int r = 0; r < 4; ++r) {
        int rrow = i0 + wr + m * 16 + fg * 4 + r;
        int col = j0 + wc + n * 16 + fr;
        Sb[(size_t)rrow * 256 + col] = acc[m][n][r];
      }
}

// ---------------------------------------------------------------------------
// softmax over j (contiguous)
// ---------------------------------------------------------------------------
__global__ __launch_bounds__(256) void softmax_rows_kernel(
    const float* __restrict__ S, const uchar_t* __restrict__ hypoT,
    ushort_t* __restrict__ W) {
  int r = blockIdx.x * 4 + (threadIdx.x >> 6);
  int lane = threadIdx.x & 63;
  int b = r >> 8;
  const float* row = S + (size_t)r * 256;
  f4 x = *(const f4*)(row + lane * 4);
  const uchar_t* mp = hypoT + b * 256 + lane * 4;
  float v0 = mp[0] ? -1e30f : x[0];
  float v1 = mp[1] ? -1e30f : x[1];
  float v2 = mp[2] ? -1e30f : x[2];
  float v3 = mp[3] ? -1e30f : x[3];
  float m = fmaxf(fmaxf(v0, v1), fmaxf(v2, v3));
#pragma unroll
  for (int off = 32; off > 0; off >>= 1) m = fmaxf(m, __shfl_xor(m, off));
  float e0 = expf(v0 - m), e1 = expf(v1 - m), e2 = expf(v2 - m), e3 = expf(v3 - m);
  float s = e0 + e1 + e2 + e3;
#pragma unroll
  for (int off = 32; off > 0; off >>= 1) s += __shfl_xor(s, off);
  float rinv = 1.0f / s;
  ushort_t w0 = f2bf(e0 * rinv), w1 = f2bf(e1 * rinv), w2 = f2bf(e2 * rinv), w3 = f2bf(e3 * rinv);
  *(u2*)(W + (size_t)r * 256 + lane * 4) = u2{ pk2(w0, w1), pk2(w2, w3) };
}

// ---------------------------------------------------------------------------
// softmax over i (strided) + transpose: V[b][j][i]
// ---------------------------------------------------------------------------
__global__ __launch_bounds__(256) void softmax_cols_kernel(
    const float* __restrict__ S, const uchar_t* __restrict__ premT,
    ushort_t* __restrict__ V) {
  __shared__ float tl[32][257];
  __shared__ float pm[8][32], ps[8][32], mfin[32], rs[32];
  int t = threadIdx.x;
  int jl = t & 31, ig = t >> 5;
  int b = blockIdx.y, j0 = blockIdx.x * 32;
  const float* Sb = S + (size_t)b * 65536;
  const uchar_t* pmsk = premT + b * 256;
  for (int i = ig; i < 256; i += 8)
    tl[jl][i] = pmsk[i] ? -1e30f : Sb[(size_t)i * 256 + j0 + jl];
  __syncthreads();
  float m = -3e30f;
#pragma unroll 8
  for (int ii = 0; ii < 32; ++ii) m = fmaxf(m, tl[jl][ig * 32 + ii]);
  float s = 0.f;
#pragma unroll 8
  for (int ii = 0; ii < 32; ++ii) s += expf(tl[jl][ig * 32 + ii] - m);
  pm[ig][jl] = m; ps[ig][jl] = s;
  __syncthreads();
  if (t < 32) {
    float M = pm[0][t];
#pragma unroll
    for (int g = 1; g < 8; ++g) M = fmaxf(M, pm[g][t]);
    float ss = 0.f;
#pragma unroll
    for (int g = 0; g < 8; ++g) ss += ps[g][t] * expf(pm[g][t] - M);
    mfin[t] = M; rs[t] = 1.0f / ss;
  }
  __syncthreads();
  for (int j2 = 0; j2 < 32; ++j2) {
    float val = expf(tl[j2][t] - mfin[j2]) * rs[j2];
    V[((size_t)b * 256 + j0 + j2) * 256 + t] = f2bf(val);
  }
}

// ---------------------------------------------------------------------------
// emb transpose: E[pos][b][h] f32 -> T[b][h][pos] bf16
// ---------------------------------------------------------------------------
__global__ __launch_bounds__(256) void transpose_pos_h_kernel(
    const float* __restrict__ E, ushort_t* __restrict__ T) {
  __shared__ ushort_t tl[64][65];
  int i0 = blockIdx.x * 64, h0 = blockIdx.y * 64, b = blockIdx.z;
  int t = threadIdx.x;
#pragma unroll
  for (int it = 0; it < 16; ++it) {
    int idx = t + it * 256;
    int i = idx >> 6, h = idx & 63;
    tl[h][i] = f2bf(E[((size_t)(i0 + i) * 64 + b) * 1024 + h0 + h]);
  }
  __syncthreads();
#pragma unroll
  for (int it = 0; it < 16; ++it) {
    int idx = t + it * 256;
    int h = idx >> 6, i = idx & 63;
    T[((size_t)b * 1024 + h0 + h) * 256 + i0 + i] = tl[h][i];
  }
}

// ---------------------------------------------------------------------------
// cast f32 emb -> first half of X: X[(pos*64+b)][0:1024] = bf16(E). grid 8192
// ---------------------------------------------------------------------------
__global__ __launch_bounds__(256) void cast_half_kernel(
    const float* __restrict__ E, ushort_t* __restrict__ X) {
  size_t idx = (size_t)blockIdx.x * 256 + threadIdx.x;
  size_t r = idx >> 7;
  int h8 = ((int)idx & 127) << 3;
  const f4* p = (const f4*)(E + r * 1024 + h8);
  f4 a = p[0], c = p[1];
  ushort_t hh[8];
#pragma unroll
  for (int q = 0; q < 4; ++q) { hh[q] = f2bf(a[q]); hh[4 + q] = f2bf(c[q]); }
  *(u4*)(X + r * 2048 + h8) =
      u4{ pk2(hh[0], hh[1]), pk2(hh[2], hh[3]), pk2(hh[4], hh[5]), pk2(hh[6], hh[7]) };
}

// ---------------------------------------------------------------------------
// context GEMM (pipelined): ctx[pos][h] = sum_k Attn[b][pos][k]*T[b][h][k]
// masked-write bf16 into X[(pos*64+b)*2048 + 1024 + h]. grid (2, 8, 64)
// ---------------------------------------------------------------------------
__global__ __launch_bounds__(256) void gemm_ctx_kernel(
    const ushort_t* __restrict__ Attn, const ushort_t* __restrict__ T,
    const uchar_t* __restrict__ maskT, ushort_t* __restrict__ X) {
  __shared__ ushort_t lab[6 * 4096];
  int t = threadIdx.x;
  int b = blockIdx.z;
  int m0 = blockIdx.x * 128, n0 = blockIdx.y * 128;
  const ushort_t* A = Attn + (size_t)b * 65536 + (size_t)m0 * 256;
  const ushort_t* B = T + (size_t)b * 262144 + (size_t)n0 * 256;
  int lane = t & 63, wave = t >> 6;
  int wr = (wave >> 1) << 6, wc = (wave & 1) << 6;
  int fr = lane & 15, fg = lane >> 4;
  f4 acc[4][4];
#pragma unroll
  for (int m = 0; m < 4; ++m)
#pragma unroll
    for (int n = 0; n < 4; ++n) acc[m][n] = f4{0.f, 0.f, 0.f, 0.f};
  gemm_pipe(A, 256, B, 256, 256, lab, acc, t, wr, wc, fr, fg);
#pragma unroll
  for (int m = 0; m < 4; ++m)
#pragma unroll
    for (int n = 0; n < 4; ++n)
#pragma unroll
      for (int r = 0; r < 4; ++r) {
        int gm = m0 + wr + m * 16 + fg * 4 + r;
        int gn = n0 + wc + n * 16 + fr;
        float v = maskT[b * 256 + gm] ? 0.f : acc[m][n][r];
        X[((size_t)gm * 64 + b) * 2048 + 1024 + gn] = f2bf(v);
      }
}

// ---------------------------------------------------------------------------
// MLP GEMM (pipelined): C = relu(A @ W^T + bias). grid (128, 8), block 256.
// ---------------------------------------------------------------------------
__global__ __launch_bounds__(256) void gemm_mlp_kernel(
    const ushort_t* __restrict__ A, int lda, const ushort_t* __restrict__ W,
    int ldw, const float* __restrict__ bias, ushort_t* __restrict__ C, int K) {
  __shared__ ushort_t lab[6 * 4096];
  int t = threadIdx.x;
  int m0 = blockIdx.x * 128, n0 = blockIdx.y * 128;
  int lane = t & 63, wave = t >> 6;
  int wr = (wave >> 1) << 6, wc = (wave & 1) << 6;
  int fr = lane & 15, fg = lane >> 4;
  f4 acc[4][4];
#pragma unroll
  for (int m = 0; m < 4; ++m)
#pragma unroll
    for (int n = 0; n < 4; ++n) acc[m][n] = f4{0.f, 0.f, 0.f, 0.f};
  gemm_pipe(A + (size_t)m0 * lda, lda, W + (size_t)n0 * ldw, ldw, K,
            lab, acc, t, wr, wc, fr, fg);
#pragma unroll
  for (int m = 0; m < 4; ++m)
#pragma unroll
    for (int n = 0; n < 4; ++n)
#pragma unroll
      for (int r = 0; r < 4; ++r) {
        int gm = m0 + wr + m * 16 + fg * 4 + r;
        int gn = n0 + wc + n * 16 + fr;
        float v = acc[m][n][r] + bias[gn];
        v = v > 0.f ? v : 0.f;
        C[(size_t)gm * 1024 + gn] = f2bf(v);
      }
}

// ---------------------------------------------------------------------------
// pool partial: partial[jc][b][coff+n] = sum_{j in chunk} H2[(j*64+b)][n]
// ---------------------------------------------------------------------------
__global__ __launch_bounds__(256) void pool_partial_kernel(
    const ushort_t* __restrict__ H2, float* __restrict__ partial, int coff) {
  int jc = blockIdx.x, b = blockIdx.y, t = threadIdx.x;
  float a0 = 0.f, a1 = 0.f, a2 = 0.f, a3 = 0.f;
  for (int j = jc * 32; j < jc * 32 + 32; ++j) {
    u2 v = *(const u2*)(H2 + ((size_t)(j * 64 + b)) * 1024 + t * 4);
    a0 += bf2f((ushort_t)(v[0] & 0xffff));
    a1 += bf2f((ushort_t)(v[0] >> 16));
    a2 += bf2f((ushort_t)(v[1] & 0xffff));
    a3 += bf2f((ushort_t)(v[1] >> 16));
  }
  *(f4*)(partial + ((size_t)(jc * 64 + b)) * 2048 + coff + t * 4) = f4{a0, a1, a2, a3};
}

// ---------------------------------------------------------------------------
// pool final + hi/lo split. grid 512, block 256
// ---------------------------------------------------------------------------
__global__ __launch_bounds__(256) void pool_final_kernel(
    const float* __restrict__ partial, ushort_t* __restrict__ ph,
    ushort_t* __restrict__ pl) {
  int idx = blockIdx.x * 256 + threadIdx.x;
  int b = idx >> 11, k = idx & 2047;
  float s = 0.f;
#pragma unroll
  for (int jc = 0; jc < 8; ++jc) s += partial[((size_t)(jc * 64 + b)) * 2048 + k];
  ushort_t h = f2bf(s);
  ph[idx] = h;
  pl[idx] = f2bf(s - bf2f(h));
}

// ---------------------------------------------------------------------------
// agg layer 1 (split bf16x2)
// ---------------------------------------------------------------------------
__global__ __launch_bounds__(256) void gemm_agg1_kernel(
    const ushort_t* __restrict__ Ph, const ushort_t* __restrict__ Pl,
    const ushort_t* __restrict__ Wh, const ushort_t* __restrict__ Wl,
    const float* __restrict__ bias, float* __restrict__ z) {
  __shared__ ushort_t lAh[64 * LDR], lAl[64 * LDR], lBh[128 * LDR], lBl[128 * LDR];
  int t = threadIdx.x;
  int n0 = blockIdx.x * 128;
  int lane = t & 63, wave = t >> 6;
  int wc = wave * 32;
  int fr = lane & 15, fg = lane >> 4;
  f4 acc[4][2];
#pragma unroll
  for (int m = 0; m < 4; ++m)
#pragma unroll
    for (int n = 0; n < 2; ++n) acc[m][n] = f4{0.f, 0.f, 0.f, 0.f};

  for (int k0 = 0; k0 < 2048; k0 += 32) {
    __syncthreads();
    {
      int row = t >> 2, kp = (t & 3) << 3;
      *(u4*)(lAh + row * LDR + kp) = *(const u4*)(Ph + (size_t)row * 2048 + k0 + kp);
      *(u4*)(lAl + row * LDR + kp) = *(const u4*)(Pl + (size_t)row * 2048 + k0 + kp);
    }
#pragma unroll
    for (int c = 0; c < 2; ++c) {
      int ch = t + (c << 8);
      int row = ch >> 2, kp = (ch & 3) << 3;
      *(u4*)(lBh + row * LDR + kp) = *(const u4*)(Wh + (size_t)(n0 + row) * 2048 + k0 + kp);
      *(u4*)(lBl + row * LDR + kp) = *(const u4*)(Wl + (size_t)(n0 + row) * 2048 + k0 + kp);
    }
    __syncthreads();
    u4 ah[4], al[4], bh[2], bl[2];
#pragma unroll
    for (int m = 0; m < 4; ++m) {
      int off = (m * 16 + fr) * LDR + (fg << 3);
      ah[m] = *(const u4*)(lAh + off);
      al[m] = *(const u4*)(lAl + off);
    }
#pragma unroll
    for (int n = 0; n < 2; ++n) {
      int off = (wc + n * 16 + fr) * LDR + (fg << 3);
      bh[n] = *(const u4*)(lBh + off);
      bl[n] = *(const u4*)(lBl + off);
    }
#pragma unroll
    for (int m = 0; m < 4; ++m)
#pragma unroll
      for (int n = 0; n < 2; ++n) {
        mfma16(acc[m][n], ah[m], bh[n]);
        mfma16(acc[m][n], ah[m], bl[n]);
        mfma16(acc[m][n], al[m], bh[n]);
      }
  }
#pragma unroll
  for (int m = 0; m < 4; ++m)
#pragma unroll
    for (int n = 0; n < 2; ++n)
#pragma unroll
      for (int r = 0; r < 4; ++r) {
        int row = m * 16 + fg * 4 + r;  // b
        int col = n0 + wc + n * 16 + fr;
        float v = acc[m][n][r] + bias[col];
        z[row * 1024 + col] = v > 0.f ? v : 0.f;
      }
}

// ---------------------------------------------------------------------------
// agg layer 2
// ---------------------------------------------------------------------------
__global__ __launch_bounds__(64) void agg2_kernel(
    const float* __restrict__ z, const float* __restrict__ aW2,
    const float* __restrict__ ab2, float* __restrict__ out) {
  int b = blockIdx.x, lane = threadIdx.x;
  float a0 = 0.f, a1 = 0.f, a2 = 0.f;
  for (int k = lane; k < 1024; k += 64) {
    float zv = z[b * 1024 + k];
    a0 += zv * aW2[k * 3 + 0];
    a1 += zv * aW2[k * 3 + 1];
    a2 += zv * aW2[k * 3 + 2];
  }
#pragma unroll
  for (int off = 32; off > 0; off >>= 1) {
    a0 += __shfl_xor(a0, off);
    a1 += __shfl_xor(a1, off);
    a2 += __shfl_xor(a2, off);
  }
  if (lane == 0) {
    out[b * 3 + 0] = a0 + ab2[0];
    out[b * 3 + 1] = a1 + ab2[1];
    out[b * 3 + 2] = a2 + ab2[2];
  }
}

// ---------------------------------------------------------------------------
extern "C" void kernel_launch(void* const* d_in, const int* in_sizes, int n_in,
                              void* d_out, int out_size, void* d_ws, size_t ws_size,
                              hipStream_t stream) {
  const float* P_enc = (const float*)d_in[0];
  const float* H_enc = (const float*)d_in[1];
  const float* P_emb = (const float*)d_in[2];
  const float* H_emb = (const float*)d_in[3];
  const uchar_t* prem = (const uchar_t*)d_in[4];
  const uchar_t* hypo = (const uchar_t*)d_in[5];
  const float* cW1 = (const float*)d_in[6];
  const float* cb1 = (const float*)d_in[7];
  const float* cW2 = (const float*)d_in[8];
  const float* cb2 = (const float*)d_in[9];
  const float* aW1 = (const float*)d_in[10];
  const float* ab1 = (const float*)d_in[11];
  const float* aW2 = (const float*)d_in[12];
  const float* ab2 = (const float*)d_in[13];

  char* w = (char*)d_ws;
  auto alloc = [&](size_t bytes) { char* p = w; w += bytes; return p; };
  float* S        = (float*)alloc(16777216);     // [64][256][256] f32
  ushort_t* Wsm   = (ushort_t*)alloc(8388608);   // [b][i][j] bf16
  ushort_t* Vsm   = (ushort_t*)alloc(8388608);   // [b][j][i] bf16
  ushort_t* T     = (ushort_t*)alloc(33554432);  // [b][h][pos] bf16
  ushort_t* X     = (ushort_t*)alloc(67108864);  // [16384][2048] = [emb | ctx]
  ushort_t* H1    = (ushort_t*)alloc(33554432);  // [16384][1024]
  ushort_t* H2    = (ushort_t*)alloc(33554432);  // [16384][1024]
  ushort_t* cW1T  = (ushort_t*)alloc(4194304);   // [1024][2048]
  ushort_t* cW2T  = (ushort_t*)alloc(2097152);   // [1024][1024]
  ushort_t* aW1Th = (ushort_t*)alloc(4194304);
  ushort_t* aW1Tl = (ushort_t*)alloc(4194304);
  float* partial  = (float*)alloc(4194304);      // [8][64][2048] f32
  ushort_t* poolh = (ushort_t*)alloc(262144);
  ushort_t* pooll = (ushort_t*)alloc(262144);
  float* z        = (float*)alloc(262144);       // [64][1024]
  uchar_t* premT  = (uchar_t*)alloc(16384);
  uchar_t* hypoT  = (uchar_t*)alloc(16384);

  prep_masks_kernel<<<1, 256, 0, stream>>>(prem, hypo, premT, hypoT);
  transpose_w_kernel<<<dim3(32, 16), 256, 0, stream>>>(cW1, cW1T, (ushort_t*)nullptr, 1024, 2048);
  transpose_w_kernel<<<dim3(16, 16), 256, 0, stream>>>(cW2, cW2T, (ushort_t*)nullptr, 1024, 1024);
  transpose_w_kernel<<<dim3(32, 16), 256, 0, stream>>>(aW1, aW1Th, aW1Tl, 1024, 2048);

  gemm_s_kernel<<<dim3(4, 4, 64), 256, 0, stream>>>(P_enc, H_enc, S);
  softmax_rows_kernel<<<4096, 256, 0, stream>>>(S, hypoT, Wsm);
  softmax_cols_kernel<<<dim3(8, 64), 256, 0, stream>>>(S, premT, Vsm);

  // ---- hypothesis side: H_ctx = P_attn^T @ P_emb, compare MLP, pool ----
  transpose_pos_h_kernel<<<dim3(4, 16, 64), 256, 0, stream>>>(P_emb, T);
  cast_half_kernel<<<8192, 256, 0, stream>>>(H_emb, X);
  gemm_ctx_kernel<<<dim3(2, 8, 64), 256, 0, stream>>>(Vsm, T, hypoT, X);
  gemm_mlp_kernel<<<dim3(128, 8), 256, 0, stream>>>(X, 2048, cW1T, 2048, cb1, H1, 2048);
  gemm_mlp_kernel<<<dim3(128, 8), 256, 0, stream>>>(H1, 1024, cW2T, 1024, cb2, H2, 1024);
  pool_partial_kernel<<<dim3(8, 64), 256, 0, stream>>>(H2, partial, 0);

  // ---- premise side: P_ctx = H_attn^T @ H_emb, compare MLP, pool ----
  transpose_pos_h_kernel<<<dim3(4, 16, 64), 256, 0, stream>>>(H_emb, T);
  cast_half_kernel<<<8192, 256, 0, stream>>>(P_emb, X);
  gemm_ctx_kernel<<<dim3(2, 8, 64), 256, 0, stream>>>(Wsm, T, premT, X);
  gemm_mlp_kernel<<<dim3(128, 8), 256, 0, stream>>>(X, 2048, cW1T, 2048, cb1, H1, 2048);
  gemm_mlp_kernel<<<dim3(128, 8), 256, 0, stream>>>(H1, 1024, cW2T, 1024, cb2, H2, 1024);
  pool_partial_kernel<<<dim3(8, 64), 256, 0, stream>>>(H2, partial, 1024);

  // ---- aggregation ----
  pool_final_kernel<<<512, 256, 0, stream>>>(partial, poolh, pooll);
  gemm_agg1_kernel<<<8, 256, 0, stream>>>(poolh, pooll, aW1Th, aW1Tl, ab1, z);
  agg2_kernel<<<64, 64, 0, stream>>>(z, aW2, ab2, (float*)d_out);
}

// Round 7
// 648.661 us; speedup vs baseline: 1.0214x; 1.0214x over previous
//
#include <hip/hip_runtime.h>
#include <cstdint>
#include <cstddef>

typedef unsigned short ushort_t;
typedef unsigned char uchar_t;
typedef __attribute__((ext_vector_type(4))) float f4;
typedef __attribute__((ext_vector_type(4))) unsigned int u4;
typedef __attribute__((ext_vector_type(2))) unsigned int u2;

#define DEVI static __device__ __forceinline__

DEVI ushort_t f2bf(float x) {
  union { float f; unsigned int u; } v; v.f = x;
  unsigned int r = v.u + 0x7fffu + ((v.u >> 16) & 1u);
  return (ushort_t)(r >> 16);
}
DEVI float bf2f(ushort_t b) {
  union { unsigned int u; float f; } v; v.u = ((unsigned int)b) << 16;
  return v.f;
}
DEVI unsigned pk2(ushort_t a, ushort_t b) { return (unsigned)a | ((unsigned)b << 16); }

DEVI void mfma16(f4& c, u4 a, u4 b) {
  asm("v_mfma_f32_16x16x32_bf16 %0, %1, %2, %0" : "+v"(c) : "v"(a), "v"(b));
}

constexpr int LDR = 40;  // padded LDS row stride (shorts) for reg-staged tiles

// --------------------------------------------------------------------------
// global_load_lds staging: bf16 tile [128 rows][32 cols], linear LDS layout.
// --------------------------------------------------------------------------
#if defined(__has_builtin)
#if __has_builtin(__builtin_amdgcn_global_load_lds)
#define HAS_GLD 1
#endif
#endif
#ifndef HAS_GLD
#define HAS_GLD 0
#endif

#if HAS_GLD
typedef const __attribute__((address_space(1))) unsigned int* gas1_t;
typedef __attribute__((address_space(3))) unsigned int* las3_t;
DEVI void gld16(const void* g, void* l) {
  __builtin_amdgcn_global_load_lds((gas1_t)g, (las3_t)l, 16, 0, 0);
}
#endif

// Stages rows 0..127, cols k0..k0+31 of src (row stride srcStride) into
// lT[128][32] linear. 2 vmcnt-ops/thread on the gld path.
DEVI void stage_tile(const ushort_t* __restrict__ src, int srcStride, int k0,
                     ushort_t* lT, int t) {
#if HAS_GLD
  int w = t >> 6, lane = t & 63;
#pragma unroll
  for (int c = 0; c < 2; ++c) {
    int row = c * 64 + w * 16 + (lane >> 2);
    const ushort_t* g = src + (size_t)row * srcStride + k0 + (lane & 3) * 8;
    gld16(g, lT + (c * 64 + w * 16) * 32);
  }
#else
  int row = t >> 1, kp = (t & 1) << 4;
  const ushort_t* g = src + (size_t)row * srcStride + k0 + kp;
  *(u4*)(lT + row * 32 + kp) = *(const u4*)g;
  *(u4*)(lT + row * 32 + kp + 8) = *(const u4*)(g + 8);
#endif
}

// fragment reads + 16 MFMA for the 128x128, 4-wave layout (linear [128][32] LDS)
DEVI void compute16(const ushort_t* lA, const ushort_t* lB, f4 acc[4][4],
                    int wr, int wc, int fr, int fg) {
  u4 af[4], bfv[4];
#pragma unroll
  for (int m = 0; m < 4; ++m) af[m] = *(const u4*)(lA + (wr + m * 16 + fr) * 32 + (fg << 3));
#pragma unroll
  for (int n = 0; n < 4; ++n) bfv[n] = *(const u4*)(lB + (wc + n * 16 + fr) * 32 + (fg << 3));
#pragma unroll
  for (int m = 0; m < 4; ++m)
#pragma unroll
    for (int n = 0; n < 4; ++n) mfma16(acc[m][n], af[m], bfv[n]);
}

// ---------------------------------------------------------------------------
// 3-deep pipelined GEMM core — byte-identical to the round-3 build that
// measured absmax 0.125 twice. Self-contained sync discipline (does NOT rely
// on __syncthreads draining vmcnt for global_load_lds):
//  R1 buf[t] ready before ds_read: vmcnt(4) waits stage(t); s_barrier makes
//     it workgroup-wide.
//  R2 stage(t+2) overwrites buf[(t-1)%3]: its readers drained lgkmcnt(0)
//     before their MFMA, before the barrier we just crossed.
//  R3 rule #18: sched_barrier(0) after lgkmcnt(0) so MFMA can't hoist.
// ---------------------------------------------------------------------------
#if HAS_GLD
DEVI void gemm_pipe(const ushort_t* __restrict__ A, int lda,
                    const ushort_t* __restrict__ B, int ldb, int K,
                    ushort_t* lab, f4 acc[4][4], int t, int wr, int wc,
                    int fr, int fg) {
  ushort_t* a0 = lab;             ushort_t* b0 = lab + 4096;
  ushort_t* a1 = lab + 2 * 4096;  ushort_t* b1 = lab + 3 * 4096;
  ushort_t* a2 = lab + 4 * 4096;  ushort_t* b2 = lab + 5 * 4096;
  const int nt = K >> 5;
  stage_tile(A, lda, 0, a0, t);
  stage_tile(B, ldb, 0, b0, t);
  stage_tile(A, lda, 32, a1, t);
  stage_tile(B, ldb, 32, b1, t);
  for (int tt = 0; tt < nt; ++tt) {
    if (tt + 1 < nt) asm volatile("s_waitcnt vmcnt(4)" ::: "memory");
    else             asm volatile("s_waitcnt vmcnt(0)" ::: "memory");
    asm volatile("s_barrier" ::: "memory");
    if (tt + 2 < nt) {
      stage_tile(A, lda, (tt + 2) << 5, a2, t);
      stage_tile(B, ldb, (tt + 2) << 5, b2, t);
    }
    u4 af[4], bfv[4];
#pragma unroll
    for (int m = 0; m < 4; ++m) af[m] = *(const u4*)(a0 + (wr + m * 16 + fr) * 32 + (fg << 3));
#pragma unroll
    for (int n = 0; n < 4; ++n) bfv[n] = *(const u4*)(b0 + (wc + n * 16 + fr) * 32 + (fg << 3));
    asm volatile("s_waitcnt lgkmcnt(0)" ::: "memory");
    __builtin_amdgcn_sched_barrier(0);
#pragma unroll
    for (int m = 0; m < 4; ++m)
#pragma unroll
      for (int n = 0; n < 4; ++n) mfma16(acc[m][n], af[m], bfv[n]);
    ushort_t* ta = a0; a0 = a1; a1 = a2; a2 = ta;
    ushort_t* tb = b0; b0 = b1; b1 = b2; b2 = tb;
  }
}
#else
// fallback: single-buffer 2-barrier (accuracy-clean class)
DEVI void gemm_pipe(const ushort_t* __restrict__ A, int lda,
                    const ushort_t* __restrict__ B, int ldb, int K,
                    ushort_t* lab, f4 acc[4][4], int t, int wr, int wc,
                    int fr, int fg) {
  ushort_t* a0 = lab;
  ushort_t* b0 = lab + 4096;
  const int nt = K >> 5;
  for (int tt = 0; tt < nt; ++tt) {
    __syncthreads();
    stage_tile(A, lda, tt << 5, a0, t);
    stage_tile(B, ldb, tt << 5, b0, t);
    __syncthreads();
    compute16(a0, b0, acc, wr, wc, fr, fg);
  }
}
#endif

// ---------------------------------------------------------------------------
// mask prep: detect uint8-bool vs int32 storage, write transposed [b][pos]
// ---------------------------------------------------------------------------
__global__ __launch_bounds__(256) void prep_masks_kernel(
    const uchar_t* __restrict__ prem, const uchar_t* __restrict__ hypo,
    uchar_t* __restrict__ premT, uchar_t* __restrict__ hypoT) {
  __shared__ int flagP, flagH;
  int t = threadIdx.x;
  if (t == 0) { flagP = 0; flagH = 0; }
  __syncthreads();
  int locP = 0, locH = 0;
  for (int i = t; i < 16384; i += 256) {
    if (i & 3) { locP |= prem[i]; locH |= hypo[i]; }
  }
  if (locP) atomicOr(&flagP, 1);
  if (locH) atomicOr(&flagH, 1);
  __syncthreads();
  bool p8 = flagP != 0, h8 = flagH != 0;  // true -> 1-byte bools
  for (int i = t; i < 16384; i += 256) {
    int p = i >> 6, b = i & 63;
    premT[b * 256 + p] = p8 ? prem[i] : prem[i * 4];
    hypoT[b * 256 + p] = h8 ? hypo[i] : hypo[i * 4];
  }
}

// ---------------------------------------------------------------------------
// weight transpose: f32 [K][N] -> bf16 [N][K] (optionally hi/lo split)
// ---------------------------------------------------------------------------
__global__ __launch_bounds__(256) void transpose_w_kernel(
    const float* __restrict__ Win, ushort_t* __restrict__ Thi,
    ushort_t* __restrict__ Tlo, int N, int K) {
  __shared__ float tl[64][65];
  int k0 = blockIdx.x * 64, n0 = blockIdx.y * 64;
  int t = threadIdx.x;
#pragma unroll
  for (int it = 0; it < 16; ++it) {
    int idx = t + it * 256;
    int k = idx >> 6, n = idx & 63;
    tl[n][k] = Win[(size_t)(k0 + k) * N + n0 + n];
  }
  __syncthreads();
#pragma unroll
  for (int it = 0; it < 16; ++it) {
    int idx = t + it * 256;
    int n = idx >> 6, k = idx & 63;
    float x = tl[n][k];
    ushort_t h = f2bf(x);
    Thi[(size_t)(n0 + n) * K + k0 + k] = h;
    if (Tlo) Tlo[(size_t)(n0 + n) * K + k0 + k] = f2bf(x - bf2f(h));
  }
}

// ---------------------------------------------------------------------------
// S GEMM, bf16x2 split, 64x64 tiles, dbuf single-barrier (ds_write staging
// only -> __syncthreads fully covers it; in the clean 0.125 build).
// grid 1024 (1-D, XCD-swizzled), block 256.
// ---------------------------------------------------------------------------
__global__ __launch_bounds__(256) void gemm_s_kernel(
    const float* __restrict__ Penc, const float* __restrict__ Henc,
    float* __restrict__ S) {
  __shared__ ushort_t lAh[2][64 * LDR], lAl[2][64 * LDR];
  __shared__ ushort_t lBh[2][64 * LDR], lBl[2][64 * LDR];
  const int t = threadIdx.x;
  const int bid = blockIdx.x;
  const int nw = (bid & 7) * 128 + (bid >> 3);  // bijective: 1024 = 8*128
  const int b = nw >> 4;
  const int local = nw & 15;
  const int i0 = (local & 3) * 64, j0 = (local >> 2) * 64;
  const int lda = 64 * 1024;
  const float* Ab = Penc + (size_t)i0 * lda + (size_t)b * 1024;
  const float* Bb = Henc + (size_t)j0 * lda + (size_t)b * 1024;
  const int lane = t & 63, wave = t >> 6;
  const int wr = (wave >> 1) << 5, wc = (wave & 1) << 5;
  const int fr = lane & 15, fg = lane >> 4;
  const int row = t >> 2, kp = (t & 3) << 3;

  f4 acc[2][2];
#pragma unroll
  for (int m = 0; m < 2; ++m)
#pragma unroll
    for (int n = 0; n < 2; ++n) acc[m][n] = f4{0.f, 0.f, 0.f, 0.f};

  auto stage = [&](int k0, int bi) {
    {
      const float* p = Ab + (size_t)row * lda + k0 + kp;
      f4 x0 = *(const f4*)p, x1 = *(const f4*)(p + 4);
      ushort_t hh[8], ll[8];
#pragma unroll
      for (int q = 0; q < 4; ++q) {
        ushort_t h0 = f2bf(x0[q]); hh[q] = h0; ll[q] = f2bf(x0[q] - bf2f(h0));
        ushort_t h1 = f2bf(x1[q]); hh[4 + q] = h1; ll[4 + q] = f2bf(x1[q] - bf2f(h1));
      }
      *(u4*)(lAh[bi] + row * LDR + kp) = u4{ pk2(hh[0], hh[1]), pk2(hh[2], hh[3]), pk2(hh[4], hh[5]), pk2(hh[6], hh[7]) };
      *(u4*)(lAl[bi] + row * LDR + kp) = u4{ pk2(ll[0], ll[1]), pk2(ll[2], ll[3]), pk2(ll[4], ll[5]), pk2(ll[6], ll[7]) };
    }
    {
      const float* p = Bb + (size_t)row * lda + k0 + kp;
      f4 x0 = *(const f4*)p, x1 = *(const f4*)(p + 4);
      ushort_t hh[8], ll[8];
#pragma unroll
      for (int q = 0; q < 4; ++q) {
        ushort_t h0 = f2bf(x0[q]); hh[q] = h0; ll[q] = f2bf(x0[q] - bf2f(h0));
        ushort_t h1 = f2bf(x1[q]); hh[4 + q] = h1; ll[4 + q] = f2bf(x1[q] - bf2f(h1));
      }
      *(u4*)(lBh[bi] + row * LDR + kp) = u4{ pk2(hh[0], hh[1]), pk2(hh[2], hh[3]), pk2(hh[4], hh[5]), pk2(hh[6], hh[7]) };
      *(u4*)(lBl[bi] + row * LDR + kp) = u4{ pk2(ll[0], ll[1]), pk2(ll[2], ll[3]), pk2(ll[4], ll[5]), pk2(ll[6], ll[7]) };
    }
  };

  stage(0, 0);
  __syncthreads();
  for (int tt = 0; tt < 32; ++tt) {
    int cur = tt & 1;
    if (tt + 1 < 32) stage((tt + 1) << 5, cur ^ 1);
    u4 ah[2], al[2], bh[2], bl[2];
#pragma unroll
    for (int m = 0; m < 2; ++m) {
      int off = (wr + m * 16 + fr) * LDR + (fg << 3);
      ah[m] = *(const u4*)(lAh[cur] + off);
      al[m] = *(const u4*)(lAl[cur] + off);
    }
#pragma unroll
    for (int n = 0; n < 2; ++n) {
      int off = (wc + n * 16 + fr) * LDR + (fg << 3);
      bh[n] = *(const u4*)(lBh[cur] + off);
      bl[n] = *(const u4*)(lBl[cur] + off);
    }
#pragma unroll
    for (int m = 0; m < 2; ++m)
#pragma unroll
      for (int n = 0; n < 2; ++n) {
        mfma16(acc[m][n], ah[m], bh[n]);
        mfma16(acc[m][n], ah[m], bl[n]);
        mfma16(acc[m][n], al[m], bh[n]);
      }
    __syncthreads();
  }

  float* Sb = S + (size_t)b * 65536;
#pragma unroll
  for (int m = 0; m < 2; ++m)
#pragma unroll
    for (int n = 0; n < 2; ++n)
#pragma unroll
      for (int r = 0; r < 4; ++r) {
        int rrow = i0 + wr + m * 16 + fg * 4 + r;
        int col = j0 + wc + n * 16 + fr;
        Sb[(size_t)rrow * 256 + col] = acc[m][n][r];
      }
}

// ---------------------------------------------------------------------------
// softmax over j (contiguous)
// ---------------------------------------------------------------------------
__global__ __launch_bounds__(256) void softmax_rows_kernel(
    const float* __restrict__ S, const uchar_t* __restrict__ hypoT,
    ushort_t* __restrict__ W) {
  int r = blockIdx.x * 4 + (threadIdx.x >> 6);
  int lane = threadIdx.x & 63;
  int b = r >> 8;
  const float* row = S + (size_t)r * 256;
  f4 x = *(const f4*)(row + lane * 4);
  const uchar_t* mp = hypoT + b * 256 + lane * 4;
  float v0 = mp[0] ? -1e30f : x[0];
  float v1 = mp[1] ? -1e30f : x[1];
  float v2 = mp[2] ? -1e30f : x[2];
  float v3 = mp[3] ? -1e30f : x[3];
  float m = fmaxf(fmaxf(v0, v1), fmaxf(v2, v3));
#pragma unroll
  for (int off = 32; off > 0; off >>= 1) m = fmaxf(m, __shfl_xor(m, off));
  float e0 = expf(v0 - m), e1 = expf(v1 - m), e2 = expf(v2 - m), e3 = expf(v3 - m);
  float s = e0 + e1 + e2 + e3;
#pragma unroll
  for (int off = 32; off > 0; off >>= 1) s += __shfl_xor(s, off);
  float rinv = 1.0f / s;
  ushort_t w0 = f2bf(e0 * rinv), w1 = f2bf(e1 * rinv), w2 = f2bf(e2 * rinv), w3 = f2bf(e3 * rinv);
  *(u2*)(W + (size_t)r * 256 + lane * 4) = u2{ pk2(w0, w1), pk2(w2, w3) };
}

// ---------------------------------------------------------------------------
// softmax over i (strided) + transpose: V[b][j][i]
// ---------------------------------------------------------------------------
__global__ __launch_bounds__(256) void softmax_cols_kernel(
    const float* __restrict__ S, const uchar_t* __restrict__ premT,
    ushort_t* __restrict__ V) {
  __shared__ float tl[32][257];
  __shared__ float pm[8][32], ps[8][32], mfin[32], rs[32];
  int t = threadIdx.x;
  int jl = t & 31, ig = t >> 5;
  int b = blockIdx.y, j0 = blockIdx.x * 32;
  const float* Sb = S + (size_t)b * 65536;
  const uchar_t* pmsk = premT + b * 256;
  for (int i = ig; i < 256; i += 8)
    tl[jl][i] = pmsk[i] ? -1e30f : Sb[(size_t)i * 256 + j0 + jl];
  __syncthreads();
  float m = -3e30f;
#pragma unroll 8
  for (int ii = 0; ii < 32; ++ii) m = fmaxf(m, tl[jl][ig * 32 + ii]);
  float s = 0.f;
#pragma unroll 8
  for (int ii = 0; ii < 32; ++ii) s += expf(tl[jl][ig * 32 + ii] - m);
  pm[ig][jl] = m; ps[ig][jl] = s;
  __syncthreads();
  if (t < 32) {
    float M = pm[0][t];
#pragma unroll
    for (int g = 1; g < 8; ++g) M = fmaxf(M, pm[g][t]);
    float ss = 0.f;
#pragma unroll
    for (int g = 0; g < 8; ++g) ss += ps[g][t] * expf(pm[g][t] - M);
    mfin[t] = M; rs[t] = 1.0f / ss;
  }
  __syncthreads();
  for (int j2 = 0; j2 < 32; ++j2) {
    float val = expf(tl[j2][t] - mfin[j2]) * rs[j2];
    V[((size_t)b * 256 + j0 + j2) * 256 + t] = f2bf(val);
  }
}

// ---------------------------------------------------------------------------
// emb transpose: E[pos][b][h] f32 -> T[b][h][pos] bf16
// ---------------------------------------------------------------------------
__global__ __launch_bounds__(256) void transpose_pos_h_kernel(
    const float* __restrict__ E, ushort_t* __restrict__ T) {
  __shared__ ushort_t tl[64][65];
  int i0 = blockIdx.x * 64, h0 = blockIdx.y * 64, b = blockIdx.z;
  int t = threadIdx.x;
#pragma unroll
  for (int it = 0; it < 16; ++it) {
    int idx = t + it * 256;
    int i = idx >> 6, h = idx & 63;
    tl[h][i] = f2bf(E[((size_t)(i0 + i) * 64 + b) * 1024 + h0 + h]);
  }
  __syncthreads();
#pragma unroll
  for (int it = 0; it < 16; ++it) {
    int idx = t + it * 256;
    int h = idx >> 6, i = idx & 63;
    T[((size_t)b * 1024 + h0 + h) * 256 + i0 + i] = tl[h][i];
  }
}

// ---------------------------------------------------------------------------
// cast f32 emb -> first half of X: X[(pos*64+b)][0:1024] = bf16(E). grid 8192
// ---------------------------------------------------------------------------
__global__ __launch_bounds__(256) void cast_half_kernel(
    const float* __restrict__ E, ushort_t* __restrict__ X) {
  size_t idx = (size_t)blockIdx.x * 256 + threadIdx.x;
  size_t r = idx >> 7;
  int h8 = ((int)idx & 127) << 3;
  const f4* p = (const f4*)(E + r * 1024 + h8);
  f4 a = p[0], c = p[1];
  ushort_t hh[8];
#pragma unroll
  for (int q = 0; q < 4; ++q) { hh[q] = f2bf(a[q]); hh[4 + q] = f2bf(c[q]); }
  *(u4*)(X + r * 2048 + h8) =
      u4{ pk2(hh[0], hh[1]), pk2(hh[2], hh[3]), pk2(hh[4], hh[5]), pk2(hh[6], hh[7]) };
}

// ---------------------------------------------------------------------------
// context GEMM (3-deep pipe, XCD-swizzled): grid 1024 (1-D), block 256
// ---------------------------------------------------------------------------
__global__ __launch_bounds__(256) void gemm_ctx_kernel(
    const ushort_t* __restrict__ Attn, const ushort_t* __restrict__ T,
    const uchar_t* __restrict__ maskT, ushort_t* __restrict__ X) {
  __shared__ ushort_t lab[6 * 4096];
  int t = threadIdx.x;
  int bid = blockIdx.x;
  int nw = (bid & 7) * 128 + (bid >> 3);  // bijective: 1024 = 8*128
  int b = nw >> 4;
  int local = nw & 15;
  int m0 = (local & 1) * 128, n0 = (local >> 1) * 128;
  const ushort_t* A = Attn + (size_t)b * 65536 + (size_t)m0 * 256;
  const ushort_t* B = T + (size_t)b * 262144 + (size_t)n0 * 256;
  int lane = t & 63, wave = t >> 6;
  int wr = (wave >> 1) << 6, wc = (wave & 1) << 6;
  int fr = lane & 15, fg = lane >> 4;
  f4 acc[4][4];
#pragma unroll
  for (int m = 0; m < 4; ++m)
#pragma unroll
    for (int n = 0; n < 4; ++n) acc[m][n] = f4{0.f, 0.f, 0.f, 0.f};
  gemm_pipe(A, 256, B, 256, 256, lab, acc, t, wr, wc, fr, fg);
#pragma unroll
  for (int m = 0; m < 4; ++m)
#pragma unroll
    for (int n = 0; n < 4; ++n)
#pragma unroll
      for (int r = 0; r < 4; ++r) {
        int gm = m0 + wr + m * 16 + fg * 4 + r;
        int gn = n0 + wc + n * 16 + fr;
        float v = maskT[b * 256 + gm] ? 0.f : acc[m][n][r];
        X[((size_t)gm * 64 + b) * 2048 + 1024 + gn] = f2bf(v);
      }
}

// ---------------------------------------------------------------------------
// MLP GEMM (3-deep pipe, XCD-swizzled): C = relu(A @ W^T + bias).
// grid 1024 (1-D), block 256.
// ---------------------------------------------------------------------------
__global__ __launch_bounds__(256) void gemm_mlp_kernel(
    const ushort_t* __restrict__ A, int lda, const ushort_t* __restrict__ W,
    int ldw, const float* __restrict__ bias, ushort_t* __restrict__ C, int K) {
  __shared__ ushort_t lab[6 * 4096];
  int t = threadIdx.x;
  int bid = blockIdx.x;
  int mt = (bid & 7) * 16 + ((bid >> 3) & 15);  // [0,128) bijective
  int nt = bid >> 7;                            // [0,8)
  int m0 = mt * 128, n0 = nt * 128;
  int lane = t & 63, wave = t >> 6;
  int wr = (wave >> 1) << 6, wc = (wave & 1) << 6;
  int fr = lane & 15, fg = lane >> 4;
  f4 acc[4][4];
#pragma unroll
  for (int m = 0; m < 4; ++m)
#pragma unroll
    for (int n = 0; n < 4; ++n) acc[m][n] = f4{0.f, 0.f, 0.f, 0.f};
  gemm_pipe(A + (size_t)m0 * lda, lda, W + (size_t)n0 * ldw, ldw, K,
            lab, acc, t, wr, wc, fr, fg);
#pragma unroll
  for (int m = 0; m < 4; ++m)
#pragma unroll
    for (int n = 0; n < 4; ++n)
#pragma unroll
      for (int r = 0; r < 4; ++r) {
        int gm = m0 + wr + m * 16 + fg * 4 + r;
        int gn = n0 + wc + n * 16 + fr;
        float v = acc[m][n][r] + bias[gn];
        v = v > 0.f ? v : 0.f;
        C[(size_t)gm * 1024 + gn] = f2bf(v);
      }
}

// ---------------------------------------------------------------------------
// pool partial: partial[jc][b][coff+n] = sum_{j in chunk} H2[(j*64+b)][n]
// ---------------------------------------------------------------------------
__global__ __launch_bounds__(256) void pool_partial_kernel(
    const ushort_t* __restrict__ H2, float* __restrict__ partial, int coff) {
  int jc = blockIdx.x, b = blockIdx.y, t = threadIdx.x;
  float a0 = 0.f, a1 = 0.f, a2 = 0.f, a3 = 0.f;
  for (int j = jc * 32; j < jc * 32 + 32; ++j) {
    u2 v = *(const u2*)(H2 + ((size_t)(j * 64 + b)) * 1024 + t * 4);
    a0 += bf2f((ushort_t)(v[0] & 0xffff));
    a1 += bf2f((ushort_t)(v[0] >> 16));
    a2 += bf2f((ushort_t)(v[1] & 0xffff));
    a3 += bf2f((ushort_t)(v[1] >> 16));
  }
  *(f4*)(partial + ((size_t)(jc * 64 + b)) * 2048 + coff + t * 4) = f4{a0, a1, a2, a3};
}

// ---------------------------------------------------------------------------
// pool final + hi/lo split. grid 512, block 256
// ---------------------------------------------------------------------------
__global__ __launch_bounds__(256) void pool_final_kernel(
    const float* __restrict__ partial, ushort_t* __restrict__ ph,
    ushort_t* __restrict__ pl) {
  int idx = blockIdx.x * 256 + threadIdx.x;
  int b = idx >> 11, k = idx & 2047;
  float s = 0.f;
#pragma unroll
  for (int jc = 0; jc < 8; ++jc) s += partial[((size_t)(jc * 64 + b)) * 2048 + k];
  ushort_t h = f2bf(s);
  ph[idx] = h;
  pl[idx] = f2bf(s - bf2f(h));
}

// ---------------------------------------------------------------------------
// agg layer 1 (split bf16x2)
// ---------------------------------------------------------------------------
__global__ __launch_bounds__(256) void gemm_agg1_kernel(
    const ushort_t* __restrict__ Ph, const ushort_t* __restrict__ Pl,
    const ushort_t* __restrict__ Wh, const ushort_t* __restrict__ Wl,
    const float* __restrict__ bias, float* __restrict__ z) {
  __shared__ ushort_t lAh[64 * LDR], lAl[64 * LDR], lBh[128 * LDR], lBl[128 * LDR];
  int t = threadIdx.x;
  int n0 = blockIdx.x * 128;
  int lane = t & 63, wave = t >> 6;
  int wc = wave * 32;
  int fr = lane & 15, fg = lane >> 4;
  f4 acc[4][2];
#pragma unroll
  for (int m = 0; m < 4; ++m)
#pragma unroll
    for (int n = 0; n < 2; ++n) acc[m][n] = f4{0.f, 0.f, 0.f, 0.f};

  for (int k0 = 0; k0 < 2048; k0 += 32) {
    __syncthreads();
    {
      int row = t >> 2, kp = (t & 3) << 3;
      *(u4*)(lAh + row * LDR + kp) = *(const u4*)(Ph + (size_t)row * 2048 + k0 + kp);
      *(u4*)(lAl + row * LDR + kp) = *(const u4*)(Pl + (size_t)row * 2048 + k0 + kp);
    }
#pragma unroll
    for (int c = 0; c < 2; ++c) {
      int ch = t + (c << 8);
      int row = ch >> 2, kp = (ch & 3) << 3;
      *(u4*)(lBh + row * LDR + kp) = *(const u4*)(Wh + (size_t)(n0 + row) * 2048 + k0 + kp);
      *(u4*)(lBl + row * LDR + kp) = *(const u4*)(Wl + (size_t)(n0 + row) * 2048 + k0 + kp);
    }
    __syncthreads();
    u4 ah[4], al[4], bh[2], bl[2];
#pragma unroll
    for (int m = 0; m < 4; ++m) {
      int off = (m * 16 + fr) * LDR + (fg << 3);
      ah[m] = *(const u4*)(lAh + off);
      al[m] = *(const u4*)(lAl + off);
    }
#pragma unroll
    for (int n = 0; n < 2; ++n) {
      int off = (wc + n * 16 + fr) * LDR + (fg << 3);
      bh[n] = *(const u4*)(lBh + off);
      bl[n] = *(const u4*)(lBl + off);
    }
#pragma unroll
    for (int m = 0; m < 4; ++m)
#pragma unroll
      for (int n = 0; n < 2; ++n) {
        mfma16(acc[m][n], ah[m], bh[n]);
        mfma16(acc[m][n], ah[m], bl[n]);
        mfma16(acc[m][n], al[m], bh[n]);
      }
  }
#pragma unroll
  for (int m = 0; m < 4; ++m)
#pragma unroll
    for (int n = 0; n < 2; ++n)
#pragma unroll
      for (int r = 0; r < 4; ++r) {
        int row = m * 16 + fg * 4 + r;  // b
        int col = n0 + wc + n * 16 + fr;
        float v = acc[m][n][r] + bias[col];
        z[row * 1024 + col] = v > 0.f ? v : 0.f;
      }
}

// ---------------------------------------------------------------------------
// agg layer 2
// ---------------------------------------------------------------------------
__global__ __launch_bounds__(64) void agg2_kernel(
    const float* __restrict__ z, const float* __restrict__ aW2,
    const float* __restrict__ ab2, float* __restrict__ out) {
  int b = blockIdx.x, lane = threadIdx.x;
  float a0 = 0.f, a1 = 0.f, a2 = 0.f;
  for (int k = lane; k < 1024; k += 64) {
    float zv = z[b * 1024 + k];
    a0 += zv * aW2[k * 3 + 0];
    a1 += zv * aW2[k * 3 + 1];
    a2 += zv * aW2[k * 3 + 2];
  }
#pragma unroll
  for (int off = 32; off > 0; off >>= 1) {
    a0 += __shfl_xor(a0, off);
    a1 += __shfl_xor(a1, off);
    a2 += __shfl_xor(a2, off);
  }
  if (lane == 0) {
    out[b * 3 + 0] = a0 + ab2[0];
    out[b * 3 + 1] = a1 + ab2[1];
    out[b * 3 + 2] = a2 + ab2[2];
  }
}

// ---------------------------------------------------------------------------
extern "C" void kernel_launch(void* const* d_in, const int* in_sizes, int n_in,
                              void* d_out, int out_size, void* d_ws, size_t ws_size,
                              hipStream_t stream) {
  const float* P_enc = (const float*)d_in[0];
  const float* H_enc = (const float*)d_in[1];
  const float* P_emb = (const float*)d_in[2];
  const float* H_emb = (const float*)d_in[3];
  const uchar_t* prem = (const uchar_t*)d_in[4];
  const uchar_t* hypo = (const uchar_t*)d_in[5];
  const float* cW1 = (const float*)d_in[6];
  const float* cb1 = (const float*)d_in[7];
  const float* cW2 = (const float*)d_in[8];
  const float* cb2 = (const float*)d_in[9];
  const float* aW1 = (const float*)d_in[10];
  const float* ab1 = (const float*)d_in[11];
  const float* aW2 = (const float*)d_in[12];
  const float* ab2 = (const float*)d_in[13];

  char* w = (char*)d_ws;
  auto alloc = [&](size_t bytes) { char* p = w; w += bytes; return p; };
  float* S        = (float*)alloc(16777216);     // [64][256][256] f32
  ushort_t* Wsm   = (ushort_t*)alloc(8388608);   // [b][i][j] bf16
  ushort_t* Vsm   = (ushort_t*)alloc(8388608);   // [b][j][i] bf16
  ushort_t* T     = (ushort_t*)alloc(33554432);  // [b][h][pos] bf16
  ushort_t* X     = (ushort_t*)alloc(67108864);  // [16384][2048] = [emb | ctx]
  ushort_t* H1    = (ushort_t*)alloc(33554432);  // [16384][1024]
  ushort_t* H2    = (ushort_t*)alloc(33554432);  // [16384][1024]
  ushort_t* cW1T  = (ushort_t*)alloc(4194304);   // [1024][2048]
  ushort_t* cW2T  = (ushort_t*)alloc(2097152);   // [1024][1024]
  ushort_t* aW1Th = (ushort_t*)alloc(4194304);
  ushort_t* aW1Tl = (ushort_t*)alloc(4194304);
  float* partial  = (float*)alloc(4194304);      // [8][64][2048] f32
  ushort_t* poolh = (ushort_t*)alloc(262144);
  ushort_t* pooll = (ushort_t*)alloc(262144);
  float* z        = (float*)alloc(262144);       // [64][1024]
  uchar_t* premT  = (uchar_t*)alloc(16384);
  uchar_t* hypoT  = (uchar_t*)alloc(16384);

  prep_masks_kernel<<<1, 256, 0, stream>>>(prem, hypo, premT, hypoT);
  transpose_w_kernel<<<dim3(32, 16), 256, 0, stream>>>(cW1, cW1T, (ushort_t*)nullptr, 1024, 2048);
  transpose_w_kernel<<<dim3(16, 16), 256, 0, stream>>>(cW2, cW2T, (ushort_t*)nullptr, 1024, 1024);
  transpose_w_kernel<<<dim3(32, 16), 256, 0, stream>>>(aW1, aW1Th, aW1Tl, 1024, 2048);

  gemm_s_kernel<<<1024, 256, 0, stream>>>(P_enc, H_enc, S);
  softmax_rows_kernel<<<4096, 256, 0, stream>>>(S, hypoT, Wsm);
  softmax_cols_kernel<<<dim3(8, 64), 256, 0, stream>>>(S, premT, Vsm);

  // ---- hypothesis side: H_ctx = P_attn^T @ P_emb, compare MLP, pool ----
  transpose_pos_h_kernel<<<dim3(4, 16, 64), 256, 0, stream>>>(P_emb, T);
  cast_half_kernel<<<8192, 256, 0, stream>>>(H_emb, X);
  gemm_ctx_kernel<<<1024, 256, 0, stream>>>(Vsm, T, hypoT, X);
  gemm_mlp_kernel<<<1024, 256, 0, stream>>>(X, 2048, cW1T, 2048, cb1, H1, 2048);
  gemm_mlp_kernel<<<1024, 256, 0, stream>>>(H1, 1024, cW2T, 1024, cb2, H2, 1024);
  pool_partial_kernel<<<dim3(8, 64), 256, 0, stream>>>(H2, partial, 0);

  // ---- premise side: P_ctx = H_attn^T @ H_emb, compare MLP, pool ----
  transpose_pos_h_kernel<<<dim3(4, 16, 64), 256, 0, stream>>>(H_emb, T);
  cast_half_kernel<<<8192, 256, 0, stream>>>(P_emb, X);
  gemm_ctx_kernel<<<1024, 256, 0, stream>>>(Wsm, T, premT, X);
  gemm_mlp_kernel<<<1024, 256, 0, stream>>>(X, 2048, cW1T, 2048, cb1, H1, 2048);
  gemm_mlp_kernel<<<1024, 256, 0, stream>>>(H1, 1024, cW2T, 1024, cb2, H2, 1024);
  pool_partial_kernel<<<dim3(8, 64), 256, 0, stream>>>(H2, partial, 1024);

  // ---- aggregation ----
  pool_final_kernel<<<512, 256, 0, stream>>>(partial, poolh, pooll);
  gemm_agg1_kernel<<<8, 256, 0, stream>>>(poolh, pooll, aW1Th, aW1Tl, ab1, z);
  agg2_kernel<<<64, 64, 0, stream>>>(z, aW2, ab2, (float*)d_out);
}

// Round 8
// 632.427 us; speedup vs baseline: 1.0477x; 1.0257x over previous
//
#include <hip/hip_runtime.h>
#include <cstdint>
#include <cstddef>

typedef unsigned short ushort_t;
typedef unsigned char uchar_t;
typedef __attribute__((ext_vector_type(4))) float f4;
typedef __attribute__((ext_vector_type(4))) unsigned int u4;
typedef __attribute__((ext_vector_type(2))) unsigned int u2;

#define DEVI static __device__ __forceinline__

DEVI ushort_t f2bf(float x) {
  union { float f; unsigned int u; } v; v.f = x;
  unsigned int r = v.u + 0x7fffu + ((v.u >> 16) & 1u);
  return (ushort_t)(r >> 16);
}
DEVI float bf2f(ushort_t b) {
  union { unsigned int u; float f; } v; v.u = ((unsigned int)b) << 16;
  return v.f;
}
DEVI unsigned pk2(ushort_t a, ushort_t b) { return (unsigned)a | ((unsigned)b << 16); }

DEVI void mfma16(f4& c, u4 a, u4 b) {
  asm("v_mfma_f32_16x16x32_bf16 %0, %1, %2, %0" : "+v"(c) : "v"(a), "v"(b));
}

constexpr int LDR = 40;  // padded LDS row stride (shorts) for reg-staged tiles

// --------------------------------------------------------------------------
// global_load_lds staging: bf16 tile [128 rows][32 cols], linear LDS layout.
// --------------------------------------------------------------------------
#if defined(__has_builtin)
#if __has_builtin(__builtin_amdgcn_global_load_lds)
#define HAS_GLD 1
#endif
#endif
#ifndef HAS_GLD
#define HAS_GLD 0
#endif

#if HAS_GLD
typedef const __attribute__((address_space(1))) unsigned int* gas1_t;
typedef __attribute__((address_space(3))) unsigned int* las3_t;
DEVI void gld16(const void* g, void* l) {
  __builtin_amdgcn_global_load_lds((gas1_t)g, (las3_t)l, 16, 0, 0);
}
#endif

// Stages rows 0..127, cols k0..k0+31 of src (row stride srcStride) into
// lT[128][32] linear. 2 vmcnt-ops/thread on the gld path.
DEVI void stage_tile(const ushort_t* __restrict__ src, int srcStride, int k0,
                     ushort_t* lT, int t) {
#if HAS_GLD
  int w = t >> 6, lane = t & 63;
#pragma unroll
  for (int c = 0; c < 2; ++c) {
    int row = c * 64 + w * 16 + (lane >> 2);
    const ushort_t* g = src + (size_t)row * srcStride + k0 + (lane & 3) * 8;
    gld16(g, lT + (c * 64 + w * 16) * 32);
  }
#else
  int row = t >> 1, kp = (t & 1) << 4;
  const ushort_t* g = src + (size_t)row * srcStride + k0 + kp;
  *(u4*)(lT + row * 32 + kp) = *(const u4*)g;
  *(u4*)(lT + row * 32 + kp + 8) = *(const u4*)(g + 8);
#endif
}

// fragment reads + 16 MFMA for the 128x128, 4-wave layout (linear [128][32] LDS)
DEVI void compute16(const ushort_t* lA, const ushort_t* lB, f4 acc[4][4],
                    int wr, int wc, int fr, int fg) {
  u4 af[4], bfv[4];
#pragma unroll
  for (int m = 0; m < 4; ++m) af[m] = *(const u4*)(lA + (wr + m * 16 + fr) * 32 + (fg << 3));
#pragma unroll
  for (int n = 0; n < 4; ++n) bfv[n] = *(const u4*)(lB + (wc + n * 16 + fr) * 32 + (fg << 3));
#pragma unroll
  for (int m = 0; m < 4; ++m)
#pragma unroll
    for (int n = 0; n < 4; ++n) mfma16(acc[m][n], af[m], bfv[n]);
}

// ---------------------------------------------------------------------------
// Depth-2 explicit-sync pipelined GEMM core: round-3's occupancy (32 KB LDS,
// 5 blk/CU) + round-7's proven sync discipline. Race ledger:
//  R1 buf[t] ready before ds_read: vmcnt(0) at top covers stage(t) (stage(t+1)
//     not yet issued); s_barrier makes it workgroup-wide.
//  R2 stage(t+1) overwrites buf[t^1]: its readers (iter t-1) drained
//     lgkmcnt(0) before their MFMA, then crossed THIS barrier. Issue AFTER
//     the barrier.
//  R3 rule #18: sched_barrier(0) after lgkmcnt(0) so MFMA can't hoist above
//     the ds_read drain.
// Strictly conservative vs the depth-3 variant (vmcnt(0) >= vmcnt(4));
// accumulation order identical -> bit-identical results.
// ---------------------------------------------------------------------------
#if HAS_GLD
DEVI void gemm_pipe(const ushort_t* __restrict__ A, int lda,
                    const ushort_t* __restrict__ B, int ldb, int K,
                    ushort_t* lab, f4 acc[4][4], int t, int wr, int wc,
                    int fr, int fg) {
  ushort_t* a0 = lab;             ushort_t* b0 = lab + 4096;
  ushort_t* a1 = lab + 2 * 4096;  ushort_t* b1 = lab + 3 * 4096;
  const int nt = K >> 5;
  stage_tile(A, lda, 0, a0, t);
  stage_tile(B, ldb, 0, b0, t);
  for (int tt = 0; tt < nt; ++tt) {
    asm volatile("s_waitcnt vmcnt(0)" ::: "memory");
    asm volatile("s_barrier" ::: "memory");
    if (tt + 1 < nt) {
      stage_tile(A, lda, (tt + 1) << 5, a1, t);
      stage_tile(B, ldb, (tt + 1) << 5, b1, t);
    }
    u4 af[4], bfv[4];
#pragma unroll
    for (int m = 0; m < 4; ++m) af[m] = *(const u4*)(a0 + (wr + m * 16 + fr) * 32 + (fg << 3));
#pragma unroll
    for (int n = 0; n < 4; ++n) bfv[n] = *(const u4*)(b0 + (wc + n * 16 + fr) * 32 + (fg << 3));
    asm volatile("s_waitcnt lgkmcnt(0)" ::: "memory");
    __builtin_amdgcn_sched_barrier(0);
#pragma unroll
    for (int m = 0; m < 4; ++m)
#pragma unroll
      for (int n = 0; n < 4; ++n) mfma16(acc[m][n], af[m], bfv[n]);
    ushort_t* ta = a0; a0 = a1; a1 = ta;
    ushort_t* tb = b0; b0 = b1; b1 = tb;
  }
}
#else
// fallback: single-buffer 2-barrier (accuracy-clean class)
DEVI void gemm_pipe(const ushort_t* __restrict__ A, int lda,
                    const ushort_t* __restrict__ B, int ldb, int K,
                    ushort_t* lab, f4 acc[4][4], int t, int wr, int wc,
                    int fr, int fg) {
  ushort_t* a0 = lab;
  ushort_t* b0 = lab + 4096;
  const int nt = K >> 5;
  for (int tt = 0; tt < nt; ++tt) {
    __syncthreads();
    stage_tile(A, lda, tt << 5, a0, t);
    stage_tile(B, ldb, tt << 5, b0, t);
    __syncthreads();
    compute16(a0, b0, acc, wr, wc, fr, fg);
  }
}
#endif

// ---------------------------------------------------------------------------
// mask prep: detect uint8-bool vs int32 storage, write transposed [b][pos]
// ---------------------------------------------------------------------------
__global__ __launch_bounds__(256) void prep_masks_kernel(
    const uchar_t* __restrict__ prem, const uchar_t* __restrict__ hypo,
    uchar_t* __restrict__ premT, uchar_t* __restrict__ hypoT) {
  __shared__ int flagP, flagH;
  int t = threadIdx.x;
  if (t == 0) { flagP = 0; flagH = 0; }
  __syncthreads();
  int locP = 0, locH = 0;
  for (int i = t; i < 16384; i += 256) {
    if (i & 3) { locP |= prem[i]; locH |= hypo[i]; }
  }
  if (locP) atomicOr(&flagP, 1);
  if (locH) atomicOr(&flagH, 1);
  __syncthreads();
  bool p8 = flagP != 0, h8 = flagH != 0;  // true -> 1-byte bools
  for (int i = t; i < 16384; i += 256) {
    int p = i >> 6, b = i & 63;
    premT[b * 256 + p] = p8 ? prem[i] : prem[i * 4];
    hypoT[b * 256 + p] = h8 ? hypo[i] : hypo[i * 4];
  }
}

// ---------------------------------------------------------------------------
// weight transpose: f32 [K][N] -> bf16 [N][K] (optionally hi/lo split)
// ---------------------------------------------------------------------------
__global__ __launch_bounds__(256) void transpose_w_kernel(
    const float* __restrict__ Win, ushort_t* __restrict__ Thi,
    ushort_t* __restrict__ Tlo, int N, int K) {
  __shared__ float tl[64][65];
  int k0 = blockIdx.x * 64, n0 = blockIdx.y * 64;
  int t = threadIdx.x;
#pragma unroll
  for (int it = 0; it < 16; ++it) {
    int idx = t + it * 256;
    int k = idx >> 6, n = idx & 63;
    tl[n][k] = Win[(size_t)(k0 + k) * N + n0 + n];
  }
  __syncthreads();
#pragma unroll
  for (int it = 0; it < 16; ++it) {
    int idx = t + it * 256;
    int n = idx >> 6, k = idx & 63;
    float x = tl[n][k];
    ushort_t h = f2bf(x);
    Thi[(size_t)(n0 + n) * K + k0 + k] = h;
    if (Tlo) Tlo[(size_t)(n0 + n) * K + k0 + k] = f2bf(x - bf2f(h));
  }
}

// ---------------------------------------------------------------------------
// S GEMM, bf16x2 split, 64x64 tiles, dbuf single-barrier (ds_write staging
// only -> __syncthreads fully covers it; in the clean 0.125 build).
// grid 1024 (1-D, XCD-swizzled), block 256.
// ---------------------------------------------------------------------------
__global__ __launch_bounds__(256) void gemm_s_kernel(
    const float* __restrict__ Penc, const float* __restrict__ Henc,
    float* __restrict__ S) {
  __shared__ ushort_t lAh[2][64 * LDR], lAl[2][64 * LDR];
  __shared__ ushort_t lBh[2][64 * LDR], lBl[2][64 * LDR];
  const int t = threadIdx.x;
  const int bid = blockIdx.x;
  const int nw = (bid & 7) * 128 + (bid >> 3);  // bijective: 1024 = 8*128
  const int b = nw >> 4;
  const int local = nw & 15;
  const int i0 = (local & 3) * 64, j0 = (local >> 2) * 64;
  const int lda = 64 * 1024;
  const float* Ab = Penc + (size_t)i0 * lda + (size_t)b * 1024;
  const float* Bb = Henc + (size_t)j0 * lda + (size_t)b * 1024;
  const int lane = t & 63, wave = t >> 6;
  const int wr = (wave >> 1) << 5, wc = (wave & 1) << 5;
  const int fr = lane & 15, fg = lane >> 4;
  const int row = t >> 2, kp = (t & 3) << 3;

  f4 acc[2][2];
#pragma unroll
  for (int m = 0; m < 2; ++m)
#pragma unroll
    for (int n = 0; n < 2; ++n) acc[m][n] = f4{0.f, 0.f, 0.f, 0.f};

  auto stage = [&](int k0, int bi) {
    {
      const float* p = Ab + (size_t)row * lda + k0 + kp;
      f4 x0 = *(const f4*)p, x1 = *(const f4*)(p + 4);
      ushort_t hh[8], ll[8];
#pragma unroll
      for (int q = 0; q < 4; ++q) {
        ushort_t h0 = f2bf(x0[q]); hh[q] = h0; ll[q] = f2bf(x0[q] - bf2f(h0));
        ushort_t h1 = f2bf(x1[q]); hh[4 + q] = h1; ll[4 + q] = f2bf(x1[q] - bf2f(h1));
      }
      *(u4*)(lAh[bi] + row * LDR + kp) = u4{ pk2(hh[0], hh[1]), pk2(hh[2], hh[3]), pk2(hh[4], hh[5]), pk2(hh[6], hh[7]) };
      *(u4*)(lAl[bi] + row * LDR + kp) = u4{ pk2(ll[0], ll[1]), pk2(ll[2], ll[3]), pk2(ll[4], ll[5]), pk2(ll[6], ll[7]) };
    }
    {
      const float* p = Bb + (size_t)row * lda + k0 + kp;
      f4 x0 = *(const f4*)p, x1 = *(const f4*)(p + 4);
      ushort_t hh[8], ll[8];
#pragma unroll
      for (int q = 0; q < 4; ++q) {
        ushort_t h0 = f2bf(x0[q]); hh[q] = h0; ll[q] = f2bf(x0[q] - bf2f(h0));
        ushort_t h1 = f2bf(x1[q]); hh[4 + q] = h1; ll[4 + q] = f2bf(x1[q] - bf2f(h1));
      }
      *(u4*)(lBh[bi] + row * LDR + kp) = u4{ pk2(hh[0], hh[1]), pk2(hh[2], hh[3]), pk2(hh[4], hh[5]), pk2(hh[6], hh[7]) };
      *(u4*)(lBl[bi] + row * LDR + kp) = u4{ pk2(ll[0], ll[1]), pk2(ll[2], ll[3]), pk2(ll[4], ll[5]), pk2(ll[6], ll[7]) };
    }
  };

  stage(0, 0);
  __syncthreads();
  for (int tt = 0; tt < 32; ++tt) {
    int cur = tt & 1;
    if (tt + 1 < 32) stage((tt + 1) << 5, cur ^ 1);
    u4 ah[2], al[2], bh[2], bl[2];
#pragma unroll
    for (int m = 0; m < 2; ++m) {
      int off = (wr + m * 16 + fr) * LDR + (fg << 3);
      ah[m] = *(const u4*)(lAh[cur] + off);
      al[m] = *(const u4*)(lAl[cur] + off);
    }
#pragma unroll
    for (int n = 0; n < 2; ++n) {
      int off = (wc + n * 16 + fr) * LDR + (fg << 3);
      bh[n] = *(const u4*)(lBh[cur] + off);
      bl[n] = *(const u4*)(lBl[cur] + off);
    }
#pragma unroll
    for (int m = 0; m < 2; ++m)
#pragma unroll
      for (int n = 0; n < 2; ++n) {
        mfma16(acc[m][n], ah[m], bh[n]);
        mfma16(acc[m][n], ah[m], bl[n]);
        mfma16(acc[m][n], al[m], bh[n]);
      }
    __syncthreads();
  }

  float* Sb = S + (size_t)b * 65536;
#pragma unroll
  for (int m = 0; m < 2; ++m)
#pragma unroll
    for (int n = 0; n < 2; ++n)
#pragma unroll
      for (int r = 0; r < 4; ++r) {
        int rrow = i0 + wr + m * 16 + fg * 4 + r;
        int col = j0 + wc + n * 16 + fr;
        Sb[(size_t)rrow * 256 + col] = acc[m][n][r];
      }
}

// ---------------------------------------------------------------------------
// softmax over j (contiguous)
// ---------------------------------------------------------------------------
__global__ __launch_bounds__(256) void softmax_rows_kernel(
    const float* __restrict__ S, const uchar_t* __restrict__ hypoT,
    ushort_t* __restrict__ W) {
  int r = blockIdx.x * 4 + (threadIdx.x >> 6);
  int lane = threadIdx.x & 63;
  int b = r >> 8;
  const float* row = S + (size_t)r * 256;
  f4 x = *(const f4*)(row + lane * 4);
  const uchar_t* mp = hypoT + b * 256 + lane * 4;
  float v0 = mp[0] ? -1e30f : x[0];
  float v1 = mp[1] ? -1e30f : x[1];
  float v2 = mp[2] ? -1e30f : x[2];
  float v3 = mp[3] ? -1e30f : x[3];
  float m = fmaxf(fmaxf(v0, v1), fmaxf(v2, v3));
#pragma unroll
  for (int off = 32; off > 0; off >>= 1) m = fmaxf(m, __shfl_xor(m, off));
  float e0 = expf(v0 - m), e1 = expf(v1 - m), e2 = expf(v2 - m), e3 = expf(v3 - m);
  float s = e0 + e1 + e2 + e3;
#pragma unroll
  for (int off = 32; off > 0; off >>= 1) s += __shfl_xor(s, off);
  float rinv = 1.0f / s;
  ushort_t w0 = f2bf(e0 * rinv), w1 = f2bf(e1 * rinv), w2 = f2bf(e2 * rinv), w3 = f2bf(e3 * rinv);
  *(u2*)(W + (size_t)r * 256 + lane * 4) = u2{ pk2(w0, w1), pk2(w2, w3) };
}

// ---------------------------------------------------------------------------
// softmax over i (strided) + transpose: V[b][j][i]
// ---------------------------------------------------------------------------
__global__ __launch_bounds__(256) void softmax_cols_kernel(
    const float* __restrict__ S, const uchar_t* __restrict__ premT,
    ushort_t* __restrict__ V) {
  __shared__ float tl[32][257];
  __shared__ float pm[8][32], ps[8][32], mfin[32], rs[32];
  int t = threadIdx.x;
  int jl = t & 31, ig = t >> 5;
  int b = blockIdx.y, j0 = blockIdx.x * 32;
  const float* Sb = S + (size_t)b * 65536;
  const uchar_t* pmsk = premT + b * 256;
  for (int i = ig; i < 256; i += 8)
    tl[jl][i] = pmsk[i] ? -1e30f : Sb[(size_t)i * 256 + j0 + jl];
  __syncthreads();
  float m = -3e30f;
#pragma unroll 8
  for (int ii = 0; ii < 32; ++ii) m = fmaxf(m, tl[jl][ig * 32 + ii]);
  float s = 0.f;
#pragma unroll 8
  for (int ii = 0; ii < 32; ++ii) s += expf(tl[jl][ig * 32 + ii] - m);
  pm[ig][jl] = m; ps[ig][jl] = s;
  __syncthreads();
  if (t < 32) {
    float M = pm[0][t];
#pragma unroll
    for (int g = 1; g < 8; ++g) M = fmaxf(M, pm[g][t]);
    float ss = 0.f;
#pragma unroll
    for (int g = 0; g < 8; ++g) ss += ps[g][t] * expf(pm[g][t] - M);
    mfin[t] = M; rs[t] = 1.0f / ss;
  }
  __syncthreads();
  for (int j2 = 0; j2 < 32; ++j2) {
    float val = expf(tl[j2][t] - mfin[j2]) * rs[j2];
    V[((size_t)b * 256 + j0 + j2) * 256 + t] = f2bf(val);
  }
}

// ---------------------------------------------------------------------------
// emb transpose: E[pos][b][h] f32 -> T[b][h][pos] bf16
// ---------------------------------------------------------------------------
__global__ __launch_bounds__(256) void transpose_pos_h_kernel(
    const float* __restrict__ E, ushort_t* __restrict__ T) {
  __shared__ ushort_t tl[64][65];
  int i0 = blockIdx.x * 64, h0 = blockIdx.y * 64, b = blockIdx.z;
  int t = threadIdx.x;
#pragma unroll
  for (int it = 0; it < 16; ++it) {
    int idx = t + it * 256;
    int i = idx >> 6, h = idx & 63;
    tl[h][i] = f2bf(E[((size_t)(i0 + i) * 64 + b) * 1024 + h0 + h]);
  }
  __syncthreads();
#pragma unroll
  for (int it = 0; it < 16; ++it) {
    int idx = t + it * 256;
    int h = idx >> 6, i = idx & 63;
    T[((size_t)b * 1024 + h0 + h) * 256 + i0 + i] = tl[h][i];
  }
}

// ---------------------------------------------------------------------------
// cast f32 emb -> first half of X: X[(pos*64+b)][0:1024] = bf16(E). grid 8192
// ---------------------------------------------------------------------------
__global__ __launch_bounds__(256) void cast_half_kernel(
    const float* __restrict__ E, ushort_t* __restrict__ X) {
  size_t idx = (size_t)blockIdx.x * 256 + threadIdx.x;
  size_t r = idx >> 7;
  int h8 = ((int)idx & 127) << 3;
  const f4* p = (const f4*)(E + r * 1024 + h8);
  f4 a = p[0], c = p[1];
  ushort_t hh[8];
#pragma unroll
  for (int q = 0; q < 4; ++q) { hh[q] = f2bf(a[q]); hh[4 + q] = f2bf(c[q]); }
  *(u4*)(X + r * 2048 + h8) =
      u4{ pk2(hh[0], hh[1]), pk2(hh[2], hh[3]), pk2(hh[4], hh[5]), pk2(hh[6], hh[7]) };
}

// ---------------------------------------------------------------------------
// context GEMM (depth-2 pipe, XCD-swizzled): grid 1024 (1-D), block 256
// ---------------------------------------------------------------------------
__global__ __launch_bounds__(256) void gemm_ctx_kernel(
    const ushort_t* __restrict__ Attn, const ushort_t* __restrict__ T,
    const uchar_t* __restrict__ maskT, ushort_t* __restrict__ X) {
  __shared__ ushort_t lab[4 * 4096];
  int t = threadIdx.x;
  int bid = blockIdx.x;
  int nw = (bid & 7) * 128 + (bid >> 3);  // bijective: 1024 = 8*128
  int b = nw >> 4;
  int local = nw & 15;
  int m0 = (local & 1) * 128, n0 = (local >> 1) * 128;
  const ushort_t* A = Attn + (size_t)b * 65536 + (size_t)m0 * 256;
  const ushort_t* B = T + (size_t)b * 262144 + (size_t)n0 * 256;
  int lane = t & 63, wave = t >> 6;
  int wr = (wave >> 1) << 6, wc = (wave & 1) << 6;
  int fr = lane & 15, fg = lane >> 4;
  f4 acc[4][4];
#pragma unroll
  for (int m = 0; m < 4; ++m)
#pragma unroll
    for (int n = 0; n < 4; ++n) acc[m][n] = f4{0.f, 0.f, 0.f, 0.f};
  gemm_pipe(A, 256, B, 256, 256, lab, acc, t, wr, wc, fr, fg);
#pragma unroll
  for (int m = 0; m < 4; ++m)
#pragma unroll
    for (int n = 0; n < 4; ++n)
#pragma unroll
      for (int r = 0; r < 4; ++r) {
        int gm = m0 + wr + m * 16 + fg * 4 + r;
        int gn = n0 + wc + n * 16 + fr;
        float v = maskT[b * 256 + gm] ? 0.f : acc[m][n][r];
        X[((size_t)gm * 64 + b) * 2048 + 1024 + gn] = f2bf(v);
      }
}

// ---------------------------------------------------------------------------
// MLP GEMM (depth-2 pipe, XCD-swizzled): C = relu(A @ W^T + bias).
// grid 1024 (1-D), block 256.
// ---------------------------------------------------------------------------
__global__ __launch_bounds__(256) void gemm_mlp_kernel(
    const ushort_t* __restrict__ A, int lda, const ushort_t* __restrict__ W,
    int ldw, const float* __restrict__ bias, ushort_t* __restrict__ C, int K) {
  __shared__ ushort_t lab[4 * 4096];
  int t = threadIdx.x;
  int bid = blockIdx.x;
  int mt = (bid & 7) * 16 + ((bid >> 3) & 15);  // [0,128) bijective
  int nt = bid >> 7;                            // [0,8)
  int m0 = mt * 128, n0 = nt * 128;
  int lane = t & 63, wave = t >> 6;
  int wr = (wave >> 1) << 6, wc = (wave & 1) << 6;
  int fr = lane & 15, fg = lane >> 4;
  f4 acc[4][4];
#pragma unroll
  for (int m = 0; m < 4; ++m)
#pragma unroll
    for (int n = 0; n < 4; ++n) acc[m][n] = f4{0.f, 0.f, 0.f, 0.f};
  gemm_pipe(A + (size_t)m0 * lda, lda, W + (size_t)n0 * ldw, ldw, K,
            lab, acc, t, wr, wc, fr, fg);
#pragma unroll
  for (int m = 0; m < 4; ++m)
#pragma unroll
    for (int n = 0; n < 4; ++n)
#pragma unroll
      for (int r = 0; r < 4; ++r) {
        int gm = m0 + wr + m * 16 + fg * 4 + r;
        int gn = n0 + wc + n * 16 + fr;
        float v = acc[m][n][r] + bias[gn];
        v = v > 0.f ? v : 0.f;
        C[(size_t)gm * 1024 + gn] = f2bf(v);
      }
}

// ---------------------------------------------------------------------------
// pool partial: partial[jc][b][coff+n] = sum_{j in chunk} H2[(j*64+b)][n]
// ---------------------------------------------------------------------------
__global__ __launch_bounds__(256) void pool_partial_kernel(
    const ushort_t* __restrict__ H2, float* __restrict__ partial, int coff) {
  int jc = blockIdx.x, b = blockIdx.y, t = threadIdx.x;
  float a0 = 0.f, a1 = 0.f, a2 = 0.f, a3 = 0.f;
  for (int j = jc * 32; j < jc * 32 + 32; ++j) {
    u2 v = *(const u2*)(H2 + ((size_t)(j * 64 + b)) * 1024 + t * 4);
    a0 += bf2f((ushort_t)(v[0] & 0xffff));
    a1 += bf2f((ushort_t)(v[0] >> 16));
    a2 += bf2f((ushort_t)(v[1] & 0xffff));
    a3 += bf2f((ushort_t)(v[1] >> 16));
  }
  *(f4*)(partial + ((size_t)(jc * 64 + b)) * 2048 + coff + t * 4) = f4{a0, a1, a2, a3};
}

// ---------------------------------------------------------------------------
// pool final + hi/lo split. grid 512, block 256
// ---------------------------------------------------------------------------
__global__ __launch_bounds__(256) void pool_final_kernel(
    const float* __restrict__ partial, ushort_t* __restrict__ ph,
    ushort_t* __restrict__ pl) {
  int idx = blockIdx.x * 256 + threadIdx.x;
  int b = idx >> 11, k = idx & 2047;
  float s = 0.f;
#pragma unroll
  for (int jc = 0; jc < 8; ++jc) s += partial[((size_t)(jc * 64 + b)) * 2048 + k];
  ushort_t h = f2bf(s);
  ph[idx] = h;
  pl[idx] = f2bf(s - bf2f(h));
}

// ---------------------------------------------------------------------------
// agg layer 1 (split bf16x2)
// ---------------------------------------------------------------------------
__global__ __launch_bounds__(256) void gemm_agg1_kernel(
    const ushort_t* __restrict__ Ph, const ushort_t* __restrict__ Pl,
    const ushort_t* __restrict__ Wh, const ushort_t* __restrict__ Wl,
    const float* __restrict__ bias, float* __restrict__ z) {
  __shared__ ushort_t lAh[64 * LDR], lAl[64 * LDR], lBh[128 * LDR], lBl[128 * LDR];
  int t = threadIdx.x;
  int n0 = blockIdx.x * 128;
  int lane = t & 63, wave = t >> 6;
  int wc = wave * 32;
  int fr = lane & 15, fg = lane >> 4;
  f4 acc[4][2];
#pragma unroll
  for (int m = 0; m < 4; ++m)
#pragma unroll
    for (int n = 0; n < 2; ++n) acc[m][n] = f4{0.f, 0.f, 0.f, 0.f};

  for (int k0 = 0; k0 < 2048; k0 += 32) {
    __syncthreads();
    {
      int row = t >> 2, kp = (t & 3) << 3;
      *(u4*)(lAh + row * LDR + kp) = *(const u4*)(Ph + (size_t)row * 2048 + k0 + kp);
      *(u4*)(lAl + row * LDR + kp) = *(const u4*)(Pl + (size_t)row * 2048 + k0 + kp);
    }
#pragma unroll
    for (int c = 0; c < 2; ++c) {
      int ch = t + (c << 8);
      int row = ch >> 2, kp = (ch & 3) << 3;
      *(u4*)(lBh + row * LDR + kp) = *(const u4*)(Wh + (size_t)(n0 + row) * 2048 + k0 + kp);
      *(u4*)(lBl + row * LDR + kp) = *(const u4*)(Wl + (size_t)(n0 + row) * 2048 + k0 + kp);
    }
    __syncthreads();
    u4 ah[4], al[4], bh[2], bl[2];
#pragma unroll
    for (int m = 0; m < 4; ++m) {
      int off = (m * 16 + fr) * LDR + (fg << 3);
      ah[m] = *(const u4*)(lAh + off);
      al[m] = *(const u4*)(lAl + off);
    }
#pragma unroll
    for (int n = 0; n < 2; ++n) {
      int off = (wc + n * 16 + fr) * LDR + (fg << 3);
      bh[n] = *(const u4*)(lBh + off);
      bl[n] = *(const u4*)(lBl + off);
    }
#pragma unroll
    for (int m = 0; m < 4; ++m)
#pragma unroll
      for (int n = 0; n < 2; ++n) {
        mfma16(acc[m][n], ah[m], bh[n]);
        mfma16(acc[m][n], ah[m], bl[n]);
        mfma16(acc[m][n], al[m], bh[n]);
      }
  }
#pragma unroll
  for (int m = 0; m < 4; ++m)
#pragma unroll
    for (int n = 0; n < 2; ++n)
#pragma unroll
      for (int r = 0; r < 4; ++r) {
        int row = m * 16 + fg * 4 + r;  // b
        int col = n0 + wc + n * 16 + fr;
        float v = acc[m][n][r] + bias[col];
        z[row * 1024 + col] = v > 0.f ? v : 0.f;
      }
}

// ---------------------------------------------------------------------------
// agg layer 2
// ---------------------------------------------------------------------------
__global__ __launch_bounds__(64) void agg2_kernel(
    const float* __restrict__ z, const float* __restrict__ aW2,
    const float* __restrict__ ab2, float* __restrict__ out) {
  int b = blockIdx.x, lane = threadIdx.x;
  float a0 = 0.f, a1 = 0.f, a2 = 0.f;
  for (int k = lane; k < 1024; k += 64) {
    float zv = z[b * 1024 + k];
    a0 += zv * aW2[k * 3 + 0];
    a1 += zv * aW2[k * 3 + 1];
    a2 += zv * aW2[k * 3 + 2];
  }
#pragma unroll
  for (int off = 32; off > 0; off >>= 1) {
    a0 += __shfl_xor(a0, off);
    a1 += __shfl_xor(a1, off);
    a2 += __shfl_xor(a2, off);
  }
  if (lane == 0) {
    out[b * 3 + 0] = a0 + ab2[0];
    out[b * 3 + 1] = a1 + ab2[1];
    out[b * 3 + 2] = a2 + ab2[2];
  }
}

// ---------------------------------------------------------------------------
extern "C" void kernel_launch(void* const* d_in, const int* in_sizes, int n_in,
                              void* d_out, int out_size, void* d_ws, size_t ws_size,
                              hipStream_t stream) {
  const float* P_enc = (const float*)d_in[0];
  const float* H_enc = (const float*)d_in[1];
  const float* P_emb = (const float*)d_in[2];
  const float* H_emb = (const float*)d_in[3];
  const uchar_t* prem = (const uchar_t*)d_in[4];
  const uchar_t* hypo = (const uchar_t*)d_in[5];
  const float* cW1 = (const float*)d_in[6];
  const float* cb1 = (const float*)d_in[7];
  const float* cW2 = (const float*)d_in[8];
  const float* cb2 = (const float*)d_in[9];
  const float* aW1 = (const float*)d_in[10];
  const float* ab1 = (const float*)d_in[11];
  const float* aW2 = (const float*)d_in[12];
  const float* ab2 = (const float*)d_in[13];

  char* w = (char*)d_ws;
  auto alloc = [&](size_t bytes) { char* p = w; w += bytes; return p; };
  float* S        = (float*)alloc(16777216);     // [64][256][256] f32
  ushort_t* Wsm   = (ushort_t*)alloc(8388608);   // [b][i][j] bf16
  ushort_t* Vsm   = (ushort_t*)alloc(8388608);   // [b][j][i] bf16
  ushort_t* T     = (ushort_t*)alloc(33554432);  // [b][h][pos] bf16
  ushort_t* X     = (ushort_t*)alloc(67108864);  // [16384][2048] = [emb | ctx]
  ushort_t* H1    = (ushort_t*)alloc(33554432);  // [16384][1024]
  ushort_t* H2    = (ushort_t*)alloc(33554432);  // [16384][1024]
  ushort_t* cW1T  = (ushort_t*)alloc(4194304);   // [1024][2048]
  ushort_t* cW2T  = (ushort_t*)alloc(2097152);   // [1024][1024]
  ushort_t* aW1Th = (ushort_t*)alloc(4194304);
  ushort_t* aW1Tl = (ushort_t*)alloc(4194304);
  float* partial  = (float*)alloc(4194304);      // [8][64][2048] f32
  ushort_t* poolh = (ushort_t*)alloc(262144);
  ushort_t* pooll = (ushort_t*)alloc(262144);
  float* z        = (float*)alloc(262144);       // [64][1024]
  uchar_t* premT  = (uchar_t*)alloc(16384);
  uchar_t* hypoT  = (uchar_t*)alloc(16384);

  prep_masks_kernel<<<1, 256, 0, stream>>>(prem, hypo, premT, hypoT);
  transpose_w_kernel<<<dim3(32, 16), 256, 0, stream>>>(cW1, cW1T, (ushort_t*)nullptr, 1024, 2048);
  transpose_w_kernel<<<dim3(16, 16), 256, 0, stream>>>(cW2, cW2T, (ushort_t*)nullptr, 1024, 1024);
  transpose_w_kernel<<<dim3(32, 16), 256, 0, stream>>>(aW1, aW1Th, aW1Tl, 1024, 2048);

  gemm_s_kernel<<<1024, 256, 0, stream>>>(P_enc, H_enc, S);
  softmax_rows_kernel<<<4096, 256, 0, stream>>>(S, hypoT, Wsm);
  softmax_cols_kernel<<<dim3(8, 64), 256, 0, stream>>>(S, premT, Vsm);

  // ---- hypothesis side: H_ctx = P_attn^T @ P_emb, compare MLP, pool ----
  transpose_pos_h_kernel<<<dim3(4, 16, 64), 256, 0, stream>>>(P_emb, T);
  cast_half_kernel<<<8192, 256, 0, stream>>>(H_emb, X);
  gemm_ctx_kernel<<<1024, 256, 0, stream>>>(Vsm, T, hypoT, X);
  gemm_mlp_kernel<<<1024, 256, 0, stream>>>(X, 2048, cW1T, 2048, cb1, H1, 2048);
  gemm_mlp_kernel<<<1024, 256, 0, stream>>>(H1, 1024, cW2T, 1024, cb2, H2, 1024);
  pool_partial_kernel<<<dim3(8, 64), 256, 0, stream>>>(H2, partial, 0);

  // ---- premise side: P_ctx = H_attn^T @ H_emb, compare MLP, pool ----
  transpose_pos_h_kernel<<<dim3(4, 16, 64), 256, 0, stream>>>(H_emb, T);
  cast_half_kernel<<<8192, 256, 0, stream>>>(P_emb, X);
  gemm_ctx_kernel<<<1024, 256, 0, stream>>>(Wsm, T, premT, X);
  gemm_mlp_kernel<<<1024, 256, 0, stream>>>(X, 2048, cW1T, 2048, cb1, H1, 2048);
  gemm_mlp_kernel<<<1024, 256, 0, stream>>>(H1, 1024, cW2T, 1024, cb2, H2, 1024);
  pool_partial_kernel<<<dim3(8, 64), 256, 0, stream>>>(H2, partial, 1024);

  // ---- aggregation ----
  pool_final_kernel<<<512, 256, 0, stream>>>(partial, poolh, pooll);
  gemm_agg1_kernel<<<8, 256, 0, stream>>>(poolh, pooll, aW1Th, aW1Tl, ab1, z);
  agg2_kernel<<<64, 64, 0, stream>>>(z, aW2, ab2, (float*)d_out);
}

// Round 9
// 607.348 us; speedup vs baseline: 1.0909x; 1.0413x over previous
//
#include <hip/hip_runtime.h>
#include <cstdint>
#include <cstddef>

typedef unsigned short ushort_t;
typedef unsigned char uchar_t;
typedef __attribute__((ext_vector_type(4))) float f4;
typedef __attribute__((ext_vector_type(4))) unsigned int u4;
typedef __attribute__((ext_vector_type(2))) unsigned int u2;

#define DEVI static __device__ __forceinline__

DEVI ushort_t f2bf(float x) {
  union { float f; unsigned int u; } v; v.f = x;
  unsigned int r = v.u + 0x7fffu + ((v.u >> 16) & 1u);
  return (ushort_t)(r >> 16);
}
DEVI float bf2f(ushort_t b) {
  union { unsigned int u; float f; } v; v.u = ((unsigned int)b) << 16;
  return v.f;
}
DEVI unsigned pk2(ushort_t a, ushort_t b) { return (unsigned)a | ((unsigned)b << 16); }

DEVI void mfma16(f4& c, u4 a, u4 b) {
  asm("v_mfma_f32_16x16x32_bf16 %0, %1, %2, %0" : "+v"(c) : "v"(a), "v"(b));
}

constexpr int LDR = 40;  // padded LDS row stride (shorts) for reg-staged tiles

// --------------------------------------------------------------------------
// global_load_lds staging: bf16 tile [128 rows][32 cols], linear LDS layout.
// --------------------------------------------------------------------------
#if defined(__has_builtin)
#if __has_builtin(__builtin_amdgcn_global_load_lds)
#define HAS_GLD 1
#endif
#endif
#ifndef HAS_GLD
#define HAS_GLD 0
#endif

#if HAS_GLD
typedef const __attribute__((address_space(1))) unsigned int* gas1_t;
typedef __attribute__((address_space(3))) unsigned int* las3_t;
DEVI void gld16(const void* g, void* l) {
  __builtin_amdgcn_global_load_lds((gas1_t)g, (las3_t)l, 16, 0, 0);
}
#endif

// Stages rows 0..127, cols k0..k0+31 of src (row stride srcStride) into
// lT[128][32] linear. 2 vmcnt-ops/thread on the gld path.
DEVI void stage_tile(const ushort_t* __restrict__ src, int srcStride, int k0,
                     ushort_t* lT, int t) {
#if HAS_GLD
  int w = t >> 6, lane = t & 63;
#pragma unroll
  for (int c = 0; c < 2; ++c) {
    int row = c * 64 + w * 16 + (lane >> 2);
    const ushort_t* g = src + (size_t)row * srcStride + k0 + (lane & 3) * 8;
    gld16(g, lT + (c * 64 + w * 16) * 32);
  }
#else
  int row = t >> 1, kp = (t & 1) << 4;
  const ushort_t* g = src + (size_t)row * srcStride + k0 + kp;
  *(u4*)(lT + row * 32 + kp) = *(const u4*)g;
  *(u4*)(lT + row * 32 + kp + 8) = *(const u4*)(g + 8);
#endif
}

// f32 source staging: convert 16 f32 -> bf16 in regs, ds_write into [128][32].
// ds_writes are drained by the pre-MFMA lgkmcnt(0) of the same step.
DEVI void stage_tile_f32(const float* __restrict__ src, int k0,
                         ushort_t* lT, int t) {
  int row = t >> 1, kp = (t & 1) << 4;
  const float* p = src + (size_t)row * 1024 + k0 + kp;
  f4 x0 = *(const f4*)p, x1 = *(const f4*)(p + 4);
  f4 x2 = *(const f4*)(p + 8), x3 = *(const f4*)(p + 12);
  ushort_t hh[16];
#pragma unroll
  for (int q = 0; q < 4; ++q) {
    hh[q] = f2bf(x0[q]); hh[4 + q] = f2bf(x1[q]);
    hh[8 + q] = f2bf(x2[q]); hh[12 + q] = f2bf(x3[q]);
  }
  *(u4*)(lT + row * 32 + kp) =
      u4{ pk2(hh[0], hh[1]), pk2(hh[2], hh[3]), pk2(hh[4], hh[5]), pk2(hh[6], hh[7]) };
  *(u4*)(lT + row * 32 + kp + 8) =
      u4{ pk2(hh[8], hh[9]), pk2(hh[10], hh[11]), pk2(hh[12], hh[13]), pk2(hh[14], hh[15]) };
}

// fragment reads + 16 MFMA for the 128x128, 4-wave layout (linear [128][32] LDS)
DEVI void compute16(const ushort_t* lA, const ushort_t* lB, f4 acc[4][4],
                    int wr, int wc, int fr, int fg) {
  u4 af[4], bfv[4];
#pragma unroll
  for (int m = 0; m < 4; ++m) af[m] = *(const u4*)(lA + (wr + m * 16 + fr) * 32 + (fg << 3));
#pragma unroll
  for (int n = 0; n < 4; ++n) bfv[n] = *(const u4*)(lB + (wc + n * 16 + fr) * 32 + (fg << 3));
#pragma unroll
  for (int m = 0; m < 4; ++m)
#pragma unroll
    for (int n = 0; n < 4; ++n) mfma16(acc[m][n], af[m], bfv[n]);
}

// ---------------------------------------------------------------------------
// Depth-2 explicit-sync pipelined GEMM core (round-8 verified, absmax 0.125):
//  R1 buf[t] ready before ds_read: vmcnt(0)+lgkmcnt(0) at top; s_barrier.
//  R2 stage(t+1) overwrites buf[t^1]: its readers (iter t-1) drained
//     lgkmcnt(0) before their MFMA, then crossed THIS barrier.
//  R3 rule #18: sched_barrier(0) after lgkmcnt(0) so MFMA can't hoist.
//  ds_write staging (f32 path) drains via the pre-MFMA lgkmcnt(0).
// ---------------------------------------------------------------------------
#if HAS_GLD
DEVI void gemm_pipe(const ushort_t* __restrict__ A, int lda,
                    const ushort_t* __restrict__ B, int ldb, int K,
                    ushort_t* lab, f4 acc[4][4], int t, int wr, int wc,
                    int fr, int fg) {
  ushort_t* a0 = lab;             ushort_t* b0 = lab + 4096;
  ushort_t* a1 = lab + 2 * 4096;  ushort_t* b1 = lab + 3 * 4096;
  const int nt = K >> 5;
  stage_tile(A, lda, 0, a0, t);
  stage_tile(B, ldb, 0, b0, t);
  for (int tt = 0; tt < nt; ++tt) {
    asm volatile("s_waitcnt vmcnt(0)" ::: "memory");
    asm volatile("s_barrier" ::: "memory");
    if (tt + 1 < nt) {
      stage_tile(A, lda, (tt + 1) << 5, a1, t);
      stage_tile(B, ldb, (tt + 1) << 5, b1, t);
    }
    u4 af[4], bfv[4];
#pragma unroll
    for (int m = 0; m < 4; ++m) af[m] = *(const u4*)(a0 + (wr + m * 16 + fr) * 32 + (fg << 3));
#pragma unroll
    for (int n = 0; n < 4; ++n) bfv[n] = *(const u4*)(b0 + (wc + n * 16 + fr) * 32 + (fg << 3));
    asm volatile("s_waitcnt lgkmcnt(0)" ::: "memory");
    __builtin_amdgcn_sched_barrier(0);
#pragma unroll
    for (int m = 0; m < 4; ++m)
#pragma unroll
      for (int n = 0; n < 4; ++n) mfma16(acc[m][n], af[m], bfv[n]);
    ushort_t* ta = a0; a0 = a1; a1 = ta;
    ushort_t* tb = b0; b0 = b1; b1 = tb;
  }
}
#else
// fallback: single-buffer 2-barrier (accuracy-clean class)
DEVI void gemm_pipe(const ushort_t* __restrict__ A, int lda,
                    const ushort_t* __restrict__ B, int ldb, int K,
                    ushort_t* lab, f4 acc[4][4], int t, int wr, int wc,
                    int fr, int fg) {
  ushort_t* a0 = lab;
  ushort_t* b0 = lab + 4096;
  const int nt = K >> 5;
  for (int tt = 0; tt < nt; ++tt) {
    __syncthreads();
    stage_tile(A, lda, tt << 5, a0, t);
    stage_tile(B, ldb, tt << 5, b0, t);
    __syncthreads();
    compute16(a0, b0, acc, wr, wc, fr, fg);
  }
}
#endif

// ---------------------------------------------------------------------------
// mask prep: detect uint8-bool vs int32 storage, write transposed [b][pos]
// ---------------------------------------------------------------------------
__global__ __launch_bounds__(256) void prep_masks_kernel(
    const uchar_t* __restrict__ prem, const uchar_t* __restrict__ hypo,
    uchar_t* __restrict__ premT, uchar_t* __restrict__ hypoT) {
  __shared__ int flagP, flagH;
  int t = threadIdx.x;
  if (t == 0) { flagP = 0; flagH = 0; }
  __syncthreads();
  int locP = 0, locH = 0;
  for (int i = t; i < 16384; i += 256) {
    if (i & 3) { locP |= prem[i]; locH |= hypo[i]; }
  }
  if (locP) atomicOr(&flagP, 1);
  if (locH) atomicOr(&flagH, 1);
  __syncthreads();
  bool p8 = flagP != 0, h8 = flagH != 0;  // true -> 1-byte bools
  for (int i = t; i < 16384; i += 256) {
    int p = i >> 6, b = i & 63;
    premT[b * 256 + p] = p8 ? prem[i] : prem[i * 4];
    hypoT[b * 256 + p] = h8 ? hypo[i] : hypo[i * 4];
  }
}

// ---------------------------------------------------------------------------
// weight transpose: f32 [K][N] -> bf16 [N][K] (optionally hi/lo split)
// ---------------------------------------------------------------------------
__global__ __launch_bounds__(256) void transpose_w_kernel(
    const float* __restrict__ Win, ushort_t* __restrict__ Thi,
    ushort_t* __restrict__ Tlo, int N, int K) {
  __shared__ float tl[64][65];
  int k0 = blockIdx.x * 64, n0 = blockIdx.y * 64;
  int t = threadIdx.x;
#pragma unroll
  for (int it = 0; it < 16; ++it) {
    int idx = t + it * 256;
    int k = idx >> 6, n = idx & 63;
    tl[n][k] = Win[(size_t)(k0 + k) * N + n0 + n];
  }
  __syncthreads();
#pragma unroll
  for (int it = 0; it < 16; ++it) {
    int idx = t + it * 256;
    int n = idx >> 6, k = idx & 63;
    float x = tl[n][k];
    ushort_t h = f2bf(x);
    Thi[(size_t)(n0 + n) * K + k0 + k] = h;
    if (Tlo) Tlo[(size_t)(n0 + n) * K + k0 + k] = f2bf(x - bf2f(h));
  }
}

// ---------------------------------------------------------------------------
// S GEMM, bf16x2 split, 64x64 tiles, dbuf single-barrier (ds_write staging
// only -> __syncthreads fully covers it; in the clean 0.125 build).
// grid 1024 (1-D, XCD-swizzled), block 256.
// ---------------------------------------------------------------------------
__global__ __launch_bounds__(256) void gemm_s_kernel(
    const float* __restrict__ Penc, const float* __restrict__ Henc,
    float* __restrict__ S) {
  __shared__ ushort_t lAh[2][64 * LDR], lAl[2][64 * LDR];
  __shared__ ushort_t lBh[2][64 * LDR], lBl[2][64 * LDR];
  const int t = threadIdx.x;
  const int bid = blockIdx.x;
  const int nw = (bid & 7) * 128 + (bid >> 3);  // bijective: 1024 = 8*128
  const int b = nw >> 4;
  const int local = nw & 15;
  const int i0 = (local & 3) * 64, j0 = (local >> 2) * 64;
  const int lda = 64 * 1024;
  const float* Ab = Penc + (size_t)i0 * lda + (size_t)b * 1024;
  const float* Bb = Henc + (size_t)j0 * lda + (size_t)b * 1024;
  const int lane = t & 63, wave = t >> 6;
  const int wr = (wave >> 1) << 5, wc = (wave & 1) << 5;
  const int fr = lane & 15, fg = lane >> 4;
  const int row = t >> 2, kp = (t & 3) << 3;

  f4 acc[2][2];
#pragma unroll
  for (int m = 0; m < 2; ++m)
#pragma unroll
    for (int n = 0; n < 2; ++n) acc[m][n] = f4{0.f, 0.f, 0.f, 0.f};

  auto stage = [&](int k0, int bi) {
    {
      const float* p = Ab + (size_t)row * lda + k0 + kp;
      f4 x0 = *(const f4*)p, x1 = *(const f4*)(p + 4);
      ushort_t hh[8], ll[8];
#pragma unroll
      for (int q = 0; q < 4; ++q) {
        ushort_t h0 = f2bf(x0[q]); hh[q] = h0; ll[q] = f2bf(x0[q] - bf2f(h0));
        ushort_t h1 = f2bf(x1[q]); hh[4 + q] = h1; ll[4 + q] = f2bf(x1[q] - bf2f(h1));
      }
      *(u4*)(lAh[bi] + row * LDR + kp) = u4{ pk2(hh[0], hh[1]), pk2(hh[2], hh[3]), pk2(hh[4], hh[5]), pk2(hh[6], hh[7]) };
      *(u4*)(lAl[bi] + row * LDR + kp) = u4{ pk2(ll[0], ll[1]), pk2(ll[2], ll[3]), pk2(ll[4], ll[5]), pk2(ll[6], ll[7]) };
    }
    {
      const float* p = Bb + (size_t)row * lda + k0 + kp;
      f4 x0 = *(const f4*)p, x1 = *(const f4*)(p + 4);
      ushort_t hh[8], ll[8];
#pragma unroll
      for (int q = 0; q < 4; ++q) {
        ushort_t h0 = f2bf(x0[q]); hh[q] = h0; ll[q] = f2bf(x0[q] - bf2f(h0));
        ushort_t h1 = f2bf(x1[q]); hh[4 + q] = h1; ll[4 + q] = f2bf(x1[q] - bf2f(h1));
      }
      *(u4*)(lBh[bi] + row * LDR + kp) = u4{ pk2(hh[0], hh[1]), pk2(hh[2], hh[3]), pk2(hh[4], hh[5]), pk2(hh[6], hh[7]) };
      *(u4*)(lBl[bi] + row * LDR + kp) = u4{ pk2(ll[0], ll[1]), pk2(ll[2], ll[3]), pk2(ll[4], ll[5]), pk2(ll[6], ll[7]) };
    }
  };

  stage(0, 0);
  __syncthreads();
  for (int tt = 0; tt < 32; ++tt) {
    int cur = tt & 1;
    if (tt + 1 < 32) stage((tt + 1) << 5, cur ^ 1);
    u4 ah[2], al[2], bh[2], bl[2];
#pragma unroll
    for (int m = 0; m < 2; ++m) {
      int off = (wr + m * 16 + fr) * LDR + (fg << 3);
      ah[m] = *(const u4*)(lAh[cur] + off);
      al[m] = *(const u4*)(lAl[cur] + off);
    }
#pragma unroll
    for (int n = 0; n < 2; ++n) {
      int off = (wc + n * 16 + fr) * LDR + (fg << 3);
      bh[n] = *(const u4*)(lBh[cur] + off);
      bl[n] = *(const u4*)(lBl[cur] + off);
    }
#pragma unroll
    for (int m = 0; m < 2; ++m)
#pragma unroll
      for (int n = 0; n < 2; ++n) {
        mfma16(acc[m][n], ah[m], bh[n]);
        mfma16(acc[m][n], ah[m], bl[n]);
        mfma16(acc[m][n], al[m], bh[n]);
      }
    __syncthreads();
  }

  float* Sb = S + (size_t)b * 65536;
#pragma unroll
  for (int m = 0; m < 2; ++m)
#pragma unroll
    for (int n = 0; n < 2; ++n)
#pragma unroll
      for (int r = 0; r < 4; ++r) {
        int rrow = i0 + wr + m * 16 + fg * 4 + r;
        int col = j0 + wc + n * 16 + fr;
        Sb[(size_t)rrow * 256 + col] = acc[m][n][r];
      }
}

// ---------------------------------------------------------------------------
// softmax over j (contiguous)
// ---------------------------------------------------------------------------
__global__ __launch_bounds__(256) void softmax_rows_kernel(
    const float* __restrict__ S, const uchar_t* __restrict__ hypoT,
    ushort_t* __restrict__ W) {
  int r = blockIdx.x * 4 + (threadIdx.x >> 6);
  int lane = threadIdx.x & 63;
  int b = r >> 8;
  const float* row = S + (size_t)r * 256;
  f4 x = *(const f4*)(row + lane * 4);
  const uchar_t* mp = hypoT + b * 256 + lane * 4;
  float v0 = mp[0] ? -1e30f : x[0];
  float v1 = mp[1] ? -1e30f : x[1];
  float v2 = mp[2] ? -1e30f : x[2];
  float v3 = mp[3] ? -1e30f : x[3];
  float m = fmaxf(fmaxf(v0, v1), fmaxf(v2, v3));
#pragma unroll
  for (int off = 32; off > 0; off >>= 1) m = fmaxf(m, __shfl_xor(m, off));
  float e0 = expf(v0 - m), e1 = expf(v1 - m), e2 = expf(v2 - m), e3 = expf(v3 - m);
  float s = e0 + e1 + e2 + e3;
#pragma unroll
  for (int off = 32; off > 0; off >>= 1) s += __shfl_xor(s, off);
  float rinv = 1.0f / s;
  ushort_t w0 = f2bf(e0 * rinv), w1 = f2bf(e1 * rinv), w2 = f2bf(e2 * rinv), w3 = f2bf(e3 * rinv);
  *(u2*)(W + (size_t)r * 256 + lane * 4) = u2{ pk2(w0, w1), pk2(w2, w3) };
}

// ---------------------------------------------------------------------------
// softmax over i (strided) + transpose: V[b][j][i]
// ---------------------------------------------------------------------------
__global__ __launch_bounds__(256) void softmax_cols_kernel(
    const float* __restrict__ S, const uchar_t* __restrict__ premT,
    ushort_t* __restrict__ V) {
  __shared__ float tl[32][257];
  __shared__ float pm[8][32], ps[8][32], mfin[32], rs[32];
  int t = threadIdx.x;
  int jl = t & 31, ig = t >> 5;
  int b = blockIdx.y, j0 = blockIdx.x * 32;
  const float* Sb = S + (size_t)b * 65536;
  const uchar_t* pmsk = premT + b * 256;
  for (int i = ig; i < 256; i += 8)
    tl[jl][i] = pmsk[i] ? -1e30f : Sb[(size_t)i * 256 + j0 + jl];
  __syncthreads();
  float m = -3e30f;
#pragma unroll 8
  for (int ii = 0; ii < 32; ++ii) m = fmaxf(m, tl[jl][ig * 32 + ii]);
  float s = 0.f;
#pragma unroll 8
  for (int ii = 0; ii < 32; ++ii) s += expf(tl[jl][ig * 32 + ii] - m);
  pm[ig][jl] = m; ps[ig][jl] = s;
  __syncthreads();
  if (t < 32) {
    float M = pm[0][t];
#pragma unroll
    for (int g = 1; g < 8; ++g) M = fmaxf(M, pm[g][t]);
    float ss = 0.f;
#pragma unroll
    for (int g = 0; g < 8; ++g) ss += ps[g][t] * expf(pm[g][t] - M);
    mfin[t] = M; rs[t] = 1.0f / ss;
  }
  __syncthreads();
  for (int j2 = 0; j2 < 32; ++j2) {
    float val = expf(tl[j2][t] - mfin[j2]) * rs[j2];
    V[((size_t)b * 256 + j0 + j2) * 256 + t] = f2bf(val);
  }
}

// ---------------------------------------------------------------------------
// emb transpose: E[pos][b][h] f32 -> T[b][h][pos] bf16
// ---------------------------------------------------------------------------
__global__ __launch_bounds__(256) void transpose_pos_h_kernel(
    const float* __restrict__ E, ushort_t* __restrict__ T) {
  __shared__ ushort_t tl[64][65];
  int i0 = blockIdx.x * 64, h0 = blockIdx.y * 64, b = blockIdx.z;
  int t = threadIdx.x;
#pragma unroll
  for (int it = 0; it < 16; ++it) {
    int idx = t + it * 256;
    int i = idx >> 6, h = idx & 63;
    tl[h][i] = f2bf(E[((size_t)(i0 + i) * 64 + b) * 1024 + h0 + h]);
  }
  __syncthreads();
#pragma unroll
  for (int it = 0; it < 16; ++it) {
    int idx = t + it * 256;
    int h = idx >> 6, i = idx & 63;
    T[((size_t)b * 1024 + h0 + h) * 256 + i0 + i] = tl[h][i];
  }
}

// ---------------------------------------------------------------------------
// context GEMM (depth-2 pipe, XCD-swizzled): ctx[pos][h], masked-write bf16
// into Xc[(pos*64+b)*1024 + h]. grid 1024 (1-D), block 256
// ---------------------------------------------------------------------------
__global__ __launch_bounds__(256) void gemm_ctx_kernel(
    const ushort_t* __restrict__ Attn, const ushort_t* __restrict__ T,
    const uchar_t* __restrict__ maskT, ushort_t* __restrict__ Xc) {
  __shared__ ushort_t lab[4 * 4096];
  int t = threadIdx.x;
  int bid = blockIdx.x;
  int nw = (bid & 7) * 128 + (bid >> 3);  // bijective: 1024 = 8*128
  int b = nw >> 4;
  int local = nw & 15;
  int m0 = (local & 1) * 128, n0 = (local >> 1) * 128;
  const ushort_t* A = Attn + (size_t)b * 65536 + (size_t)m0 * 256;
  const ushort_t* B = T + (size_t)b * 262144 + (size_t)n0 * 256;
  int lane = t & 63, wave = t >> 6;
  int wr = (wave >> 1) << 6, wc = (wave & 1) << 6;
  int fr = lane & 15, fg = lane >> 4;
  f4 acc[4][4];
#pragma unroll
  for (int m = 0; m < 4; ++m)
#pragma unroll
    for (int n = 0; n < 4; ++n) acc[m][n] = f4{0.f, 0.f, 0.f, 0.f};
  gemm_pipe(A, 256, B, 256, 256, lab, acc, t, wr, wc, fr, fg);
#pragma unroll
  for (int m = 0; m < 4; ++m)
#pragma unroll
    for (int n = 0; n < 4; ++n)
#pragma unroll
      for (int r = 0; r < 4; ++r) {
        int gm = m0 + wr + m * 16 + fg * 4 + r;
        int gn = n0 + wc + n * 16 + fr;
        float v = maskT[b * 256 + gm] ? 0.f : acc[m][n][r];
        Xc[((size_t)gm * 64 + b) * 1024 + gn] = f2bf(v);
      }
}

// ---------------------------------------------------------------------------
// MLP layer-1 GEMM (fused cast, depth-2 explicit pipe, XCD-swizzled):
// C = relu([bf16(E) | Xc] @ cW1T^T + bias). Phase-E (K 0..1023): A staged
// from f32 E via reg-convert + ds_write (drained by pre-MFMA lgkmcnt(0)).
// Phase-ctx (K 1024..2047): A staged from Xc via gld16.
// grid 1024 (1-D), block 256.
// ---------------------------------------------------------------------------
__global__ __launch_bounds__(256) void gemm_mlp1_kernel(
    const float* __restrict__ Ef, const ushort_t* __restrict__ Xc,
    const ushort_t* __restrict__ W, const float* __restrict__ bias,
    ushort_t* __restrict__ C) {
  __shared__ ushort_t lab[4 * 4096];
  int t = threadIdx.x;
  int bid = blockIdx.x;
  int mt = (bid & 7) * 16 + ((bid >> 3) & 15);  // [0,128) bijective
  int nt = bid >> 7;                            // [0,8)
  int m0 = mt * 128, n0 = nt * 128;
  int lane = t & 63, wave = t >> 6;
  int wr = (wave >> 1) << 6, wc = (wave & 1) << 6;
  int fr = lane & 15, fg = lane >> 4;
  const float* Eb = Ef + (size_t)m0 * 1024;
  const ushort_t* Ab = Xc + (size_t)m0 * 1024;
  const ushort_t* Wn = W + (size_t)n0 * 2048;
  f4 acc[4][4];
#pragma unroll
  for (int m = 0; m < 4; ++m)
#pragma unroll
    for (int n = 0; n < 4; ++n) acc[m][n] = f4{0.f, 0.f, 0.f, 0.f};

  ushort_t* a0 = lab;             ushort_t* b0 = lab + 4096;
  ushort_t* a1 = lab + 2 * 4096;  ushort_t* b1 = lab + 3 * 4096;
  auto stageA = [&](int ks, ushort_t* buf) {
    if (ks < 32) stage_tile_f32(Eb, ks << 5, buf, t);
    else         stage_tile(Ab, 1024, (ks - 32) << 5, buf, t);
  };
  stageA(0, a0);
  stage_tile(Wn, 2048, 0, b0, t);
  for (int tt = 0; tt < 64; ++tt) {
    asm volatile("s_waitcnt vmcnt(0) lgkmcnt(0)" ::: "memory");
    asm volatile("s_barrier" ::: "memory");
    if (tt + 1 < 64) {
      stageA(tt + 1, a1);
      stage_tile(Wn, 2048, (tt + 1) << 5, b1, t);
    }
    u4 af[4], bfv[4];
#pragma unroll
    for (int m = 0; m < 4; ++m) af[m] = *(const u4*)(a0 + (wr + m * 16 + fr) * 32 + (fg << 3));
#pragma unroll
    for (int n = 0; n < 4; ++n) bfv[n] = *(const u4*)(b0 + (wc + n * 16 + fr) * 32 + (fg << 3));
    asm volatile("s_waitcnt lgkmcnt(0)" ::: "memory");
    __builtin_amdgcn_sched_barrier(0);
#pragma unroll
    for (int m = 0; m < 4; ++m)
#pragma unroll
      for (int n = 0; n < 4; ++n) mfma16(acc[m][n], af[m], bfv[n]);
    ushort_t* ta = a0; a0 = a1; a1 = ta;
    ushort_t* tb = b0; b0 = b1; b1 = tb;
  }

#pragma unroll
  for (int m = 0; m < 4; ++m)
#pragma unroll
    for (int n = 0; n < 4; ++n)
#pragma unroll
      for (int r = 0; r < 4; ++r) {
        int gm = m0 + wr + m * 16 + fg * 4 + r;
        int gn = n0 + wc + n * 16 + fr;
        float v = acc[m][n][r] + bias[gn];
        v = v > 0.f ? v : 0.f;
        C[(size_t)gm * 1024 + gn] = f2bf(v);
      }
}

// ---------------------------------------------------------------------------
// MLP GEMM (depth-2 pipe, XCD-swizzled): C = relu(A @ W^T + bias).
// grid 1024 (1-D), block 256. (layer 2: K=1024)
// ---------------------------------------------------------------------------
__global__ __launch_bounds__(256) void gemm_mlp_kernel(
    const ushort_t* __restrict__ A, int lda, const ushort_t* __restrict__ W,
    int ldw, const float* __restrict__ bias, ushort_t* __restrict__ C, int K) {
  __shared__ ushort_t lab[4 * 4096];
  int t = threadIdx.x;
  int bid = blockIdx.x;
  int mt = (bid & 7) * 16 + ((bid >> 3) & 15);  // [0,128) bijective
  int nt = bid >> 7;                            // [0,8)
  int m0 = mt * 128, n0 = nt * 128;
  int lane = t & 63, wave = t >> 6;
  int wr = (wave >> 1) << 6, wc = (wave & 1) << 6;
  int fr = lane & 15, fg = lane >> 4;
  f4 acc[4][4];
#pragma unroll
  for (int m = 0; m < 4; ++m)
#pragma unroll
    for (int n = 0; n < 4; ++n) acc[m][n] = f4{0.f, 0.f, 0.f, 0.f};
  gemm_pipe(A + (size_t)m0 * lda, lda, W + (size_t)n0 * ldw, ldw, K,
            lab, acc, t, wr, wc, fr, fg);
#pragma unroll
  for (int m = 0; m < 4; ++m)
#pragma unroll
    for (int n = 0; n < 4; ++n)
#pragma unroll
      for (int r = 0; r < 4; ++r) {
        int gm = m0 + wr + m * 16 + fg * 4 + r;
        int gn = n0 + wc + n * 16 + fr;
        float v = acc[m][n][r] + bias[gn];
        v = v > 0.f ? v : 0.f;
        C[(size_t)gm * 1024 + gn] = f2bf(v);
      }
}

// ---------------------------------------------------------------------------
// pool partial: partial[jc][b][coff+n] = sum_{j in chunk} H2[(j*64+b)][n]
// ---------------------------------------------------------------------------
__global__ __launch_bounds__(256) void pool_partial_kernel(
    const ushort_t* __restrict__ H2, float* __restrict__ partial, int coff) {
  int jc = blockIdx.x, b = blockIdx.y, t = threadIdx.x;
  float a0 = 0.f, a1 = 0.f, a2 = 0.f, a3 = 0.f;
  for (int j = jc * 32; j < jc * 32 + 32; ++j) {
    u2 v = *(const u2*)(H2 + ((size_t)(j * 64 + b)) * 1024 + t * 4);
    a0 += bf2f((ushort_t)(v[0] & 0xffff));
    a1 += bf2f((ushort_t)(v[0] >> 16));
    a2 += bf2f((ushort_t)(v[1] & 0xffff));
    a3 += bf2f((ushort_t)(v[1] >> 16));
  }
  *(f4*)(partial + ((size_t)(jc * 64 + b)) * 2048 + coff + t * 4) = f4{a0, a1, a2, a3};
}

// ---------------------------------------------------------------------------
// pool final + hi/lo split. grid 512, block 256
// ---------------------------------------------------------------------------
__global__ __launch_bounds__(256) void pool_final_kernel(
    const float* __restrict__ partial, ushort_t* __restrict__ ph,
    ushort_t* __restrict__ pl) {
  int idx = blockIdx.x * 256 + threadIdx.x;
  int b = idx >> 11, k = idx & 2047;
  float s = 0.f;
#pragma unroll
  for (int jc = 0; jc < 8; ++jc) s += partial[((size_t)(jc * 64 + b)) * 2048 + k];
  ushort_t h = f2bf(s);
  ph[idx] = h;
  pl[idx] = f2bf(s - bf2f(h));
}

// ---------------------------------------------------------------------------
// agg layer 1 (split bf16x2)
// ---------------------------------------------------------------------------
__global__ __launch_bounds__(256) void gemm_agg1_kernel(
    const ushort_t* __restrict__ Ph, const ushort_t* __restrict__ Pl,
    const ushort_t* __restrict__ Wh, const ushort_t* __restrict__ Wl,
    const float* __restrict__ bias, float* __restrict__ z) {
  __shared__ ushort_t lAh[64 * LDR], lAl[64 * LDR], lBh[128 * LDR], lBl[128 * LDR];
  int t = threadIdx.x;
  int n0 = blockIdx.x * 128;
  int lane = t & 63, wave = t >> 6;
  int wc = wave * 32;
  int fr = lane & 15, fg = lane >> 4;
  f4 acc[4][2];
#pragma unroll
  for (int m = 0; m < 4; ++m)
#pragma unroll
    for (int n = 0; n < 2; ++n) acc[m][n] = f4{0.f, 0.f, 0.f, 0.f};

  for (int k0 = 0; k0 < 2048; k0 += 32) {
    __syncthreads();
    {
      int row = t >> 2, kp = (t & 3) << 3;
      *(u4*)(lAh + row * LDR + kp) = *(const u4*)(Ph + (size_t)row * 2048 + k0 + kp);
      *(u4*)(lAl + row * LDR + kp) = *(const u4*)(Pl + (size_t)row * 2048 + k0 + kp);
    }
#pragma unroll
    for (int c = 0; c < 2; ++c) {
      int ch = t + (c << 8);
      int row = ch >> 2, kp = (ch & 3) << 3;
      *(u4*)(lBh + row * LDR + kp) = *(const u4*)(Wh + (size_t)(n0 + row) * 2048 + k0 + kp);
      *(u4*)(lBl + row * LDR + kp) = *(const u4*)(Wl + (size_t)(n0 + row) * 2048 + k0 + kp);
    }
    __syncthreads();
    u4 ah[4], al[4], bh[2], bl[2];
#pragma unroll
    for (int m = 0; m < 4; ++m) {
      int off = (m * 16 + fr) * LDR + (fg << 3);
      ah[m] = *(const u4*)(lAh + off);
      al[m] = *(const u4*)(lAl + off);
    }
#pragma unroll
    for (int n = 0; n < 2; ++n) {
      int off = (wc + n * 16 + fr) * LDR + (fg << 3);
      bh[n] = *(const u4*)(lBh + off);
      bl[n] = *(const u4*)(lBl + off);
    }
#pragma unroll
    for (int m = 0; m < 4; ++m)
#pragma unroll
      for (int n = 0; n < 2; ++n) {
        mfma16(acc[m][n], ah[m], bh[n]);
        mfma16(acc[m][n], ah[m], bl[n]);
        mfma16(acc[m][n], al[m], bh[n]);
      }
  }
#pragma unroll
  for (int m = 0; m < 4; ++m)
#pragma unroll
    for (int n = 0; n < 2; ++n)
#pragma unroll
      for (int r = 0; r < 4; ++r) {
        int row = m * 16 + fg * 4 + r;  // b
        int col = n0 + wc + n * 16 + fr;
        float v = acc[m][n][r] + bias[col];
        z[row * 1024 + col] = v > 0.f ? v : 0.f;
      }
}

// ---------------------------------------------------------------------------
// agg layer 2
// ---------------------------------------------------------------------------
__global__ __launch_bounds__(64) void agg2_kernel(
    const float* __restrict__ z, const float* __restrict__ aW2,
    const float* __restrict__ ab2, float* __restrict__ out) {
  int b = blockIdx.x, lane = threadIdx.x;
  float a0 = 0.f, a1 = 0.f, a2 = 0.f;
  for (int k = lane; k < 1024; k += 64) {
    float zv = z[b * 1024 + k];
    a0 += zv * aW2[k * 3 + 0];
    a1 += zv * aW2[k * 3 + 1];
    a2 += zv * aW2[k * 3 + 2];
  }
#pragma unroll
  for (int off = 32; off > 0; off >>= 1) {
    a0 += __shfl_xor(a0, off);
    a1 += __shfl_xor(a1, off);
    a2 += __shfl_xor(a2, off);
  }
  if (lane == 0) {
    out[b * 3 + 0] = a0 + ab2[0];
    out[b * 3 + 1] = a1 + ab2[1];
    out[b * 3 + 2] = a2 + ab2[2];
  }
}

// ---------------------------------------------------------------------------
extern "C" void kernel_launch(void* const* d_in, const int* in_sizes, int n_in,
                              void* d_out, int out_size, void* d_ws, size_t ws_size,
                              hipStream_t stream) {
  const float* P_enc = (const float*)d_in[0];
  const float* H_enc = (const float*)d_in[1];
  const float* P_emb = (const float*)d_in[2];
  const float* H_emb = (const float*)d_in[3];
  const uchar_t* prem = (const uchar_t*)d_in[4];
  const uchar_t* hypo = (const uchar_t*)d_in[5];
  const float* cW1 = (const float*)d_in[6];
  const float* cb1 = (const float*)d_in[7];
  const float* cW2 = (const float*)d_in[8];
  const float* cb2 = (const float*)d_in[9];
  const float* aW1 = (const float*)d_in[10];
  const float* ab1 = (const float*)d_in[11];
  const float* aW2 = (const float*)d_in[12];
  const float* ab2 = (const float*)d_in[13];

  char* w = (char*)d_ws;
  auto alloc = [&](size_t bytes) { char* p = w; w += bytes; return p; };
  float* S        = (float*)alloc(16777216);     // [64][256][256] f32
  ushort_t* Wsm   = (ushort_t*)alloc(8388608);   // [b][i][j] bf16
  ushort_t* Vsm   = (ushort_t*)alloc(8388608);   // [b][j][i] bf16
  ushort_t* T     = (ushort_t*)alloc(33554432);  // [b][h][pos] bf16
  ushort_t* Xc    = (ushort_t*)alloc(33554432);  // ctx [16384][1024] bf16
  ushort_t* H1    = (ushort_t*)alloc(33554432);  // [16384][1024]
  ushort_t* H2    = (ushort_t*)alloc(33554432);  // [16384][1024]
  ushort_t* cW1T  = (ushort_t*)alloc(4194304);   // [1024][2048]
  ushort_t* cW2T  = (ushort_t*)alloc(2097152);   // [1024][1024]
  ushort_t* aW1Th = (ushort_t*)alloc(4194304);
  ushort_t* aW1Tl = (ushort_t*)alloc(4194304);
  float* partial  = (float*)alloc(4194304);      // [8][64][2048] f32
  ushort_t* poolh = (ushort_t*)alloc(262144);
  ushort_t* pooll = (ushort_t*)alloc(262144);
  float* z        = (float*)alloc(262144);       // [64][1024]
  uchar_t* premT  = (uchar_t*)alloc(16384);
  uchar_t* hypoT  = (uchar_t*)alloc(16384);

  prep_masks_kernel<<<1, 256, 0, stream>>>(prem, hypo, premT, hypoT);
  transpose_w_kernel<<<dim3(32, 16), 256, 0, stream>>>(cW1, cW1T, (ushort_t*)nullptr, 1024, 2048);
  transpose_w_kernel<<<dim3(16, 16), 256, 0, stream>>>(cW2, cW2T, (ushort_t*)nullptr, 1024, 1024);
  transpose_w_kernel<<<dim3(32, 16), 256, 0, stream>>>(aW1, aW1Th, aW1Tl, 1024, 2048);

  gemm_s_kernel<<<1024, 256, 0, stream>>>(P_enc, H_enc, S);
  softmax_rows_kernel<<<4096, 256, 0, stream>>>(S, hypoT, Wsm);
  softmax_cols_kernel<<<dim3(8, 64), 256, 0, stream>>>(S, premT, Vsm);

  // ---- hypothesis side: H_ctx = P_attn^T @ P_emb, compare MLP, pool ----
  transpose_pos_h_kernel<<<dim3(4, 16, 64), 256, 0, stream>>>(P_emb, T);
  gemm_ctx_kernel<<<1024, 256, 0, stream>>>(Vsm, T, hypoT, Xc);
  gemm_mlp1_kernel<<<1024, 256, 0, stream>>>(H_emb, Xc, cW1T, cb1, H1);
  gemm_mlp_kernel<<<1024, 256, 0, stream>>>(H1, 1024, cW2T, 1024, cb2, H2, 1024);
  pool_partial_kernel<<<dim3(8, 64), 256, 0, stream>>>(H2, partial, 0);

  // ---- premise side: P_ctx = H_attn^T @ H_emb, compare MLP, pool ----
  transpose_pos_h_kernel<<<dim3(4, 16, 64), 256, 0, stream>>>(H_emb, T);
  gemm_ctx_kernel<<<1024, 256, 0, stream>>>(Wsm, T, premT, Xc);
  gemm_mlp1_kernel<<<1024, 256, 0, stream>>>(P_emb, Xc, cW1T, cb1, H1);
  gemm_mlp_kernel<<<1024, 256, 0, stream>>>(H1, 1024, cW2T, 1024, cb2, H2, 1024);
  pool_partial_kernel<<<dim3(8, 64), 256, 0, stream>>>(H2, partial, 1024);

  // ---- aggregation ----
  pool_final_kernel<<<512, 256, 0, stream>>>(partial, poolh, pooll);
  gemm_agg1_kernel<<<8, 256, 0, stream>>>(poolh, pooll, aW1Th, aW1Tl, ab1, z);
  agg2_kernel<<<64, 64, 0, stream>>>(z, aW2, ab2, (float*)d_out);
}

// Round 13
// 604.981 us; speedup vs baseline: 1.0952x; 1.0039x over previous
//
#include <hip/hip_runtime.h>
#include <cstdint>
#include <cstddef>

typedef unsigned short ushort_t;
typedef unsigned char uchar_t;
typedef __attribute__((ext_vector_type(4))) float f4;
typedef __attribute__((ext_vector_type(4))) unsigned int u4;
typedef __attribute__((ext_vector_type(2))) unsigned int u2;

#define DEVI static __device__ __forceinline__

DEVI ushort_t f2bf(float x) {
  union { float f; unsigned int u; } v; v.f = x;
  unsigned int r = v.u + 0x7fffu + ((v.u >> 16) & 1u);
  return (ushort_t)(r >> 16);
}
DEVI float bf2f(ushort_t b) {
  union { unsigned int u; float f; } v; v.u = ((unsigned int)b) << 16;
  return v.f;
}
DEVI unsigned pk2(ushort_t a, ushort_t b) { return (unsigned)a | ((unsigned)b << 16); }

DEVI void mfma16(f4& c, u4 a, u4 b) {
  asm("v_mfma_f32_16x16x32_bf16 %0, %1, %2, %0" : "+v"(c) : "v"(a), "v"(b));
}

constexpr int LDR = 40;  // padded LDS row stride (shorts) for reg-staged tiles

// --------------------------------------------------------------------------
// global_load_lds staging: bf16 tile [128 rows][32 cols], linear LDS layout.
// NOTE (r10-r12 post-mortem): this staging is VERIFIED ONLY in 4-wave
// (256-thread) workgroups. All 8-wave variants produced LDS garbage.
// --------------------------------------------------------------------------
#if defined(__has_builtin)
#if __has_builtin(__builtin_amdgcn_global_load_lds)
#define HAS_GLD 1
#endif
#endif
#ifndef HAS_GLD
#define HAS_GLD 0
#endif

#if HAS_GLD
typedef const __attribute__((address_space(1))) unsigned int* gas1_t;
typedef __attribute__((address_space(3))) unsigned int* las3_t;
DEVI void gld16(const void* g, void* l) {
  __builtin_amdgcn_global_load_lds((gas1_t)g, (las3_t)l, 16, 0, 0);
}
#endif

// Stages rows 0..127, cols k0..k0+31 of src (row stride srcStride) into
// lT[128][32] linear. 2 vmcnt-ops/thread on the gld path.
DEVI void stage_tile(const ushort_t* __restrict__ src, int srcStride, int k0,
                     ushort_t* lT, int t) {
#if HAS_GLD
  int w = t >> 6, lane = t & 63;
#pragma unroll
  for (int c = 0; c < 2; ++c) {
    int row = c * 64 + w * 16 + (lane >> 2);
    const ushort_t* g = src + (size_t)row * srcStride + k0 + (lane & 3) * 8;
    gld16(g, lT + (c * 64 + w * 16) * 32);
  }
#else
  int row = t >> 1, kp = (t & 1) << 4;
  const ushort_t* g = src + (size_t)row * srcStride + k0 + kp;
  *(u4*)(lT + row * 32 + kp) = *(const u4*)g;
  *(u4*)(lT + row * 32 + kp + 8) = *(const u4*)(g + 8);
#endif
}

// f32 source staging: convert 16 f32 -> bf16 in regs, ds_write into [128][32].
// ds_writes are drained by the pre-MFMA lgkmcnt(0) of the same step.
DEVI void stage_tile_f32(const float* __restrict__ src, int k0,
                         ushort_t* lT, int t) {
  int row = t >> 1, kp = (t & 1) << 4;
  const float* p = src + (size_t)row * 1024 + k0 + kp;
  f4 x0 = *(const f4*)p, x1 = *(const f4*)(p + 4);
  f4 x2 = *(const f4*)(p + 8), x3 = *(const f4*)(p + 12);
  ushort_t hh[16];
#pragma unroll
  for (int q = 0; q < 4; ++q) {
    hh[q] = f2bf(x0[q]); hh[4 + q] = f2bf(x1[q]);
    hh[8 + q] = f2bf(x2[q]); hh[12 + q] = f2bf(x3[q]);
  }
  *(u4*)(lT + row * 32 + kp) =
      u4{ pk2(hh[0], hh[1]), pk2(hh[2], hh[3]), pk2(hh[4], hh[5]), pk2(hh[6], hh[7]) };
  *(u4*)(lT + row * 32 + kp + 8) =
      u4{ pk2(hh[8], hh[9]), pk2(hh[10], hh[11]), pk2(hh[12], hh[13]), pk2(hh[14], hh[15]) };
}

// fragment reads + 16 MFMA for the 128x128, 4-wave layout (linear [128][32] LDS)
DEVI void compute16(const ushort_t* lA, const ushort_t* lB, f4 acc[4][4],
                    int wr, int wc, int fr, int fg) {
  u4 af[4], bfv[4];
#pragma unroll
  for (int m = 0; m < 4; ++m) af[m] = *(const u4*)(lA + (wr + m * 16 + fr) * 32 + (fg << 3));
#pragma unroll
  for (int n = 0; n < 4; ++n) bfv[n] = *(const u4*)(lB + (wc + n * 16 + fr) * 32 + (fg << 3));
#pragma unroll
  for (int m = 0; m < 4; ++m)
#pragma unroll
    for (int n = 0; n < 4; ++n) mfma16(acc[m][n], af[m], bfv[n]);
}

// ---------------------------------------------------------------------------
// Depth-2 explicit-sync pipelined GEMM core (round-8/9 verified, absmax 0.125):
//  R1 buf[t] ready before ds_read: vmcnt(0) at top; s_barrier globalizes.
//  R2 stage(t+1) overwrites buf[t^1]: its readers (iter t-1) drained
//     lgkmcnt(0) before their MFMA, then crossed THIS barrier.
//  R3 rule #18: sched_barrier(0) after lgkmcnt(0) so MFMA can't hoist.
// ---------------------------------------------------------------------------
#if HAS_GLD
DEVI void gemm_pipe(const ushort_t* __restrict__ A, int lda,
                    const ushort_t* __restrict__ B, int ldb, int K,
                    ushort_t* lab, f4 acc[4][4], int t, int wr, int wc,
                    int fr, int fg) {
  ushort_t* a0 = lab;             ushort_t* b0 = lab + 4096;
  ushort_t* a1 = lab + 2 * 4096;  ushort_t* b1 = lab + 3 * 4096;
  const int nt = K >> 5;
  stage_tile(A, lda, 0, a0, t);
  stage_tile(B, ldb, 0, b0, t);
  for (int tt = 0; tt < nt; ++tt) {
    asm volatile("s_waitcnt vmcnt(0)" ::: "memory");
    asm volatile("s_barrier" ::: "memory");
    if (tt + 1 < nt) {
      stage_tile(A, lda, (tt + 1) << 5, a1, t);
      stage_tile(B, ldb, (tt + 1) << 5, b1, t);
    }
    u4 af[4], bfv[4];
#pragma unroll
    for (int m = 0; m < 4; ++m) af[m] = *(const u4*)(a0 + (wr + m * 16 + fr) * 32 + (fg << 3));
#pragma unroll
    for (int n = 0; n < 4; ++n) bfv[n] = *(const u4*)(b0 + (wc + n * 16 + fr) * 32 + (fg << 3));
    asm volatile("s_waitcnt lgkmcnt(0)" ::: "memory");
    __builtin_amdgcn_sched_barrier(0);
#pragma unroll
    for (int m = 0; m < 4; ++m)
#pragma unroll
      for (int n = 0; n < 4; ++n) mfma16(acc[m][n], af[m], bfv[n]);
    ushort_t* ta = a0; a0 = a1; a1 = ta;
    ushort_t* tb = b0; b0 = b1; b1 = tb;
  }
}
#else
DEVI void gemm_pipe(const ushort_t* __restrict__ A, int lda,
                    const ushort_t* __restrict__ B, int ldb, int K,
                    ushort_t* lab, f4 acc[4][4], int t, int wr, int wc,
                    int fr, int fg) {
  ushort_t* a0 = lab;
  ushort_t* b0 = lab + 4096;
  const int nt = K >> 5;
  for (int tt = 0; tt < nt; ++tt) {
    __syncthreads();
    stage_tile(A, lda, tt << 5, a0, t);
    stage_tile(B, ldb, tt << 5, b0, t);
    __syncthreads();
    compute16(a0, b0, acc, wr, wc, fr, fg);
  }
}
#endif

// ---------------------------------------------------------------------------
// mask prep: detect uint8-bool vs int32 storage, write transposed [b][pos]
// ---------------------------------------------------------------------------
__global__ __launch_bounds__(256) void prep_masks_kernel(
    const uchar_t* __restrict__ prem, const uchar_t* __restrict__ hypo,
    uchar_t* __restrict__ premT, uchar_t* __restrict__ hypoT) {
  __shared__ int flagP, flagH;
  int t = threadIdx.x;
  if (t == 0) { flagP = 0; flagH = 0; }
  __syncthreads();
  int locP = 0, locH = 0;
  for (int i = t; i < 16384; i += 256) {
    if (i & 3) { locP |= prem[i]; locH |= hypo[i]; }
  }
  if (locP) atomicOr(&flagP, 1);
  if (locH) atomicOr(&flagH, 1);
  __syncthreads();
  bool p8 = flagP != 0, h8 = flagH != 0;  // true -> 1-byte bools
  for (int i = t; i < 16384; i += 256) {
    int p = i >> 6, b = i & 63;
    premT[b * 256 + p] = p8 ? prem[i] : prem[i * 4];
    hypoT[b * 256 + p] = h8 ? hypo[i] : hypo[i * 4];
  }
}

// ---------------------------------------------------------------------------
// weight transpose: f32 [K][N] -> bf16 [N][K] (optionally hi/lo split)
// ---------------------------------------------------------------------------
__global__ __launch_bounds__(256) void transpose_w_kernel(
    const float* __restrict__ Win, ushort_t* __restrict__ Thi,
    ushort_t* __restrict__ Tlo, int N, int K) {
  __shared__ float tl[64][65];
  int k0 = blockIdx.x * 64, n0 = blockIdx.y * 64;
  int t = threadIdx.x;
#pragma unroll
  for (int it = 0; it < 16; ++it) {
    int idx = t + it * 256;
    int k = idx >> 6, n = idx & 63;
    tl[n][k] = Win[(size_t)(k0 + k) * N + n0 + n];
  }
  __syncthreads();
#pragma unroll
  for (int it = 0; it < 16; ++it) {
    int idx = t + it * 256;
    int n = idx >> 6, k = idx & 63;
    float x = tl[n][k];
    ushort_t h = f2bf(x);
    Thi[(size_t)(n0 + n) * K + k0 + k] = h;
    if (Tlo) Tlo[(size_t)(n0 + n) * K + k0 + k] = f2bf(x - bf2f(h));
  }
}

// ---------------------------------------------------------------------------
// S GEMM, bf16x2 split, 64x64 tiles, dbuf single-barrier (ds_write staging
// only -> __syncthreads fully covers it). grid 1024 (1-D, XCD-swizzled).
// ---------------------------------------------------------------------------
__global__ __launch_bounds__(256) void gemm_s_kernel(
    const float* __restrict__ Penc, const float* __restrict__ Henc,
    float* __restrict__ S) {
  __shared__ ushort_t lAh[2][64 * LDR], lAl[2][64 * LDR];
  __shared__ ushort_t lBh[2][64 * LDR], lBl[2][64 * LDR];
  const int t = threadIdx.x;
  const int bid = blockIdx.x;
  const int nw = (bid & 7) * 128 + (bid >> 3);  // bijective: 1024 = 8*128
  const int b = nw >> 4;
  const int local = nw & 15;
  const int i0 = (local & 3) * 64, j0 = (local >> 2) * 64;
  const int lda = 64 * 1024;
  const float* Ab = Penc + (size_t)i0 * lda + (size_t)b * 1024;
  const float* Bb = Henc + (size_t)j0 * lda + (size_t)b * 1024;
  const int lane = t & 63, wave = t >> 6;
  const int wr = (wave >> 1) << 5, wc = (wave & 1) << 5;
  const int fr = lane & 15, fg = lane >> 4;
  const int row = t >> 2, kp = (t & 3) << 3;

  f4 acc[2][2];
#pragma unroll
  for (int m = 0; m < 2; ++m)
#pragma unroll
    for (int n = 0; n < 2; ++n) acc[m][n] = f4{0.f, 0.f, 0.f, 0.f};

  auto stage = [&](int k0, int bi) {
    {
      const float* p = Ab + (size_t)row * lda + k0 + kp;
      f4 x0 = *(const f4*)p, x1 = *(const f4*)(p + 4);
      ushort_t hh[8], ll[8];
#pragma unroll
      for (int q = 0; q < 4; ++q) {
        ushort_t h0 = f2bf(x0[q]); hh[q] = h0; ll[q] = f2bf(x0[q] - bf2f(h0));
        ushort_t h1 = f2bf(x1[q]); hh[4 + q] = h1; ll[4 + q] = f2bf(x1[q] - bf2f(h1));
      }
      *(u4*)(lAh[bi] + row * LDR + kp) = u4{ pk2(hh[0], hh[1]), pk2(hh[2], hh[3]), pk2(hh[4], hh[5]), pk2(hh[6], hh[7]) };
      *(u4*)(lAl[bi] + row * LDR + kp) = u4{ pk2(ll[0], ll[1]), pk2(ll[2], ll[3]), pk2(ll[4], ll[5]), pk2(ll[6], ll[7]) };
    }
    {
      const float* p = Bb + (size_t)row * lda + k0 + kp;
      f4 x0 = *(const f4*)p, x1 = *(const f4*)(p + 4);
      ushort_t hh[8], ll[8];
#pragma unroll
      for (int q = 0; q < 4; ++q) {
        ushort_t h0 = f2bf(x0[q]); hh[q] = h0; ll[q] = f2bf(x0[q] - bf2f(h0));
        ushort_t h1 = f2bf(x1[q]); hh[4 + q] = h1; ll[4 + q] = f2bf(x1[q] - bf2f(h1));
      }
      *(u4*)(lBh[bi] + row * LDR + kp) = u4{ pk2(hh[0], hh[1]), pk2(hh[2], hh[3]), pk2(hh[4], hh[5]), pk2(hh[6], hh[7]) };
      *(u4*)(lBl[bi] + row * LDR + kp) = u4{ pk2(ll[0], ll[1]), pk2(ll[2], ll[3]), pk2(ll[4], ll[5]), pk2(ll[6], ll[7]) };
    }
  };

  stage(0, 0);
  __syncthreads();
  for (int tt = 0; tt < 32; ++tt) {
    int cur = tt & 1;
    if (tt + 1 < 32) stage((tt + 1) << 5, cur ^ 1);
    u4 ah[2], al[2], bh[2], bl[2];
#pragma unroll
    for (int m = 0; m < 2; ++m) {
      int off = (wr + m * 16 + fr) * LDR + (fg << 3);
      ah[m] = *(const u4*)(lAh[cur] + off);
      al[m] = *(const u4*)(lAl[cur] + off);
    }
#pragma unroll
    for (int n = 0; n < 2; ++n) {
      int off = (wc + n * 16 + fr) * LDR + (fg << 3);
      bh[n] = *(const u4*)(lBh[cur] + off);
      bl[n] = *(const u4*)(lBl[cur] + off);
    }
#pragma unroll
    for (int m = 0; m < 2; ++m)
#pragma unroll
      for (int n = 0; n < 2; ++n) {
        mfma16(acc[m][n], ah[m], bh[n]);
        mfma16(acc[m][n], ah[m], bl[n]);
        mfma16(acc[m][n], al[m], bh[n]);
      }
    __syncthreads();
  }

  float* Sb = S + (size_t)b * 65536;
#pragma unroll
  for (int m = 0; m < 2; ++m)
#pragma unroll
    for (int n = 0; n < 2; ++n)
#pragma unroll
      for (int r = 0; r < 4; ++r) {
        int rrow = i0 + wr + m * 16 + fg * 4 + r;
        int col = j0 + wc + n * 16 + fr;
        Sb[(size_t)rrow * 256 + col] = acc[m][n][r];
      }
}

// ---------------------------------------------------------------------------
// softmax over j (contiguous)
// ---------------------------------------------------------------------------
__global__ __launch_bounds__(256) void softmax_rows_kernel(
    const float* __restrict__ S, const uchar_t* __restrict__ hypoT,
    ushort_t* __restrict__ W) {
  int r = blockIdx.x * 4 + (threadIdx.x >> 6);
  int lane = threadIdx.x & 63;
  int b = r >> 8;
  const float* row = S + (size_t)r * 256;
  f4 x = *(const f4*)(row + lane * 4);
  const uchar_t* mp = hypoT + b * 256 + lane * 4;
  float v0 = mp[0] ? -1e30f : x[0];
  float v1 = mp[1] ? -1e30f : x[1];
  float v2 = mp[2] ? -1e30f : x[2];
  float v3 = mp[3] ? -1e30f : x[3];
  float m = fmaxf(fmaxf(v0, v1), fmaxf(v2, v3));
#pragma unroll
  for (int off = 32; off > 0; off >>= 1) m = fmaxf(m, __shfl_xor(m, off));
  float e0 = expf(v0 - m), e1 = expf(v1 - m), e2 = expf(v2 - m), e3 = expf(v3 - m);
  float s = e0 + e1 + e2 + e3;
#pragma unroll
  for (int off = 32; off > 0; off >>= 1) s += __shfl_xor(s, off);
  float rinv = 1.0f / s;
  ushort_t w0 = f2bf(e0 * rinv), w1 = f2bf(e1 * rinv), w2 = f2bf(e2 * rinv), w3 = f2bf(e3 * rinv);
  *(u2*)(W + (size_t)r * 256 + lane * 4) = u2{ pk2(w0, w1), pk2(w2, w3) };
}

// ---------------------------------------------------------------------------
// softmax over i (strided) + transpose: V[b][j][i]
// ---------------------------------------------------------------------------
__global__ __launch_bounds__(256) void softmax_cols_kernel(
    const float* __restrict__ S, const uchar_t* __restrict__ premT,
    ushort_t* __restrict__ V) {
  __shared__ float tl[32][257];
  __shared__ float pm[8][32], ps[8][32], mfin[32], rs[32];
  int t = threadIdx.x;
  int jl = t & 31, ig = t >> 5;
  int b = blockIdx.y, j0 = blockIdx.x * 32;
  const float* Sb = S + (size_t)b * 65536;
  const uchar_t* pmsk = premT + b * 256;
  for (int i = ig; i < 256; i += 8)
    tl[jl][i] = pmsk[i] ? -1e30f : Sb[(size_t)i * 256 + j0 + jl];
  __syncthreads();
  float m = -3e30f;
#pragma unroll 8
  for (int ii = 0; ii < 32; ++ii) m = fmaxf(m, tl[jl][ig * 32 + ii]);
  float s = 0.f;
#pragma unroll 8
  for (int ii = 0; ii < 32; ++ii) s += expf(tl[jl][ig * 32 + ii] - m);
  pm[ig][jl] = m; ps[ig][jl] = s;
  __syncthreads();
  if (t < 32) {
    float M = pm[0][t];
#pragma unroll
    for (int g = 1; g < 8; ++g) M = fmaxf(M, pm[g][t]);
    float ss = 0.f;
#pragma unroll
    for (int g = 0; g < 8; ++g) ss += ps[g][t] * expf(pm[g][t] - M);
    mfin[t] = M; rs[t] = 1.0f / ss;
  }
  __syncthreads();
  for (int j2 = 0; j2 < 32; ++j2) {
    float val = expf(tl[j2][t] - mfin[j2]) * rs[j2];
    V[((size_t)b * 256 + j0 + j2) * 256 + t] = f2bf(val);
  }
}

// ---------------------------------------------------------------------------
// emb transpose: E[pos][b][h] f32 -> T[b][h][pos] bf16
// ---------------------------------------------------------------------------
__global__ __launch_bounds__(256) void transpose_pos_h_kernel(
    const float* __restrict__ E, ushort_t* __restrict__ T) {
  __shared__ ushort_t tl[64][65];
  int i0 = blockIdx.x * 64, h0 = blockIdx.y * 64, b = blockIdx.z;
  int t = threadIdx.x;
#pragma unroll
  for (int it = 0; it < 16; ++it) {
    int idx = t + it * 256;
    int i = idx >> 6, h = idx & 63;
    tl[h][i] = f2bf(E[((size_t)(i0 + i) * 64 + b) * 1024 + h0 + h]);
  }
  __syncthreads();
#pragma unroll
  for (int it = 0; it < 16; ++it) {
    int idx = t + it * 256;
    int h = idx >> 6, i = idx & 63;
    T[((size_t)b * 1024 + h0 + h) * 256 + i0 + i] = tl[h][i];
  }
}

// ---------------------------------------------------------------------------
// context GEMM (depth-2 pipe, XCD-swizzled): ctx[pos][h], masked-write bf16
// into Xc[(pos*64+b)*1024 + h]. grid 1024 (1-D), block 256
// ---------------------------------------------------------------------------
__global__ __launch_bounds__(256) void gemm_ctx_kernel(
    const ushort_t* __restrict__ Attn, const ushort_t* __restrict__ T,
    const uchar_t* __restrict__ maskT, ushort_t* __restrict__ Xc) {
  __shared__ ushort_t lab[4 * 4096];
  int t = threadIdx.x;
  int bid = blockIdx.x;
  int nw = (bid & 7) * 128 + (bid >> 3);  // bijective: 1024 = 8*128
  int b = nw >> 4;
  int local = nw & 15;
  int m0 = (local & 1) * 128, n0 = (local >> 1) * 128;
  const ushort_t* A = Attn + (size_t)b * 65536 + (size_t)m0 * 256;
  const ushort_t* B = T + (size_t)b * 262144 + (size_t)n0 * 256;
  int lane = t & 63, wave = t >> 6;
  int wr = (wave >> 1) << 6, wc = (wave & 1) << 6;
  int fr = lane & 15, fg = lane >> 4;
  f4 acc[4][4];
#pragma unroll
  for (int m = 0; m < 4; ++m)
#pragma unroll
    for (int n = 0; n < 4; ++n) acc[m][n] = f4{0.f, 0.f, 0.f, 0.f};
  gemm_pipe(A, 256, B, 256, 256, lab, acc, t, wr, wc, fr, fg);
#pragma unroll
  for (int m = 0; m < 4; ++m)
#pragma unroll
    for (int n = 0; n < 4; ++n)
#pragma unroll
      for (int r = 0; r < 4; ++r) {
        int gm = m0 + wr + m * 16 + fg * 4 + r;
        int gn = n0 + wc + n * 16 + fr;
        float v = maskT[b * 256 + gm] ? 0.f : acc[m][n][r];
        Xc[((size_t)gm * 64 + b) * 1024 + gn] = f2bf(v);
      }
}

// ---------------------------------------------------------------------------
// MLP layer-1 GEMM (fused cast, depth-2 explicit pipe, XCD-swizzled) —
// round-9 verified (absmax 0.125, 104 us).
// ---------------------------------------------------------------------------
__global__ __launch_bounds__(256) void gemm_mlp1_kernel(
    const float* __restrict__ Ef, const ushort_t* __restrict__ Xc,
    const ushort_t* __restrict__ W, const float* __restrict__ bias,
    ushort_t* __restrict__ C) {
  __shared__ ushort_t lab[4 * 4096];
  int t = threadIdx.x;
  int bid = blockIdx.x;
  int mt = (bid & 7) * 16 + ((bid >> 3) & 15);  // [0,128) bijective
  int nt = bid >> 7;                            // [0,8)
  int m0 = mt * 128, n0 = nt * 128;
  int lane = t & 63, wave = t >> 6;
  int wr = (wave >> 1) << 6, wc = (wave & 1) << 6;
  int fr = lane & 15, fg = lane >> 4;
  const float* Eb = Ef + (size_t)m0 * 1024;
  const ushort_t* Ab = Xc + (size_t)m0 * 1024;
  const ushort_t* Wn = W + (size_t)n0 * 2048;
  f4 acc[4][4];
#pragma unroll
  for (int m = 0; m < 4; ++m)
#pragma unroll
    for (int n = 0; n < 4; ++n) acc[m][n] = f4{0.f, 0.f, 0.f, 0.f};

  ushort_t* a0 = lab;             ushort_t* b0 = lab + 4096;
  ushort_t* a1 = lab + 2 * 4096;  ushort_t* b1 = lab + 3 * 4096;
  auto stageA = [&](int ks, ushort_t* buf) {
    if (ks < 32) stage_tile_f32(Eb, ks << 5, buf, t);
    else         stage_tile(Ab, 1024, (ks - 32) << 5, buf, t);
  };
  stageA(0, a0);
  stage_tile(Wn, 2048, 0, b0, t);
  for (int tt = 0; tt < 64; ++tt) {
    asm volatile("s_waitcnt vmcnt(0) lgkmcnt(0)" ::: "memory");
    asm volatile("s_barrier" ::: "memory");
    if (tt + 1 < 64) {
      stageA(tt + 1, a1);
      stage_tile(Wn, 2048, (tt + 1) << 5, b1, t);
    }
    u4 af[4], bfv[4];
#pragma unroll
    for (int m = 0; m < 4; ++m) af[m] = *(const u4*)(a0 + (wr + m * 16 + fr) * 32 + (fg << 3));
#pragma unroll
    for (int n = 0; n < 4; ++n) bfv[n] = *(const u4*)(b0 + (wc + n * 16 + fr) * 32 + (fg << 3));
    asm volatile("s_waitcnt lgkmcnt(0)" ::: "memory");
    __builtin_amdgcn_sched_barrier(0);
#pragma unroll
    for (int m = 0; m < 4; ++m)
#pragma unroll
      for (int n = 0; n < 4; ++n) mfma16(acc[m][n], af[m], bfv[n]);
    ushort_t* ta = a0; a0 = a1; a1 = ta;
    ushort_t* tb = b0; b0 = b1; b1 = tb;
  }

#pragma unroll
  for (int m = 0; m < 4; ++m)
#pragma unroll
    for (int n = 0; n < 4; ++n)
#pragma unroll
      for (int r = 0; r < 4; ++r) {
        int gm = m0 + wr + m * 16 + fg * 4 + r;
        int gn = n0 + wc + n * 16 + fr;
        float v = acc[m][n][r] + bias[gn];
        v = v > 0.f ? v : 0.f;
        C[(size_t)gm * 1024 + gn] = f2bf(v);
      }
}

// ---------------------------------------------------------------------------
// MLP GEMM (depth-2 pipe, XCD-swizzled): C = relu(A @ W^T + bias).
// grid 1024 (1-D), block 256. (layer 2: K=1024)
// ---------------------------------------------------------------------------
__global__ __launch_bounds__(256) void gemm_mlp_kernel(
    const ushort_t* __restrict__ A, int lda, const ushort_t* __restrict__ W,
    int ldw, const float* __restrict__ bias, ushort_t* __restrict__ C, int K) {
  __shared__ ushort_t lab[4 * 4096];
  int t = threadIdx.x;
  int bid = blockIdx.x;
  int mt = (bid & 7) * 16 + ((bid >> 3) & 15);  // [0,128) bijective
  int nt = bid >> 7;                            // [0,8)
  int m0 = mt * 128, n0 = nt * 128;
  int lane = t & 63, wave = t >> 6;
  int wr = (wave >> 1) << 6, wc = (wave & 1) << 6;
  int fr = lane & 15, fg = lane >> 4;
  f4 acc[4][4];
#pragma unroll
  for (int m = 0; m < 4; ++m)
#pragma unroll
    for (int n = 0; n < 4; ++n) acc[m][n] = f4{0.f, 0.f, 0.f, 0.f};
  gemm_pipe(A + (size_t)m0 * lda, lda, W + (size_t)n0 * ldw, ldw, K,
            lab, acc, t, wr, wc, fr, fg);
#pragma unroll
  for (int m = 0; m < 4; ++m)
#pragma unroll
    for (int n = 0; n < 4; ++n)
#pragma unroll
      for (int r = 0; r < 4; ++r) {
        int gm = m0 + wr + m * 16 + fg * 4 + r;
        int gn = n0 + wc + n * 16 + fr;
        float v = acc[m][n][r] + bias[gn];
        v = v > 0.f ? v : 0.f;
        C[(size_t)gm * 1024 + gn] = f2bf(v);
      }
}

// ---------------------------------------------------------------------------
// pool partial: partial[jc][b][coff+n] = sum_{j in chunk} H2[(j*64+b)][n]
// ---------------------------------------------------------------------------
__global__ __launch_bounds__(256) void pool_partial_kernel(
    const ushort_t* __restrict__ H2, float* __restrict__ partial, int coff) {
  int jc = blockIdx.x, b = blockIdx.y, t = threadIdx.x;
  float a0 = 0.f, a1 = 0.f, a2 = 0.f, a3 = 0.f;
  for (int j = jc * 32; j < jc * 32 + 32; ++j) {
    u2 v = *(const u2*)(H2 + ((size_t)(j * 64 + b)) * 1024 + t * 4);
    a0 += bf2f((ushort_t)(v[0] & 0xffff));
    a1 += bf2f((ushort_t)(v[0] >> 16));
    a2 += bf2f((ushort_t)(v[1] & 0xffff));
    a3 += bf2f((ushort_t)(v[1] >> 16));
  }
  *(f4*)(partial + ((size_t)(jc * 64 + b)) * 2048 + coff + t * 4) = f4{a0, a1, a2, a3};
}

// ---------------------------------------------------------------------------
// pool final + hi/lo split. grid 512, block 256
// ---------------------------------------------------------------------------
__global__ __launch_bounds__(256) void pool_final_kernel(
    const float* __restrict__ partial, ushort_t* __restrict__ ph,
    ushort_t* __restrict__ pl) {
  int idx = blockIdx.x * 256 + threadIdx.x;
  int b = idx >> 11, k = idx & 2047;
  float s = 0.f;
#pragma unroll
  for (int jc = 0; jc < 8; ++jc) s += partial[((size_t)(jc * 64 + b)) * 2048 + k];
  ushort_t h = f2bf(s);
  ph[idx] = h;
  pl[idx] = f2bf(s - bf2f(h));
}

// ---------------------------------------------------------------------------
// agg layer 1 (split bf16x2)
// ---------------------------------------------------------------------------
__global__ __launch_bounds__(256) void gemm_agg1_kernel(
    const ushort_t* __restrict__ Ph, const ushort_t* __restrict__ Pl,
    const ushort_t* __restrict__ Wh, const ushort_t* __restrict__ Wl,
    const float* __restrict__ bias, float* __restrict__ z) {
  __shared__ ushort_t lAh[64 * LDR], lAl[64 * LDR], lBh[128 * LDR], lBl[128 * LDR];
  int t = threadIdx.x;
  int n0 = blockIdx.x * 128;
  int lane = t & 63, wave = t >> 6;
  int wc = wave * 32;
  int fr = lane & 15, fg = lane >> 4;
  f4 acc[4][2];
#pragma unroll
  for (int m = 0; m < 4; ++m)
#pragma unroll
    for (int n = 0; n < 2; ++n) acc[m][n] = f4{0.f, 0.f, 0.f, 0.f};

  for (int k0 = 0; k0 < 2048; k0 += 32) {
    __syncthreads();
    {
      int row = t >> 2, kp = (t & 3) << 3;
      *(u4*)(lAh + row * LDR + kp) = *(const u4*)(Ph + (size_t)row * 2048 + k0 + kp);
      *(u4*)(lAl + row * LDR + kp) = *(const u4*)(Pl + (size_t)row * 2048 + k0 + kp);
    }
#pragma unroll
    for (int c = 0; c < 2; ++c) {
      int ch = t + (c << 8);
      int row = ch >> 2, kp = (ch & 3) << 3;
      *(u4*)(lBh + row * LDR + kp) = *(const u4*)(Wh + (size_t)(n0 + row) * 2048 + k0 + kp);
      *(u4*)(lBl + row * LDR + kp) = *(const u4*)(Wl + (size_t)(n0 + row) * 2048 + k0 + kp);
    }
    __syncthreads();
    u4 ah[4], al[4], bh[2], bl[2];
#pragma unroll
    for (int m = 0; m < 4; ++m) {
      int off = (m * 16 + fr) * LDR + (fg << 3);
      ah[m] = *(const u4*)(lAh + off);
      al[m] = *(const u4*)(lAl + off);
    }
#pragma unroll
    for (int n = 0; n < 2; ++n) {
      int off = (wc + n * 16 + fr) * LDR + (fg << 3);
      bh[n] = *(const u4*)(lBh + off);
      bl[n] = *(const u4*)(lBl + off);
    }
#pragma unroll
    for (int m = 0; m < 4; ++m)
#pragma unroll
      for (int n = 0; n < 2; ++n) {
        mfma16(acc[m][n], ah[m], bh[n]);
        mfma16(acc[m][n], ah[m], bl[n]);
        mfma16(acc[m][n], al[m], bh[n]);
      }
  }
#pragma unroll
  for (int m = 0; m < 4; ++m)
#pragma unroll
    for (int n = 0; n < 2; ++n)
#pragma unroll
      for (int r = 0; r < 4; ++r) {
        int row = m * 16 + fg * 4 + r;  // b
        int col = n0 + wc + n * 16 + fr;
        float v = acc[m][n][r] + bias[col];
        z[row * 1024 + col] = v > 0.f ? v : 0.f;
      }
}

// ---------------------------------------------------------------------------
// agg layer 2
// ---------------------------------------------------------------------------
__global__ __launch_bounds__(64) void agg2_kernel(
    const float* __restrict__ z, const float* __restrict__ aW2,
    const float* __restrict__ ab2, float* __restrict__ out) {
  int b = blockIdx.x, lane = threadIdx.x;
  float a0 = 0.f, a1 = 0.f, a2 = 0.f;
  for (int k = lane; k < 1024; k += 64) {
    float zv = z[b * 1024 + k];
    a0 += zv * aW2[k * 3 + 0];
    a1 += zv * aW2[k * 3 + 1];
    a2 += zv * aW2[k * 3 + 2];
  }
#pragma unroll
  for (int off = 32; off > 0; off >>= 1) {
    a0 += __shfl_xor(a0, off);
    a1 += __shfl_xor(a1, off);
    a2 += __shfl_xor(a2, off);
  }
  if (lane == 0) {
    out[b * 3 + 0] = a0 + ab2[0];
    out[b * 3 + 1] = a1 + ab2[1];
    out[b * 3 + 2] = a2 + ab2[2];
  }
}

// ---------------------------------------------------------------------------
extern "C" void kernel_launch(void* const* d_in, const int* in_sizes, int n_in,
                              void* d_out, int out_size, void* d_ws, size_t ws_size,
                              hipStream_t stream) {
  const float* P_enc = (const float*)d_in[0];
  const float* H_enc = (const float*)d_in[1];
  const float* P_emb = (const float*)d_in[2];
  const float* H_emb = (const float*)d_in[3];
  const uchar_t* prem = (const uchar_t*)d_in[4];
  const uchar_t* hypo = (const uchar_t*)d_in[5];
  const float* cW1 = (const float*)d_in[6];
  const float* cb1 = (const float*)d_in[7];
  const float* cW2 = (const float*)d_in[8];
  const float* cb2 = (const float*)d_in[9];
  const float* aW1 = (const float*)d_in[10];
  const float* ab1 = (const float*)d_in[11];
  const float* aW2 = (const float*)d_in[12];
  const float* ab2 = (const float*)d_in[13];

  char* w = (char*)d_ws;
  auto alloc = [&](size_t bytes) { char* p = w; w += bytes; return p; };
  float* S        = (float*)alloc(16777216);     // [64][256][256] f32
  ushort_t* Wsm   = (ushort_t*)alloc(8388608);   // [b][i][j] bf16
  ushort_t* Vsm   = (ushort_t*)alloc(8388608);   // [b][j][i] bf16
  ushort_t* T     = (ushort_t*)alloc(33554432);  // [b][h][pos] bf16
  ushort_t* Xc    = (ushort_t*)alloc(33554432);  // ctx [16384][1024] bf16
  ushort_t* H1    = (ushort_t*)alloc(33554432);  // [16384][1024]
  ushort_t* H2    = (ushort_t*)alloc(33554432);  // [16384][1024]
  ushort_t* cW1T  = (ushort_t*)alloc(4194304);   // [1024][2048]
  ushort_t* cW2T  = (ushort_t*)alloc(2097152);   // [1024][1024]
  ushort_t* aW1Th = (ushort_t*)alloc(4194304);
  ushort_t* aW1Tl = (ushort_t*)alloc(4194304);
  float* partial  = (float*)alloc(4194304);      // [8][64][2048] f32
  ushort_t* poolh = (ushort_t*)alloc(262144);
  ushort_t* pooll = (ushort_t*)alloc(262144);
  float* z        = (float*)alloc(262144);       // [64][1024]
  uchar_t* premT  = (uchar_t*)alloc(16384);
  uchar_t* hypoT  = (uchar_t*)alloc(16384);

  prep_masks_kernel<<<1, 256, 0, stream>>>(prem, hypo, premT, hypoT);
  transpose_w_kernel<<<dim3(32, 16), 256, 0, stream>>>(cW1, cW1T, (ushort_t*)nullptr, 1024, 2048);
  transpose_w_kernel<<<dim3(16, 16), 256, 0, stream>>>(cW2, cW2T, (ushort_t*)nullptr, 1024, 1024);
  transpose_w_kernel<<<dim3(32, 16), 256, 0, stream>>>(aW1, aW1Th, aW1Tl, 1024, 2048);

  gemm_s_kernel<<<1024, 256, 0, stream>>>(P_enc, H_enc, S);
  softmax_rows_kernel<<<4096, 256, 0, stream>>>(S, hypoT, Wsm);
  softmax_cols_kernel<<<dim3(8, 64), 256, 0, stream>>>(S, premT, Vsm);

  // ---- hypothesis side: H_ctx = P_attn^T @ P_emb, compare MLP, pool ----
  transpose_pos_h_kernel<<<dim3(4, 16, 64), 256, 0, stream>>>(P_emb, T);
  gemm_ctx_kernel<<<1024, 256, 0, stream>>>(Vsm, T, hypoT, Xc);
  gemm_mlp1_kernel<<<1024, 256, 0, stream>>>(H_emb, Xc, cW1T, cb1, H1);
  gemm_mlp_kernel<<<1024, 256, 0, stream>>>(H1, 1024, cW2T, 1024, cb2, H2, 1024);
  pool_partial_kernel<<<dim3(8, 64), 256, 0, stream>>>(H2, partial, 0);

  // ---- premise side: P_ctx = H_attn^T @ H_emb, compare MLP, pool ----
  transpose_pos_h_kernel<<<dim3(4, 16, 64), 256, 0, stream>>>(H_emb, T);
  gemm_ctx_kernel<<<1024, 256, 0, stream>>>(Wsm, T, premT, Xc);
  gemm_mlp1_kernel<<<1024, 256, 0, stream>>>(P_emb, Xc, cW1T, cb1, H1);
  gemm_mlp_kernel<<<1024, 256, 0, stream>>>(H1, 1024, cW2T, 1024, cb2, H2, 1024);
  pool_partial_kernel<<<dim3(8, 64), 256, 0, stream>>>(H2, partial, 1024);

  // ---- aggregation ----
  pool_final_kernel<<<512, 256, 0, stream>>>(partial, poolh, pooll);
  gemm_agg1_kernel<<<8, 256, 0, stream>>>(poolh, pooll, aW1Th, aW1Tl, ab1, z);
  agg2_kernel<<<64, 64, 0, stream>>>(z, aW2, ab2, (float*)d_out);
}

// Round 15
// 604.321 us; speedup vs baseline: 1.0964x; 1.0011x over previous
//
#include <hip/hip_runtime.h>
#include <cstdint>
#include <cstddef>

typedef unsigned short ushort_t;
typedef unsigned char uchar_t;
typedef __attribute__((ext_vector_type(4))) float f4;
typedef __attribute__((ext_vector_type(4))) unsigned int u4;
typedef __attribute__((ext_vector_type(2))) unsigned int u2;

#define DEVI static __device__ __forceinline__

DEVI ushort_t f2bf(float x) {
  union { float f; unsigned int u; } v; v.f = x;
  unsigned int r = v.u + 0x7fffu + ((v.u >> 16) & 1u);
  return (ushort_t)(r >> 16);
}
DEVI float bf2f(ushort_t b) {
  union { unsigned int u; float f; } v; v.u = ((unsigned int)b) << 16;
  return v.f;
}
DEVI unsigned pk2(ushort_t a, ushort_t b) { return (unsigned)a | ((unsigned)b << 16); }

DEVI void mfma16(f4& c, u4 a, u4 b) {
  asm("v_mfma_f32_16x16x32_bf16 %0, %1, %2, %0" : "+v"(c) : "v"(a), "v"(b));
}

constexpr int LDR = 40;  // padded LDS row stride (shorts) for reg-staged tiles

// --------------------------------------------------------------------------
// global_load_lds staging: bf16 tile [128 rows][32 cols], linear LDS layout.
// NOTE (r10-r14 post-mortem): this staging is VERIFIED ONLY in this exact
// 4-wave/128-row/2-calls-per-step geometry. Every variant (8-wave, 256-row,
// 3-calls-per-step) produced LDS garbage or faulted. Do not extend.
// --------------------------------------------------------------------------
#if defined(__has_builtin)
#if __has_builtin(__builtin_amdgcn_global_load_lds)
#define HAS_GLD 1
#endif
#endif
#ifndef HAS_GLD
#define HAS_GLD 0
#endif

#if HAS_GLD
typedef const __attribute__((address_space(1))) unsigned int* gas1_t;
typedef __attribute__((address_space(3))) unsigned int* las3_t;
DEVI void gld16(const void* g, void* l) {
  __builtin_amdgcn_global_load_lds((gas1_t)g, (las3_t)l, 16, 0, 0);
}
#endif

// Stages rows 0..127, cols k0..k0+31 of src (row stride srcStride) into
// lT[128][32] linear. 2 vmcnt-ops/thread on the gld path.
DEVI void stage_tile(const ushort_t* __restrict__ src, int srcStride, int k0,
                     ushort_t* lT, int t) {
#if HAS_GLD
  int w = t >> 6, lane = t & 63;
#pragma unroll
  for (int c = 0; c < 2; ++c) {
    int row = c * 64 + w * 16 + (lane >> 2);
    const ushort_t* g = src + (size_t)row * srcStride + k0 + (lane & 3) * 8;
    gld16(g, lT + (c * 64 + w * 16) * 32);
  }
#else
  int row = t >> 1, kp = (t & 1) << 4;
  const ushort_t* g = src + (size_t)row * srcStride + k0 + kp;
  *(u4*)(lT + row * 32 + kp) = *(const u4*)g;
  *(u4*)(lT + row * 32 + kp + 8) = *(const u4*)(g + 8);
#endif
}

// f32 source staging: convert 16 f32 -> bf16 in regs, ds_write into [128][32].
// ds_writes are drained by the pre-MFMA lgkmcnt(0) of the same step.
DEVI void stage_tile_f32(const float* __restrict__ src, int k0,
                         ushort_t* lT, int t) {
  int row = t >> 1, kp = (t & 1) << 4;
  const float* p = src + (size_t)row * 1024 + k0 + kp;
  f4 x0 = *(const f4*)p, x1 = *(const f4*)(p + 4);
  f4 x2 = *(const f4*)(p + 8), x3 = *(const f4*)(p + 12);
  ushort_t hh[16];
#pragma unroll
  for (int q = 0; q < 4; ++q) {
    hh[q] = f2bf(x0[q]); hh[4 + q] = f2bf(x1[q]);
    hh[8 + q] = f2bf(x2[q]); hh[12 + q] = f2bf(x3[q]);
  }
  *(u4*)(lT + row * 32 + kp) =
      u4{ pk2(hh[0], hh[1]), pk2(hh[2], hh[3]), pk2(hh[4], hh[5]), pk2(hh[6], hh[7]) };
  *(u4*)(lT + row * 32 + kp + 8) =
      u4{ pk2(hh[8], hh[9]), pk2(hh[10], hh[11]), pk2(hh[12], hh[13]), pk2(hh[14], hh[15]) };
}

// fragment reads + 16 MFMA for the 128x128, 4-wave layout (linear [128][32] LDS)
DEVI void compute16(const ushort_t* lA, const ushort_t* lB, f4 acc[4][4],
                    int wr, int wc, int fr, int fg) {
  u4 af[4], bfv[4];
#pragma unroll
  for (int m = 0; m < 4; ++m) af[m] = *(const u4*)(lA + (wr + m * 16 + fr) * 32 + (fg << 3));
#pragma unroll
  for (int n = 0; n < 4; ++n) bfv[n] = *(const u4*)(lB + (wc + n * 16 + fr) * 32 + (fg << 3));
#pragma unroll
  for (int m = 0; m < 4; ++m)
#pragma unroll
    for (int n = 0; n < 4; ++n) mfma16(acc[m][n], af[m], bfv[n]);
}

// ---------------------------------------------------------------------------
// Depth-2 explicit-sync pipelined GEMM core (rounds 8/9/13 verified, 0.125):
//  R1 buf[t] ready before ds_read: vmcnt(0) at top; s_barrier globalizes.
//  R2 stage(t+1) overwrites buf[t^1]: its readers (iter t-1) drained
//     lgkmcnt(0) before their MFMA, then crossed THIS barrier.
//  R3 rule #18: sched_barrier(0) after lgkmcnt(0) so MFMA can't hoist.
// ---------------------------------------------------------------------------
#if HAS_GLD
DEVI void gemm_pipe(const ushort_t* __restrict__ A, int lda,
                    const ushort_t* __restrict__ B, int ldb, int K,
                    ushort_t* lab, f4 acc[4][4], int t, int wr, int wc,
                    int fr, int fg) {
  ushort_t* a0 = lab;             ushort_t* b0 = lab + 4096;
  ushort_t* a1 = lab + 2 * 4096;  ushort_t* b1 = lab + 3 * 4096;
  const int nt = K >> 5;
  stage_tile(A, lda, 0, a0, t);
  stage_tile(B, ldb, 0, b0, t);
  for (int tt = 0; tt < nt; ++tt) {
    asm volatile("s_waitcnt vmcnt(0)" ::: "memory");
    asm volatile("s_barrier" ::: "memory");
    if (tt + 1 < nt) {
      stage_tile(A, lda, (tt + 1) << 5, a1, t);
      stage_tile(B, ldb, (tt + 1) << 5, b1, t);
    }
    u4 af[4], bfv[4];
#pragma unroll
    for (int m = 0; m < 4; ++m) af[m] = *(const u4*)(a0 + (wr + m * 16 + fr) * 32 + (fg << 3));
#pragma unroll
    for (int n = 0; n < 4; ++n) bfv[n] = *(const u4*)(b0 + (wc + n * 16 + fr) * 32 + (fg << 3));
    asm volatile("s_waitcnt lgkmcnt(0)" ::: "memory");
    __builtin_amdgcn_sched_barrier(0);
#pragma unroll
    for (int m = 0; m < 4; ++m)
#pragma unroll
      for (int n = 0; n < 4; ++n) mfma16(acc[m][n], af[m], bfv[n]);
    ushort_t* ta = a0; a0 = a1; a1 = ta;
    ushort_t* tb = b0; b0 = b1; b1 = tb;
  }
}
#else
DEVI void gemm_pipe(const ushort_t* __restrict__ A, int lda,
                    const ushort_t* __restrict__ B, int ldb, int K,
                    ushort_t* lab, f4 acc[4][4], int t, int wr, int wc,
                    int fr, int fg) {
  ushort_t* a0 = lab;
  ushort_t* b0 = lab + 4096;
  const int nt = K >> 5;
  for (int tt = 0; tt < nt; ++tt) {
    __syncthreads();
    stage_tile(A, lda, tt << 5, a0, t);
    stage_tile(B, ldb, tt << 5, b0, t);
    __syncthreads();
    compute16(a0, b0, acc, wr, wc, fr, fg);
  }
}
#endif

// ---------------------------------------------------------------------------
// mask prep: detect uint8-bool vs int32 storage, write transposed [b][pos]
// ---------------------------------------------------------------------------
__global__ __launch_bounds__(256) void prep_masks_kernel(
    const uchar_t* __restrict__ prem, const uchar_t* __restrict__ hypo,
    uchar_t* __restrict__ premT, uchar_t* __restrict__ hypoT) {
  __shared__ int flagP, flagH;
  int t = threadIdx.x;
  if (t == 0) { flagP = 0; flagH = 0; }
  __syncthreads();
  int locP = 0, locH = 0;
  for (int i = t; i < 16384; i += 256) {
    if (i & 3) { locP |= prem[i]; locH |= hypo[i]; }
  }
  if (locP) atomicOr(&flagP, 1);
  if (locH) atomicOr(&flagH, 1);
  __syncthreads();
  bool p8 = flagP != 0, h8 = flagH != 0;  // true -> 1-byte bools
  for (int i = t; i < 16384; i += 256) {
    int p = i >> 6, b = i & 63;
    premT[b * 256 + p] = p8 ? prem[i] : prem[i * 4];
    hypoT[b * 256 + p] = h8 ? hypo[i] : hypo[i * 4];
  }
}

// ---------------------------------------------------------------------------
// weight transpose: f32 [K][N] -> bf16 [N][K] (optionally hi/lo split)
// ---------------------------------------------------------------------------
__global__ __launch_bounds__(256) void transpose_w_kernel(
    const float* __restrict__ Win, ushort_t* __restrict__ Thi,
    ushort_t* __restrict__ Tlo, int N, int K) {
  __shared__ float tl[64][65];
  int k0 = blockIdx.x * 64, n0 = blockIdx.y * 64;
  int t = threadIdx.x;
#pragma unroll
  for (int it = 0; it < 16; ++it) {
    int idx = t + it * 256;
    int k = idx >> 6, n = idx & 63;
    tl[n][k] = Win[(size_t)(k0 + k) * N + n0 + n];
  }
  __syncthreads();
#pragma unroll
  for (int it = 0; it < 16; ++it) {
    int idx = t + it * 256;
    int n = idx >> 6, k = idx & 63;
    float x = tl[n][k];
    ushort_t h = f2bf(x);
    Thi[(size_t)(n0 + n) * K + k0 + k] = h;
    if (Tlo) Tlo[(size_t)(n0 + n) * K + k0 + k] = f2bf(x - bf2f(h));
  }
}

// ---------------------------------------------------------------------------
// S GEMM, bf16x2 split, 64x64 tiles, dbuf single-barrier (ds_write staging
// only -> __syncthreads fully covers it). grid 1024 (1-D, XCD-swizzled).
// ---------------------------------------------------------------------------
__global__ __launch_bounds__(256) void gemm_s_kernel(
    const float* __restrict__ Penc, const float* __restrict__ Henc,
    float* __restrict__ S) {
  __shared__ ushort_t lAh[2][64 * LDR], lAl[2][64 * LDR];
  __shared__ ushort_t lBh[2][64 * LDR], lBl[2][64 * LDR];
  const int t = threadIdx.x;
  const int bid = blockIdx.x;
  const int nw = (bid & 7) * 128 + (bid >> 3);  // bijective: 1024 = 8*128
  const int b = nw >> 4;
  const int local = nw & 15;
  const int i0 = (local & 3) * 64, j0 = (local >> 2) * 64;
  const int lda = 64 * 1024;
  const float* Ab = Penc + (size_t)i0 * lda + (size_t)b * 1024;
  const float* Bb = Henc + (size_t)j0 * lda + (size_t)b * 1024;
  const int lane = t & 63, wave = t >> 6;
  const int wr = (wave >> 1) << 5, wc = (wave & 1) << 5;
  const int fr = lane & 15, fg = lane >> 4;
  const int row = t >> 2, kp = (t & 3) << 3;

  f4 acc[2][2];
#pragma unroll
  for (int m = 0; m < 2; ++m)
#pragma unroll
    for (int n = 0; n < 2; ++n) acc[m][n] = f4{0.f, 0.f, 0.f, 0.f};

  auto stage = [&](int k0, int bi) {
    {
      const float* p = Ab + (size_t)row * lda + k0 + kp;
      f4 x0 = *(const f4*)p, x1 = *(const f4*)(p + 4);
      ushort_t hh[8], ll[8];
#pragma unroll
      for (int q = 0; q < 4; ++q) {
        ushort_t h0 = f2bf(x0[q]); hh[q] = h0; ll[q] = f2bf(x0[q] - bf2f(h0));
        ushort_t h1 = f2bf(x1[q]); hh[4 + q] = h1; ll[4 + q] = f2bf(x1[q] - bf2f(h1));
      }
      *(u4*)(lAh[bi] + row * LDR + kp) = u4{ pk2(hh[0], hh[1]), pk2(hh[2], hh[3]), pk2(hh[4], hh[5]), pk2(hh[6], hh[7]) };
      *(u4*)(lAl[bi] + row * LDR + kp) = u4{ pk2(ll[0], ll[1]), pk2(ll[2], ll[3]), pk2(ll[4], ll[5]), pk2(ll[6], ll[7]) };
    }
    {
      const float* p = Bb + (size_t)row * lda + k0 + kp;
      f4 x0 = *(const f4*)p, x1 = *(const f4*)(p + 4);
      ushort_t hh[8], ll[8];
#pragma unroll
      for (int q = 0; q < 4; ++q) {
        ushort_t h0 = f2bf(x0[q]); hh[q] = h0; ll[q] = f2bf(x0[q] - bf2f(h0));
        ushort_t h1 = f2bf(x1[q]); hh[4 + q] = h1; ll[4 + q] = f2bf(x1[q] - bf2f(h1));
      }
      *(u4*)(lBh[bi] + row * LDR + kp) = u4{ pk2(hh[0], hh[1]), pk2(hh[2], hh[3]), pk2(hh[4], hh[5]), pk2(hh[6], hh[7]) };
      *(u4*)(lBl[bi] + row * LDR + kp) = u4{ pk2(ll[0], ll[1]), pk2(ll[2], ll[3]), pk2(ll[4], ll[5]), pk2(ll[6], ll[7]) };
    }
  };

  stage(0, 0);
  __syncthreads();
  for (int tt = 0; tt < 32; ++tt) {
    int cur = tt & 1;
    if (tt + 1 < 32) stage((tt + 1) << 5, cur ^ 1);
    u4 ah[2], al[2], bh[2], bl[2];
#pragma unroll
    for (int m = 0; m < 2; ++m) {
      int off = (wr + m * 16 + fr) * LDR + (fg << 3);
      ah[m] = *(const u4*)(lAh[cur] + off);
      al[m] = *(const u4*)(lAl[cur] + off);
    }
#pragma unroll
    for (int n = 0; n < 2; ++n) {
      int off = (wc + n * 16 + fr) * LDR + (fg << 3);
      bh[n] = *(const u4*)(lBh[cur] + off);
      bl[n] = *(const u4*)(lBl[cur] + off);
    }
#pragma unroll
    for (int m = 0; m < 2; ++m)
#pragma unroll
      for (int n = 0; n < 2; ++n) {
        mfma16(acc[m][n], ah[m], bh[n]);
        mfma16(acc[m][n], ah[m], bl[n]);
        mfma16(acc[m][n], al[m], bh[n]);
      }
    __syncthreads();
  }

  float* Sb = S + (size_t)b * 65536;
#pragma unroll
  for (int m = 0; m < 2; ++m)
#pragma unroll
    for (int n = 0; n < 2; ++n)
#pragma unroll
      for (int r = 0; r < 4; ++r) {
        int rrow = i0 + wr + m * 16 + fg * 4 + r;
        int col = j0 + wc + n * 16 + fr;
        Sb[(size_t)rrow * 256 + col] = acc[m][n][r];
      }
}

// ---------------------------------------------------------------------------
// softmax over j (contiguous)
// ---------------------------------------------------------------------------
__global__ __launch_bounds__(256) void softmax_rows_kernel(
    const float* __restrict__ S, const uchar_t* __restrict__ hypoT,
    ushort_t* __restrict__ W) {
  int r = blockIdx.x * 4 + (threadIdx.x >> 6);
  int lane = threadIdx.x & 63;
  int b = r >> 8;
  const float* row = S + (size_t)r * 256;
  f4 x = *(const f4*)(row + lane * 4);
  const uchar_t* mp = hypoT + b * 256 + lane * 4;
  float v0 = mp[0] ? -1e30f : x[0];
  float v1 = mp[1] ? -1e30f : x[1];
  float v2 = mp[2] ? -1e30f : x[2];
  float v3 = mp[3] ? -1e30f : x[3];
  float m = fmaxf(fmaxf(v0, v1), fmaxf(v2, v3));
#pragma unroll
  for (int off = 32; off > 0; off >>= 1) m = fmaxf(m, __shfl_xor(m, off));
  float e0 = expf(v0 - m), e1 = expf(v1 - m), e2 = expf(v2 - m), e3 = expf(v3 - m);
  float s = e0 + e1 + e2 + e3;
#pragma unroll
  for (int off = 32; off > 0; off >>= 1) s += __shfl_xor(s, off);
  float rinv = 1.0f / s;
  ushort_t w0 = f2bf(e0 * rinv), w1 = f2bf(e1 * rinv), w2 = f2bf(e2 * rinv), w3 = f2bf(e3 * rinv);
  *(u2*)(W + (size_t)r * 256 + lane * 4) = u2{ pk2(w0, w1), pk2(w2, w3) };
}

// ---------------------------------------------------------------------------
// softmax over i (strided) + transpose: V[b][j][i]
// ---------------------------------------------------------------------------
__global__ __launch_bounds__(256) void softmax_cols_kernel(
    const float* __restrict__ S, const uchar_t* __restrict__ premT,
    ushort_t* __restrict__ V) {
  __shared__ float tl[32][257];
  __shared__ float pm[8][32], ps[8][32], mfin[32], rs[32];
  int t = threadIdx.x;
  int jl = t & 31, ig = t >> 5;
  int b = blockIdx.y, j0 = blockIdx.x * 32;
  const float* Sb = S + (size_t)b * 65536;
  const uchar_t* pmsk = premT + b * 256;
  for (int i = ig; i < 256; i += 8)
    tl[jl][i] = pmsk[i] ? -1e30f : Sb[(size_t)i * 256 + j0 + jl];
  __syncthreads();
  float m = -3e30f;
#pragma unroll 8
  for (int ii = 0; ii < 32; ++ii) m = fmaxf(m, tl[jl][ig * 32 + ii]);
  float s = 0.f;
#pragma unroll 8
  for (int ii = 0; ii < 32; ++ii) s += expf(tl[jl][ig * 32 + ii] - m);
  pm[ig][jl] = m; ps[ig][jl] = s;
  __syncthreads();
  if (t < 32) {
    float M = pm[0][t];
#pragma unroll
    for (int g = 1; g < 8; ++g) M = fmaxf(M, pm[g][t]);
    float ss = 0.f;
#pragma unroll
    for (int g = 0; g < 8; ++g) ss += ps[g][t] * expf(pm[g][t] - M);
    mfin[t] = M; rs[t] = 1.0f / ss;
  }
  __syncthreads();
  for (int j2 = 0; j2 < 32; ++j2) {
    float val = expf(tl[j2][t] - mfin[j2]) * rs[j2];
    V[((size_t)b * 256 + j0 + j2) * 256 + t] = f2bf(val);
  }
}

// ---------------------------------------------------------------------------
// emb transpose: E[pos][b][h] f32 -> T[b][h][pos] bf16
// ---------------------------------------------------------------------------
__global__ __launch_bounds__(256) void transpose_pos_h_kernel(
    const float* __restrict__ E, ushort_t* __restrict__ T) {
  __shared__ ushort_t tl[64][65];
  int i0 = blockIdx.x * 64, h0 = blockIdx.y * 64, b = blockIdx.z;
  int t = threadIdx.x;
#pragma unroll
  for (int it = 0; it < 16; ++it) {
    int idx = t + it * 256;
    int i = idx >> 6, h = idx & 63;
    tl[h][i] = f2bf(E[((size_t)(i0 + i) * 64 + b) * 1024 + h0 + h]);
  }
  __syncthreads();
#pragma unroll
  for (int it = 0; it < 16; ++it) {
    int idx = t + it * 256;
    int h = idx >> 6, i = idx & 63;
    T[((size_t)b * 1024 + h0 + h) * 256 + i0 + i] = tl[h][i];
  }
}

// ---------------------------------------------------------------------------
// context GEMM (depth-2 pipe, XCD-swizzled): ctx[pos][h], masked-write bf16
// into Xc[(pos*64+b)*1024 + h]. grid 1024 (1-D), block 256
// ---------------------------------------------------------------------------
__global__ __launch_bounds__(256) void gemm_ctx_kernel(
    const ushort_t* __restrict__ Attn, const ushort_t* __restrict__ T,
    const uchar_t* __restrict__ maskT, ushort_t* __restrict__ Xc) {
  __shared__ ushort_t lab[4 * 4096];
  int t = threadIdx.x;
  int bid = blockIdx.x;
  int nw = (bid & 7) * 128 + (bid >> 3);  // bijective: 1024 = 8*128
  int b = nw >> 4;
  int local = nw & 15;
  int m0 = (local & 1) * 128, n0 = (local >> 1) * 128;
  const ushort_t* A = Attn + (size_t)b * 65536 + (size_t)m0 * 256;
  const ushort_t* B = T + (size_t)b * 262144 + (size_t)n0 * 256;
  int lane = t & 63, wave = t >> 6;
  int wr = (wave >> 1) << 6, wc = (wave & 1) << 6;
  int fr = lane & 15, fg = lane >> 4;
  f4 acc[4][4];
#pragma unroll
  for (int m = 0; m < 4; ++m)
#pragma unroll
    for (int n = 0; n < 4; ++n) acc[m][n] = f4{0.f, 0.f, 0.f, 0.f};
  gemm_pipe(A, 256, B, 256, 256, lab, acc, t, wr, wc, fr, fg);
#pragma unroll
  for (int m = 0; m < 4; ++m)
#pragma unroll
    for (int n = 0; n < 4; ++n)
#pragma unroll
      for (int r = 0; r < 4; ++r) {
        int gm = m0 + wr + m * 16 + fg * 4 + r;
        int gn = n0 + wc + n * 16 + fr;
        float v = maskT[b * 256 + gm] ? 0.f : acc[m][n][r];
        Xc[((size_t)gm * 64 + b) * 1024 + gn] = f2bf(v);
      }
}

// ---------------------------------------------------------------------------
// MLP layer-1 GEMM (fused cast, depth-2 explicit pipe, XCD-swizzled) —
// rounds 9/13 verified (absmax 0.125, ~104 us).
// ---------------------------------------------------------------------------
__global__ __launch_bounds__(256) void gemm_mlp1_kernel(
    const float* __restrict__ Ef, const ushort_t* __restrict__ Xc,
    const ushort_t* __restrict__ W, const float* __restrict__ bias,
    ushort_t* __restrict__ C) {
  __shared__ ushort_t lab[4 * 4096];
  int t = threadIdx.x;
  int bid = blockIdx.x;
  int mt = (bid & 7) * 16 + ((bid >> 3) & 15);  // [0,128) bijective
  int nt = bid >> 7;                            // [0,8)
  int m0 = mt * 128, n0 = nt * 128;
  int lane = t & 63, wave = t >> 6;
  int wr = (wave >> 1) << 6, wc = (wave & 1) << 6;
  int fr = lane & 15, fg = lane >> 4;
  const float* Eb = Ef + (size_t)m0 * 1024;
  const ushort_t* Ab = Xc + (size_t)m0 * 1024;
  const ushort_t* Wn = W + (size_t)n0 * 2048;
  f4 acc[4][4];
#pragma unroll
  for (int m = 0; m < 4; ++m)
#pragma unroll
    for (int n = 0; n < 4; ++n) acc[m][n] = f4{0.f, 0.f, 0.f, 0.f};

  ushort_t* a0 = lab;             ushort_t* b0 = lab + 4096;
  ushort_t* a1 = lab + 2 * 4096;  ushort_t* b1 = lab + 3 * 4096;
  auto stageA = [&](int ks, ushort_t* buf) {
    if (ks < 32) stage_tile_f32(Eb, ks << 5, buf, t);
    else         stage_tile(Ab, 1024, (ks - 32) << 5, buf, t);
  };
  stageA(0, a0);
  stage_tile(Wn, 2048, 0, b0, t);
  for (int tt = 0; tt < 64; ++tt) {
    asm volatile("s_waitcnt vmcnt(0) lgkmcnt(0)" ::: "memory");
    asm volatile("s_barrier" ::: "memory");
    if (tt + 1 < 64) {
      stageA(tt + 1, a1);
      stage_tile(Wn, 2048, (tt + 1) << 5, b1, t);
    }
    u4 af[4], bfv[4];
#pragma unroll
    for (int m = 0; m < 4; ++m) af[m] = *(const u4*)(a0 + (wr + m * 16 + fr) * 32 + (fg << 3));
#pragma unroll
    for (int n = 0; n < 4; ++n) bfv[n] = *(const u4*)(b0 + (wc + n * 16 + fr) * 32 + (fg << 3));
    asm volatile("s_waitcnt lgkmcnt(0)" ::: "memory");
    __builtin_amdgcn_sched_barrier(0);
#pragma unroll
    for (int m = 0; m < 4; ++m)
#pragma unroll
      for (int n = 0; n < 4; ++n) mfma16(acc[m][n], af[m], bfv[n]);
    ushort_t* ta = a0; a0 = a1; a1 = ta;
    ushort_t* tb = b0; b0 = b1; b1 = tb;
  }

#pragma unroll
  for (int m = 0; m < 4; ++m)
#pragma unroll
    for (int n = 0; n < 4; ++n)
#pragma unroll
      for (int r = 0; r < 4; ++r) {
        int gm = m0 + wr + m * 16 + fg * 4 + r;
        int gn = n0 + wc + n * 16 + fr;
        float v = acc[m][n][r] + bias[gn];
        v = v > 0.f ? v : 0.f;
        C[(size_t)gm * 1024 + gn] = f2bf(v);
      }
}

// ---------------------------------------------------------------------------
// MLP GEMM (depth-2 pipe, XCD-swizzled): C = relu(A @ W^T + bias).
// grid 1024 (1-D), block 256. (layer 2: K=1024)
// ---------------------------------------------------------------------------
__global__ __launch_bounds__(256) void gemm_mlp_kernel(
    const ushort_t* __restrict__ A, int lda, const ushort_t* __restrict__ W,
    int ldw, const float* __restrict__ bias, ushort_t* __restrict__ C, int K) {
  __shared__ ushort_t lab[4 * 4096];
  int t = threadIdx.x;
  int bid = blockIdx.x;
  int mt = (bid & 7) * 16 + ((bid >> 3) & 15);  // [0,128) bijective
  int nt = bid >> 7;                            // [0,8)
  int m0 = mt * 128, n0 = nt * 128;
  int lane = t & 63, wave = t >> 6;
  int wr = (wave >> 1) << 6, wc = (wave & 1) << 6;
  int fr = lane & 15, fg = lane >> 4;
  f4 acc[4][4];
#pragma unroll
  for (int m = 0; m < 4; ++m)
#pragma unroll
    for (int n = 0; n < 4; ++n) acc[m][n] = f4{0.f, 0.f, 0.f, 0.f};
  gemm_pipe(A + (size_t)m0 * lda, lda, W + (size_t)n0 * ldw, ldw, K,
            lab, acc, t, wr, wc, fr, fg);
#pragma unroll
  for (int m = 0; m < 4; ++m)
#pragma unroll
    for (int n = 0; n < 4; ++n)
#pragma unroll
      for (int r = 0; r < 4; ++r) {
        int gm = m0 + wr + m * 16 + fg * 4 + r;
        int gn = n0 + wc + n * 16 + fr;
        float v = acc[m][n][r] + bias[gn];
        v = v > 0.f ? v : 0.f;
        C[(size_t)gm * 1024 + gn] = f2bf(v);
      }
}

// ---------------------------------------------------------------------------
// pool partial: partial[jc][b][coff+n] = sum_{j in chunk} H2[(j*64+b)][n]
// ---------------------------------------------------------------------------
__global__ __launch_bounds__(256) void pool_partial_kernel(
    const ushort_t* __restrict__ H2, float* __restrict__ partial, int coff) {
  int jc = blockIdx.x, b = blockIdx.y, t = threadIdx.x;
  float a0 = 0.f, a1 = 0.f, a2 = 0.f, a3 = 0.f;
  for (int j = jc * 32; j < jc * 32 + 32; ++j) {
    u2 v = *(const u2*)(H2 + ((size_t)(j * 64 + b)) * 1024 + t * 4);
    a0 += bf2f((ushort_t)(v[0] & 0xffff));
    a1 += bf2f((ushort_t)(v[0] >> 16));
    a2 += bf2f((ushort_t)(v[1] & 0xffff));
    a3 += bf2f((ushort_t)(v[1] >> 16));
  }
  *(f4*)(partial + ((size_t)(jc * 64 + b)) * 2048 + coff + t * 4) = f4{a0, a1, a2, a3};
}

// ---------------------------------------------------------------------------
// pool final + hi/lo split. grid 512, block 256
// ---------------------------------------------------------------------------
__global__ __launch_bounds__(256) void pool_final_kernel(
    const float* __restrict__ partial, ushort_t* __restrict__ ph,
    ushort_t* __restrict__ pl) {
  int idx = blockIdx.x * 256 + threadIdx.x;
  int b = idx >> 11, k = idx & 2047;
  float s = 0.f;
#pragma unroll
  for (int jc = 0; jc < 8; ++jc) s += partial[((size_t)(jc * 64 + b)) * 2048 + k];
  ushort_t h = f2bf(s);
  ph[idx] = h;
  pl[idx] = f2bf(s - bf2f(h));
}

// ---------------------------------------------------------------------------
// agg layer 1 (split bf16x2)
// ---------------------------------------------------------------------------
__global__ __launch_bounds__(256) void gemm_agg1_kernel(
    const ushort_t* __restrict__ Ph, const ushort_t* __restrict__ Pl,
    const ushort_t* __restrict__ Wh, const ushort_t* __restrict__ Wl,
    const float* __restrict__ bias, float* __restrict__ z) {
  __shared__ ushort_t lAh[64 * LDR], lAl[64 * LDR], lBh[128 * LDR], lBl[128 * LDR];
  int t = threadIdx.x;
  int n0 = blockIdx.x * 128;
  int lane = t & 63, wave = t >> 6;
  int wc = wave * 32;
  int fr = lane & 15, fg = lane >> 4;
  f4 acc[4][2];
#pragma unroll
  for (int m = 0; m < 4; ++m)
#pragma unroll
    for (int n = 0; n < 2; ++n) acc[m][n] = f4{0.f, 0.f, 0.f, 0.f};

  for (int k0 = 0; k0 < 2048; k0 += 32) {
    __syncthreads();
    {
      int row = t >> 2, kp = (t & 3) << 3;
      *(u4*)(lAh + row * LDR + kp) = *(const u4*)(Ph + (size_t)row * 2048 + k0 + kp);
      *(u4*)(lAl + row * LDR + kp) = *(const u4*)(Pl + (size_t)row * 2048 + k0 + kp);
    }
#pragma unroll
    for (int c = 0; c < 2; ++c) {
      int ch = t + (c << 8);
      int row = ch >> 2, kp = (ch & 3) << 3;
      *(u4*)(lBh + row * LDR + kp) = *(const u4*)(Wh + (size_t)(n0 + row) * 2048 + k0 + kp);
      *(u4*)(lBl + row * LDR + kp) = *(const u4*)(Wl + (size_t)(n0 + row) * 2048 + k0 + kp);
    }
    __syncthreads();
    u4 ah[4], al[4], bh[2], bl[2];
#pragma unroll
    for (int m = 0; m < 4; ++m) {
      int off = (m * 16 + fr) * LDR + (fg << 3);
      ah[m] = *(const u4*)(lAh + off);
      al[m] = *(const u4*)(lAl + off);
    }
#pragma unroll
    for (int n = 0; n < 2; ++n) {
      int off = (wc + n * 16 + fr) * LDR + (fg << 3);
      bh[n] = *(const u4*)(lBh + off);
      bl[n] = *(const u4*)(lBl + off);
    }
#pragma unroll
    for (int m = 0; m < 4; ++m)
#pragma unroll
      for (int n = 0; n < 2; ++n) {
        mfma16(acc[m][n], ah[m], bh[n]);
        mfma16(acc[m][n], ah[m], bl[n]);
        mfma16(acc[m][n], al[m], bh[n]);
      }
  }
#pragma unroll
  for (int m = 0; m < 4; ++m)
#pragma unroll
    for (int n = 0; n < 2; ++n)
#pragma unroll
      for (int r = 0; r < 4; ++r) {
        int row = m * 16 + fg * 4 + r;  // b
        int col = n0 + wc + n * 16 + fr;
        float v = acc[m][n][r] + bias[col];
        z[row * 1024 + col] = v > 0.f ? v : 0.f;
      }
}

// ---------------------------------------------------------------------------
// agg layer 2
// ---------------------------------------------------------------------------
__global__ __launch_bounds__(64) void agg2_kernel(
    const float* __restrict__ z, const float* __restrict__ aW2,
    const float* __restrict__ ab2, float* __restrict__ out) {
  int b = blockIdx.x, lane = threadIdx.x;
  float a0 = 0.f, a1 = 0.f, a2 = 0.f;
  for (int k = lane; k < 1024; k += 64) {
    float zv = z[b * 1024 + k];
    a0 += zv * aW2[k * 3 + 0];
    a1 += zv * aW2[k * 3 + 1];
    a2 += zv * aW2[k * 3 + 2];
  }
#pragma unroll
  for (int off = 32; off > 0; off >>= 1) {
    a0 += __shfl_xor(a0, off);
    a1 += __shfl_xor(a1, off);
    a2 += __shfl_xor(a2, off);
  }
  if (lane == 0) {
    out[b * 3 + 0] = a0 + ab2[0];
    out[b * 3 + 1] = a1 + ab2[1];
    out[b * 3 + 2] = a2 + ab2[2];
  }
}

// ---------------------------------------------------------------------------
extern "C" void kernel_launch(void* const* d_in, const int* in_sizes, int n_in,
                              void* d_out, int out_size, void* d_ws, size_t ws_size,
                              hipStream_t stream) {
  const float* P_enc = (const float*)d_in[0];
  const float* H_enc = (const float*)d_in[1];
  const float* P_emb = (const float*)d_in[2];
  const float* H_emb = (const float*)d_in[3];
  const uchar_t* prem = (const uchar_t*)d_in[4];
  const uchar_t* hypo = (const uchar_t*)d_in[5];
  const float* cW1 = (const float*)d_in[6];
  const float* cb1 = (const float*)d_in[7];
  const float* cW2 = (const float*)d_in[8];
  const float* cb2 = (const float*)d_in[9];
  const float* aW1 = (const float*)d_in[10];
  const float* ab1 = (const float*)d_in[11];
  const float* aW2 = (const float*)d_in[12];
  const float* ab2 = (const float*)d_in[13];

  char* w = (char*)d_ws;
  auto alloc = [&](size_t bytes) { char* p = w; w += bytes; return p; };
  float* S        = (float*)alloc(16777216);     // [64][256][256] f32
  ushort_t* Wsm   = (ushort_t*)alloc(8388608);   // [b][i][j] bf16
  ushort_t* Vsm   = (ushort_t*)alloc(8388608);   // [b][j][i] bf16
  ushort_t* T     = (ushort_t*)alloc(33554432);  // [b][h][pos] bf16
  ushort_t* Xc    = (ushort_t*)alloc(33554432);  // ctx [16384][1024] bf16
  ushort_t* H1    = (ushort_t*)alloc(33554432);  // [16384][1024]
  ushort_t* H2    = (ushort_t*)alloc(33554432);  // [16384][1024]
  ushort_t* cW1T  = (ushort_t*)alloc(4194304);   // [1024][2048]
  ushort_t* cW2T  = (ushort_t*)alloc(2097152);   // [1024][1024]
  ushort_t* aW1Th = (ushort_t*)alloc(4194304);
  ushort_t* aW1Tl = (ushort_t*)alloc(4194304);
  float* partial  = (float*)alloc(4194304);      // [8][64][2048] f32
  ushort_t* poolh = (ushort_t*)alloc(262144);
  ushort_t* pooll = (ushort_t*)alloc(262144);
  float* z        = (float*)alloc(262144);       // [64][1024]
  uchar_t* premT  = (uchar_t*)alloc(16384);
  uchar_t* hypoT  = (uchar_t*)alloc(16384);

  prep_masks_kernel<<<1, 256, 0, stream>>>(prem, hypo, premT, hypoT);
  transpose_w_kernel<<<dim3(32, 16), 256, 0, stream>>>(cW1, cW1T, (ushort_t*)nullptr, 1024, 2048);
  transpose_w_kernel<<<dim3(16, 16), 256, 0, stream>>>(cW2, cW2T, (ushort_t*)nullptr, 1024, 1024);
  transpose_w_kernel<<<dim3(32, 16), 256, 0, stream>>>(aW1, aW1Th, aW1Tl, 1024, 2048);

  gemm_s_kernel<<<1024, 256, 0, stream>>>(P_enc, H_enc, S);
  softmax_rows_kernel<<<4096, 256, 0, stream>>>(S, hypoT, Wsm);
  softmax_cols_kernel<<<dim3(8, 64), 256, 0, stream>>>(S, premT, Vsm);

  // ---- hypothesis side: H_ctx = P_attn^T @ P_emb, compare MLP, pool ----
  transpose_pos_h_kernel<<<dim3(4, 16, 64), 256, 0, stream>>>(P_emb, T);
  gemm_ctx_kernel<<<1024, 256, 0, stream>>>(Vsm, T, hypoT, Xc);
  gemm_mlp1_kernel<<<1024, 256, 0, stream>>>(H_emb, Xc, cW1T, cb1, H1);
  gemm_mlp_kernel<<<1024, 256, 0, stream>>>(H1, 1024, cW2T, 1024, cb2, H2, 1024);
  pool_partial_kernel<<<dim3(8, 64), 256, 0, stream>>>(H2, partial, 0);

  // ---- premise side: P_ctx = H_attn^T @ H_emb, compare MLP, pool ----
  transpose_pos_h_kernel<<<dim3(4, 16, 64), 256, 0, stream>>>(H_emb, T);
  gemm_ctx_kernel<<<1024, 256, 0, stream>>>(Wsm, T, premT, Xc);
  gemm_mlp1_kernel<<<1024, 256, 0, stream>>>(P_emb, Xc, cW1T, cb1, H1);
  gemm_mlp_kernel<<<1024, 256, 0, stream>>>(H1, 1024, cW2T, 1024, cb2, H2, 1024);
  pool_partial_kernel<<<dim3(8, 64), 256, 0, stream>>>(H2, partial, 1024);

  // ---- aggregation ----
  pool_final_kernel<<<512, 256, 0, stream>>>(partial, poolh, pooll);
  gemm_agg1_kernel<<<8, 256, 0, stream>>>(poolh, pooll, aW1Th, aW1Tl, ab1, z);
  agg2_kernel<<<64, 64, 0, stream>>>(z, aW2, ab2, (float*)d_out);
}